// Round 7
// baseline (516.186 us; speedup 1.0000x reference)
//
#include <hip/hip_runtime.h>

// HKSABlock on MI355X (gfx950). Round 13 (resubmit; prior run hit an infra
// "container failed twice" error): generic gemm_bt upgraded with the
// R12-proven machinery. R7 profile measured 9.4M LDS bank conflicts on the
// gemm_bt path (stride-BK rows -> 8-way aliasing); qkv/attn_out/outproj
// additionally ran BK=32 (64 barriers). Now: BK=64 everywhere, 32-row
// staging groups with involution slot-swizzle (phys = logical ^ (row&7),
// 0 conflicts verified R9-R12), swizzled sq0/sq1 reads. All MODE epilogues
// unchanged; K-accumulation order unchanged (ascending 32-granules) so
// numerics identical. gates GEMM (gemm_gates128, 827 TF measured) untouched.
// B=2, T=1024, D=1024, NH=16, HD=64, H=64, M=16.

typedef unsigned short u16;
typedef unsigned int   u32;
typedef __bf16 bf16x8 __attribute__((ext_vector_type(8)));
typedef float  f32x4  __attribute__((ext_vector_type(4)));

#define B_  2
#define T_  1024
#define D_  1024
#define NH_ 16
#define HD_ 64
#define H_  64
#define M_  16

__device__ __forceinline__ float b2f(u16 u) {
    return __uint_as_float(((u32)u) << 16);
}
__device__ __forceinline__ u16 f2b(float f) {
    u32 u = __float_as_uint(f);
    u32 r = (u + 0x7FFFu + ((u >> 16) & 1u)) >> 16;  // RNE
    return (u16)r;
}
__device__ __forceinline__ float blo(u32 u) { return __uint_as_float(u << 16); }
__device__ __forceinline__ float bhi(u32 u) { return __uint_as_float(u & 0xFFFF0000u); }

// Async global->LDS, 16 B per lane. LDS dest must be wave-uniform base.
__device__ __forceinline__ void stage16(const void* gp, void* lp) {
    typedef __attribute__((address_space(1))) const unsigned int GU;
    typedef __attribute__((address_space(3))) unsigned int LU;
    __builtin_amdgcn_global_load_lds((GU*)gp, (LU*)lp, 16, 0, 0);
}

// ---------------------------------------------------------------------------
// Generic MFMA GEMM: C[M,N] = A[M,K] * Bt[N,K]^T  (A,Bt bf16 row-major).
// BK = 64 (required). 4 waves: wr = w>>1 (m-half), wc = w&1 (n-half).
// Staging: 32-row groups, thread t -> row (t>>3), phys slot (t&7), global
// source slot = (t&7)^(row&7) (involution). Reads: phys = (ks*4+quad)^(l16&7)
// -> 0 LDS bank conflicts (verified R9-R12 on the gates kernel).
// MODE 0: C fp32 (+ optional fp32 addend). MODE 1: C bf16.
// MODE 2: bf16 scatter into o_mat[(b*T + row)*1024 + h*64 + col], z = b*16+h.
// MODE 6: qkv + fused RoPE. N=3072; region = n0>>10 (0=Q,1=K,2=V). Each wave
//         owns one head's 64 cols; RoPE pair (i,i+32) = acc nt and nt+2.
//         Writes Qb(Cout)/Kb(Cout2)/Vb(Cout3) bf16 in (b,h,t,d).
// CAUSAL: skip blocks with n0 > m0+BM-1. TRUNCK: K truncated to m0+BM.
// ---------------------------------------------------------------------------
template<int BM, int BN, int BK, int MODE, bool TRUNCK, bool CAUSAL, int SWZ>
__global__ __launch_bounds__(256) void gemm_bt(
    const u16* __restrict__ A, const u16* __restrict__ Bt,
    void* __restrict__ Cout, void* __restrict__ Cout2, void* __restrict__ Cout3,
    const float* __restrict__ addend,
    int M, int N, int K, long strideA, long strideB, long strideC)
{
    static_assert(BK == 64, "gemm_bt requires BK=64");
    constexpr int MT = BM / 32;
    constexpr int NT = BN / 32;
    const int z  = blockIdx.z;
    const int bx = blockIdx.x, by = blockIdx.y;
    const int m0 = by * BM;
    const int n0 = bx * BN;
    if (CAUSAL && n0 > m0 + BM - 1) return;
    const int Keff = TRUNCK ? (K < m0 + BM ? K : m0 + BM) : K;

    const u16* Ab = A  + (size_t)z * (size_t)strideA;
    const u16* Bb = Bt + (size_t)z * (size_t)strideB;

    __shared__ alignas(16) u16 As[BM * 64];
    __shared__ alignas(16) u16 Bs[BN * 64];

    const int tid  = threadIdx.x;
    const int lane = tid & 63, w = tid >> 6;
    const int wr = w >> 1, wc = w & 1;
    const int quad = lane >> 4, l16 = lane & 15;

    // staging geometry (32 rows per call)
    const int srow   = tid >> 3;                          // 0..31
    const int colOff = (((tid & 7) ^ (srow & 7)) * 8);    // involution source slot
    const u16* pA = Ab + (size_t)(m0 + srow) * K + colOff;
    const u16* pB = Bb + (size_t)(n0 + srow) * K + colOff;
    const int wbase = w * 512;                            // wave-uniform dest (u16)

    // swizzled read slots: phys = (kstep*4 + quad) ^ (l16&7)
    const int sq0 = quad ^ (l16 & 7);
    const int sq1 = sq0 ^ 4;

    f32x4 acc[MT][NT] = {};

    for (int k0 = 0; k0 < Keff; k0 += 64) {
        #pragma unroll
        for (int c = 0; c < BM / 32; ++c)
            stage16(pA + (size_t)(c * 32) * K + k0, &As[c * 2048 + wbase]);
        #pragma unroll
        for (int c = 0; c < BN / 32; ++c)
            stage16(pB + (size_t)(c * 32) * K + k0, &Bs[c * 2048 + wbase]);
        __syncthreads();

        bf16x8 af[MT], bfr[NT];
        // kstep 0 (k 0..31 of tile)
        #pragma unroll
        for (int mt = 0; mt < MT; ++mt)
            af[mt] = *(const bf16x8*)&As[(wr * (BM / 2) + mt * 16 + l16) * 64 + sq0 * 8];
        #pragma unroll
        for (int nt = 0; nt < NT; ++nt)
            bfr[nt] = *(const bf16x8*)&Bs[(wc * (BN / 2) + nt * 16 + l16) * 64 + sq0 * 8];
        #pragma unroll
        for (int mt = 0; mt < MT; ++mt)
            #pragma unroll
            for (int nt = 0; nt < NT; ++nt)
                acc[mt][nt] = __builtin_amdgcn_mfma_f32_16x16x32_bf16(
                    af[mt], bfr[nt], acc[mt][nt], 0, 0, 0);
        // kstep 1 (k 32..63 of tile)
        #pragma unroll
        for (int mt = 0; mt < MT; ++mt)
            af[mt] = *(const bf16x8*)&As[(wr * (BM / 2) + mt * 16 + l16) * 64 + sq1 * 8];
        #pragma unroll
        for (int nt = 0; nt < NT; ++nt)
            bfr[nt] = *(const bf16x8*)&Bs[(wc * (BN / 2) + nt * 16 + l16) * 64 + sq1 * 8];
        #pragma unroll
        for (int mt = 0; mt < MT; ++mt)
            #pragma unroll
            for (int nt = 0; nt < NT; ++nt)
                acc[mt][nt] = __builtin_amdgcn_mfma_f32_16x16x32_bf16(
                    af[mt], bfr[nt], acc[mt][nt], 0, 0, 0);
        __syncthreads();
    }

    // Epilogue. C/D layout: col = lane&15, row = (lane>>4)*4 + reg  [m89]
    if (MODE == 6) {
        // dedicated RoPE epilogue (NT==4, BN==128 required)
        const int reg = n0 >> 10;                      // 0=Q, 1=K, 2=V
        const int hh  = ((n0 & 1023) >> 6) + wc;       // head
        #pragma unroll
        for (int mt = 0; mt < MT; ++mt) {
            #pragma unroll
            for (int r = 0; r < 4; ++r) {
                int row = m0 + wr * (BM / 2) + mt * 16 + quad * 4 + r;
                int t = row & (T_ - 1), bb = row >> 10;
                size_t obase = ((size_t)(bb * NH_ + hh) * T_ + t) * HD_;
                if (reg == 2) {
                    #pragma unroll
                    for (int nt = 0; nt < 4; ++nt)
                        ((u16*)Cout3)[obase + nt * 16 + l16] = f2b(acc[mt][nt][r]);
                } else {
                    u16* dst = (reg == 0) ? (u16*)Cout : (u16*)Cout2;
                    #pragma unroll
                    for (int nt = 0; nt < 2; ++nt) {
                        int i = nt * 16 + l16;
                        float ang = (float)t * exp2f(-(float)i * 0.41524101186092034f);
                        float sn, cs;
                        sincosf(ang, &sn, &cs);
                        float q1 = acc[mt][nt][r], q2 = acc[mt][nt + 2][r];
                        dst[obase + i]      = f2b(q1 * cs - q2 * sn);
                        dst[obase + i + 32] = f2b(q2 * cs + q1 * sn);
                    }
                }
            }
        }
        return;
    }
    #pragma unroll
    for (int mt = 0; mt < MT; ++mt) {
        #pragma unroll
        for (int nt = 0; nt < NT; ++nt) {
            #pragma unroll
            for (int r = 0; r < 4; ++r) {
                int row = m0 + wr * (BM / 2) + mt * 16 + quad * 4 + r;
                int col = n0 + wc * (BN / 2) + nt * 16 + l16;
                float val = acc[mt][nt][r];
                if (MODE == 0) {
                    if (addend) val += addend[(size_t)row * N + col];
                    ((float*)Cout)[(size_t)z * (size_t)strideC + (size_t)row * N + col] = val;
                } else if (MODE == 1) {
                    ((u16*)Cout)[(size_t)z * (size_t)strideC + (size_t)row * N + col] = f2b(val);
                } else if (MODE == 2) {
                    size_t idx = ((size_t)(z >> 4) * T_ + row) * (size_t)D_ + (z & 15) * HD_ + col;
                    ((u16*)Cout)[idx] = f2b(val);
                }
            }
        }
    }
}

// ---------------------------------------------------------------------------
// gates+w_v GEMM: C[2048,18432] = h2[2048,1024] x waT[18432,1024]^T.
// m97-structure (R12, measured 827 TF / 93.5 us): 128x192 tile, BK=64,
// 256 threads (4 waves 2x2, wave tile 64x96), single-buffered LDS 40 KB,
// 3 blocks/CU, grid 96x16 = 1536 blocks = 2 exact fill-waves.
// Swizzle: 16B slot phys = logical ^ (row&7) (0 conflicts).
// Epilogue: cg<1088 -> gates [chain][t][272] bf16; else vvT fp32.
// ---------------------------------------------------------------------------
__global__ __launch_bounds__(256, 3) void gemm_gates128(
    const u16* __restrict__ A, const u16* __restrict__ Bt,
    u16* __restrict__ gates, float* __restrict__ vvT)
{
    constexpr int K = 1024;
    constexpr int NTILE = 16;                    // K / 64

    // bijective XCD swizzle: 1536 blocks, 192/XCD = 12 bx x 16 by, by innermost
    const int f = blockIdx.y * gridDim.x + blockIdx.x;
    const int xcd = f & 7, k8 = f >> 3;          // k8 in [0,192)
    const int by = k8 & 15;
    const int bx = xcd * 12 + (k8 >> 4);
    const int m0 = by * 128;
    const int n0 = bx * 192;

    __shared__ alignas(16) u16 As[128 * 64];     // 16 KB
    __shared__ alignas(16) u16 Bs[192 * 64];     // 24 KB

    const int tid  = threadIdx.x;                // 0..255
    const int lane = tid & 63, w = tid >> 6;     // 4 waves
    const int wr = w >> 1, wc = w & 1;           // 2 x 2 wave grid
    const int quad = lane >> 4, l16 = lane & 15;

    // staging: thread t -> row (t>>3) within each 32-row call group, physical
    // 16B slot (t&7); global source slot = (t&7) ^ (row&7)  (involution).
    const int colOff = (((tid & 7) ^ ((tid >> 3) & 7)) * 8);
    const u16* pA = A  + (size_t)(m0 + (tid >> 3)) * K + colOff;
    const u16* pB = Bt + (size_t)(n0 + (tid >> 3)) * K + colOff;
    const int wbase = w * 512;                   // wave-uniform LDS dest (u16)

    // ds-read bases (u16): row*64 + phys_slot*8; phys = (kstep*4+quad)^(l16&7)
    const int sq0 = quad ^ (l16 & 7);
    const int sq1 = sq0 ^ 4;
    const int aoff0 = (wr * 64 + l16) * 64 + sq0 * 8;
    const int aoff1 = (wr * 64 + l16) * 64 + sq1 * 8;
    const int boff0 = (wc * 96 + l16) * 64 + sq0 * 8;
    const int boff1 = (wc * 96 + l16) * 64 + sq1 * 8;

    f32x4 acc[4][6] = {};                        // [mt][nt] wave tile 64x96

    #pragma unroll 1
    for (int t = 0; t < NTILE; ++t) {
        const int kc = t * 64;
        // stage A (4 calls x 32 rows) + B (6 calls x 32 rows)
        #pragma unroll
        for (int c = 0; c < 4; ++c)
            stage16(pA + (size_t)(c * 32) * K + kc, &As[c * 2048 + wbase]);
        #pragma unroll
        for (int c = 0; c < 6; ++c)
            stage16(pB + (size_t)(c * 32) * K + kc, &Bs[c * 2048 + wbase]);
        __syncthreads();

        bf16x8 af[4], bfr[6];
        // kstep 0 (k 0..31)
        #pragma unroll
        for (int mt = 0; mt < 4; ++mt) af[mt]  = *(const bf16x8*)&As[aoff0 + mt * 1024];
        #pragma unroll
        for (int nt = 0; nt < 6; ++nt) bfr[nt] = *(const bf16x8*)&Bs[boff0 + nt * 1024];
        #pragma unroll
        for (int mt = 0; mt < 4; ++mt)
            #pragma unroll
            for (int nt = 0; nt < 6; ++nt)
                acc[mt][nt] = __builtin_amdgcn_mfma_f32_16x16x32_bf16(
                    af[mt], bfr[nt], acc[mt][nt], 0, 0, 0);
        // kstep 1 (k 32..63)
        #pragma unroll
        for (int mt = 0; mt < 4; ++mt) af[mt]  = *(const bf16x8*)&As[aoff1 + mt * 1024];
        #pragma unroll
        for (int nt = 0; nt < 6; ++nt) bfr[nt] = *(const bf16x8*)&Bs[boff1 + nt * 1024];
        #pragma unroll
        for (int mt = 0; mt < 4; ++mt)
            #pragma unroll
            for (int nt = 0; nt < 6; ++nt)
                acc[mt][nt] = __builtin_amdgcn_mfma_f32_16x16x32_bf16(
                    af[mt], bfr[nt], acc[mt][nt], 0, 0, 0);
        __syncthreads();
    }

    // Epilogue: row = m0 + wr*64 + mt*16 + quad*4 + r
    //           col-group cg = bx*12 + wc*6 + nt (lane-uniform), col = cg*16+l16
    const int cgbase = bx * 12 + wc * 6;
    #pragma unroll
    for (int mt = 0; mt < 4; ++mt) {
        #pragma unroll
        for (int r = 0; r < 4; ++r) {
            int row = m0 + wr * 64 + mt * 16 + quad * 4 + r;
            int tt = row & (T_ - 1), bb = row >> 10;
            #pragma unroll
            for (int nt = 0; nt < 6; ++nt) {
                int cg = cgbase + nt;
                float val = acc[mt][nt][r];
                if (cg >= 1088) {
                    vvT[(((size_t)(bb * 64 + (cg - 1088))) * T_ + tt) * 16 + l16] = val;
                } else {
                    int hh = cg / 17, rem = cg - hh * 17;
                    gates[(((size_t)(bb * 64 + hh)) * T_ + tt) * 272 + rem * 16 + l16] = f2b(val);
                }
            }
        }
    }
}

// ---------------------------------------------------------------------------
__global__ __launch_bounds__(256) void rmsnorm_k(
    const float* __restrict__ x, const float* __restrict__ w, u16* __restrict__ out)
{
    const int row = blockIdx.x, tid = threadIdx.x;
    float4 v = ((const float4*)(x + (size_t)row * D_))[tid];
    float ss = v.x * v.x + v.y * v.y + v.z * v.z + v.w * v.w;
    #pragma unroll
    for (int o = 32; o >= 1; o >>= 1) ss += __shfl_xor(ss, o, 64);
    __shared__ float red[4];
    if ((tid & 63) == 0) red[tid >> 6] = ss;
    __syncthreads();
    ss = red[0] + red[1] + red[2] + red[3];
    float scale = rsqrtf(ss * (1.0f / D_) + 1e-5f);
    float4 wv = ((const float4*)w)[tid];
    ushort4 o4;
    o4.x = f2b(v.x * scale * wv.x);
    o4.y = f2b(v.y * scale * wv.y);
    o4.z = f2b(v.z * scale * wv.z);
    o4.w = f2b(v.w * scale * wv.w);
    ((ushort4*)(out + (size_t)row * D_))[tid] = o4;
}

// ---------------------------------------------------------------------------
// All weight converts in one launch. Segments by blockIdx.x (all R=1024):
//   [0,96)   wqkv C=3072 -> wqkvT
//   [96,128) wao  C=1024 -> waoT
//   [128,160)wv   C=1024 -> waT + 17408*1024 (contiguous with waT)
//   [160,704)wa   C=17408-> waT
//   [704,736)wop  C=1024 -> wopT
// ---------------------------------------------------------------------------
__global__ void convT_all(
    const float* __restrict__ wqkv, const float* __restrict__ wao,
    const float* __restrict__ wv,   const float* __restrict__ wa,
    const float* __restrict__ wop,
    u16* __restrict__ wqkvT, u16* __restrict__ waoT,
    u16* __restrict__ waT,   u16* __restrict__ wopT)
{
    const int x = blockIdx.x;
    const float* in; u16* out; int C, xb;
    if (x < 96)       { in = wqkv; out = wqkvT; C = 3072;  xb = x; }
    else if (x < 128) { in = wao;  out = waoT;  C = 1024;  xb = x - 96; }
    else if (x < 160) { in = wv;   out = waT + (size_t)17408 * 1024; C = 1024; xb = x - 128; }
    else if (x < 704) { in = wa;   out = waT;   C = 17408; xb = x - 160; }
    else              { in = wop;  out = wopT;  C = 1024;  xb = x - 704; }
    constexpr int R = 1024;
    __shared__ float tile[32][33];
    const int c0 = xb * 32, r0 = blockIdx.y * 32;
    const int tx = threadIdx.x, ty = threadIdx.y;
    #pragma unroll
    for (int k = 0; k < 4; ++k)
        tile[ty + 8 * k][tx] = in[(size_t)(r0 + ty + 8 * k) * C + c0 + tx];
    __syncthreads();
    #pragma unroll
    for (int k = 0; k < 4; ++k)
        out[(size_t)(c0 + ty + 8 * k) * R + r0 + tx] = f2b(tile[tx][ty + 8 * k]);
}

__global__ void transpose_bf16_k(const u16* __restrict__ in_, u16* __restrict__ out_, int R, int C)
{
    __shared__ u16 tile[32][33];
    const u16* in = in_ + (size_t)blockIdx.z * R * C;
    u16* out      = out_ + (size_t)blockIdx.z * R * C;
    const int c0 = blockIdx.x * 32, r0 = blockIdx.y * 32;
    const int tx = threadIdx.x, ty = threadIdx.y;
    #pragma unroll
    for (int k = 0; k < 4; ++k)
        tile[ty + 8 * k][tx] = in[(size_t)(r0 + ty + 8 * k) * C + c0 + tx];
    __syncthreads();
    #pragma unroll
    for (int k = 0; k < 4; ++k)
        out[(size_t)(c0 + ty + 8 * k) * R + r0 + tx] = tile[tx][ty + 8 * k];
}

// ---------------------------------------------------------------------------
// Causal softmax, wave-per-row (4 rows/block). Only k < kmax = roundup(t+1,64)
// is read/written (PV's TRUNCK reads exactly that range).
// ---------------------------------------------------------------------------
__global__ __launch_bounds__(256) void softmax_causal_k(u16* __restrict__ S)
{
    const int w = threadIdx.x >> 6, lane = threadIdx.x & 63;
    const int z = blockIdx.x * 4 + w;
    const int t = z & (T_ - 1);
    u16* row = S + (size_t)z * T_;
    const int n = t + 1;
    const int kmax = (t & ~63) + 64;
    const int kb = lane * 4;
    float v[4][4];
    float mx = -1e30f;
    #pragma unroll
    for (int it = 0; it < 4; ++it) {
        int k = it * 256 + kb;
        if (k < kmax) {
            uint2 d = *(const uint2*)(row + k);
            v[it][0] = (k + 0 < n) ? blo(d.x) * 0.125f : -1e30f;
            v[it][1] = (k + 1 < n) ? bhi(d.x) * 0.125f : -1e30f;
            v[it][2] = (k + 2 < n) ? blo(d.y) * 0.125f : -1e30f;
            v[it][3] = (k + 3 < n) ? bhi(d.y) * 0.125f : -1e30f;
        } else {
            v[it][0] = v[it][1] = v[it][2] = v[it][3] = -1e30f;
        }
        mx = fmaxf(mx, fmaxf(fmaxf(v[it][0], v[it][1]), fmaxf(v[it][2], v[it][3])));
    }
    #pragma unroll
    for (int o = 32; o >= 1; o >>= 1) mx = fmaxf(mx, __shfl_xor(mx, o, 64));
    float sum = 0.f;
    #pragma unroll
    for (int it = 0; it < 4; ++it)
        #pragma unroll
        for (int j = 0; j < 4; ++j) {
            float e = (v[it][j] > -1e29f) ? __expf(v[it][j] - mx) : 0.f;
            v[it][j] = e;
            sum += e;
        }
    #pragma unroll
    for (int o = 32; o >= 1; o >>= 1) sum += __shfl_xor(sum, o, 64);
    float inv = 1.0f / sum;
    #pragma unroll
    for (int it = 0; it < 4; ++it) {
        int k = it * 256 + kb;
        if (k < kmax) {
            uint2 d;
            d.x = (u32)f2b(v[it][0] * inv) | ((u32)f2b(v[it][1] * inv) << 16);
            d.y = (u32)f2b(v[it][2] * inv) | ((u32)f2b(v[it][3] * inv) << 16);
            *(uint2*)(row + k) = d;
        }
    }
}

// ---------------------------------------------------------------------------
// Scan-chunk prep (shared by p1/p2): raw gate logits for a 32-step chunk in
// glds (32 x 16 rows x 17 bf16 @ 34 B). Softmax each row, repack the 16
// A-entries in place to (st*16+i)*32 B (bf16), scale vlds (v -> a0*v).
// ---------------------------------------------------------------------------
__device__ __forceinline__ void scan_prep(u16* glds, float* vlds, int lane)
{
    #pragma unroll
    for (int rnd = 0; rnd < 2; ++rnd) {
        float p[4][17];
        #pragma unroll
        for (int j = 0; j < 4; ++j) {
            int r = rnd * 256 + j * 64 + lane;
            const u16* g = &glds[r * 17];
            float vv[17];
            float mx = -1e30f;
            #pragma unroll
            for (int tt = 0; tt < 17; ++tt) { vv[tt] = b2f(g[tt]); mx = fmaxf(mx, vv[tt]); }
            float s = 0.f;
            #pragma unroll
            for (int tt = 0; tt < 17; ++tt) { vv[tt] = __expf(vv[tt] - mx); s += vv[tt]; }
            float inv = 1.0f / s;
            #pragma unroll
            for (int tt = 0; tt < 17; ++tt) p[j][tt] = vv[tt] * inv;
        }
        __syncthreads();
        #pragma unroll
        for (int j = 0; j < 4; ++j) {
            int r = rnd * 256 + j * 64 + lane;
            uint4 w0, w1;
            w0.x = (u32)f2b(p[j][1])  | ((u32)f2b(p[j][2])  << 16);
            w0.y = (u32)f2b(p[j][3])  | ((u32)f2b(p[j][4])  << 16);
            w0.z = (u32)f2b(p[j][5])  | ((u32)f2b(p[j][6])  << 16);
            w0.w = (u32)f2b(p[j][7])  | ((u32)f2b(p[j][8])  << 16);
            w1.x = (u32)f2b(p[j][9])  | ((u32)f2b(p[j][10]) << 16);
            w1.y = (u32)f2b(p[j][11]) | ((u32)f2b(p[j][12]) << 16);
            w1.z = (u32)f2b(p[j][13]) | ((u32)f2b(p[j][14]) << 16);
            w1.w = (u32)f2b(p[j][15]) | ((u32)f2b(p[j][16]) << 16);
            ((uint4*)glds)[r * 2]     = w0;
            ((uint4*)glds)[r * 2 + 1] = w1;
            vlds[r] *= p[j][0];
        }
        __syncthreads();
    }
}

// ---------------------------------------------------------------------------
// scan pass 1: per chunk of 32 steps compute P_c = A_31..A_0, e_c.
// ---------------------------------------------------------------------------
__global__ __launch_bounds__(64) void scan_p1(
    const u16* __restrict__ gates, const float* __restrict__ vvT,
    float* __restrict__ Pmat, float* __restrict__ evec)
{
    const int c = blockIdx.x, chain = blockIdx.y;
    const int lane = threadIdx.x;
    const int i = lane >> 2, q = lane & 3;
    __shared__ alignas(16) u16   glds[32 * 272];
    __shared__ alignas(16) float vlds[32 * 16];
    __shared__ alignas(16) float Pb[2][256];
    __shared__ float slds[16];

    const char* gbase = (const char*)(gates + ((size_t)chain * T_ + c * 32) * 272);
    #pragma unroll
    for (int it = 0; it < 17; ++it)
        stage16(gbase + it * 1024 + lane * 16, (char*)glds + it * 1024);
    const char* vbase = (const char*)(vvT + ((size_t)chain * T_ + c * 32) * 16);
    #pragma unroll
    for (int it = 0; it < 2; ++it)
        stage16(vbase + it * 1024 + lane * 16, (char*)vlds + it * 1024);
    __syncthreads();

    scan_prep(glds, vlds, lane);

    {
        f32x4 idq;
        #pragma unroll
        for (int m = 0; m < 4; ++m) idq[m] = (i == q * 4 + m) ? 1.f : 0.f;
        *(f32x4*)&Pb[0][i * 16 + q * 4] = idq;
    }
    f32x4 e4[4] = {};
    f32x4 np = {};
    float neLast = 0.f;
    int cur = 0;

    for (int st = 0; st < 32; ++st) {
        const uint4* rp = (const uint4*)((const char*)glds + (st * 16 + i) * 32);
        uint4 d0 = rp[0], d1 = rp[1];
        float ar[16];
        ar[0]  = blo(d0.x); ar[1]  = bhi(d0.x);
        ar[2]  = blo(d0.y); ar[3]  = bhi(d0.y);
        ar[4]  = blo(d0.z); ar[5]  = bhi(d0.z);
        ar[6]  = blo(d0.w); ar[7]  = bhi(d0.w);
        ar[8]  = blo(d1.x); ar[9]  = bhi(d1.x);
        ar[10] = blo(d1.y); ar[11] = bhi(d1.y);
        ar[12] = blo(d1.z); ar[13] = bhi(d1.z);
        ar[14] = blo(d1.w); ar[15] = bhi(d1.w);

        f32x4 pk[16];
        #pragma unroll
        for (int k = 0; k < 16; ++k)
            pk[k] = *(const f32x4*)&Pb[cur][k * 16 + q * 4];

        f32x4 a = pk[0] * ar[0];
        #pragma unroll
        for (int k = 1; k < 16; ++k) a += pk[k] * ar[k];
        np = a;

        float ne0 = ar[0] * e4[0][0] + ar[1] * e4[0][1] + ar[2] * e4[0][2] + ar[3] * e4[0][3];
        float ne1 = ar[4] * e4[1][0] + ar[5] * e4[1][1] + ar[6] * e4[1][2] + ar[7] * e4[1][3];
        float ne2 = ar[8] * e4[2][0] + ar[9] * e4[2][1] + ar[10] * e4[2][2] + ar[11] * e4[2][3];
        float ne3 = ar[12] * e4[3][0] + ar[13] * e4[3][1] + ar[14] * e4[3][2] + ar[15] * e4[3][3];
        float ne = (ne0 + ne1) + (ne2 + ne3) + vlds[st * 16 + i];

        *(f32x4*)&Pb[cur ^ 1][i * 16 + q * 4] = np;
        if (q == 0) slds[i] = ne;
        #pragma unroll
        for (int m = 0; m < 4; ++m) e4[m] = *(const f32x4*)&slds[m * 4];
        neLast = ne;
        cur ^= 1;
    }

    float* Pd = Pmat + ((size_t)chain * 32 + c) * 256;
    *(f32x4*)&Pd[i * 16 + q * 4] = np;
    if (q == 0) evec[((size_t)chain * 32 + c) * 16 + i] = neLast;
}

// ---------------------------------------------------------------------------
// scan pass 2: per chain, sequentially combine 32 chunks; sIn[c] = entry state.
// ---------------------------------------------------------------------------
__global__ __launch_bounds__(64) void scan_comb(
    const float* __restrict__ Pmat, const float* __restrict__ evec, float* __restrict__ sIn)
{
    const int chain = blockIdx.x;
    const int lane = threadIdx.x;
    const int i = lane >> 2, q = lane & 3;
    __shared__ alignas(16) float Pl[32 * 256];
    __shared__ alignas(16) float El[32 * 16];
    __shared__ float slds[16];

    const char* Pg = (const char*)(Pmat + (size_t)chain * 32 * 256);
    #pragma unroll
    for (int it = 0; it < 32; ++it)
        stage16(Pg + it * 1024 + lane * 16, (char*)Pl + it * 1024);
    const char* Eg = (const char*)(evec + (size_t)chain * 32 * 16);
    #pragma unroll
    for (int it = 0; it < 2; ++it)
        stage16(Eg + it * 1024 + lane * 16, (char*)El + it * 1024);
    __syncthreads();

    f32x4 s4[4] = {};
    if (q == 0) sIn[((size_t)chain * 32 + 0) * 16 + i] = 0.f;
    for (int cc = 0; cc < 32; ++cc) {
        f32x4 pr[4];
        #pragma unroll
        for (int m = 0; m < 4; ++m)
            pr[m] = *(const f32x4*)&Pl[cc * 256 + i * 16 + m * 4];
        float ne = 0.f;
        #pragma unroll
        for (int k = 0; k < 16; ++k) ne += pr[k >> 2][k & 3] * s4[k >> 2][k & 3];
        ne += El[cc * 16 + i];
        if (q == 0) {
            slds[i] = ne;
            if (cc < 31) sIn[((size_t)chain * 32 + cc + 1) * 16 + i] = ne;
        }
        #pragma unroll
        for (int m = 0; m < 4; ++m) s4[m] = *(const f32x4*)&slds[m * 4];
    }
}

// ---------------------------------------------------------------------------
// scan pass 3: replay each chunk from its entry state, write h_out.
// ---------------------------------------------------------------------------
__global__ __launch_bounds__(64) void scan_p2(
    const u16* __restrict__ gates, const float* __restrict__ vvT,
    const float* __restrict__ sIn, u16* __restrict__ hout)
{
    const int c = blockIdx.x, chain = blockIdx.y;
    const int b = chain >> 6, hh = chain & 63;
    const int lane = threadIdx.x;
    const int i = lane >> 2, q = lane & 3;
    __shared__ alignas(16) u16   glds[32 * 272];
    __shared__ alignas(16) float vlds[32 * 16];
    __shared__ float slds[16];

    const char* gbase = (const char*)(gates + ((size_t)chain * T_ + c * 32) * 272);
    #pragma unroll
    for (int it = 0; it < 17; ++it)
        stage16(gbase + it * 1024 + lane * 16, (char*)glds + it * 1024);
    const char* vbase = (const char*)(vvT + ((size_t)chain * T_ + c * 32) * 16);
    #pragma unroll
    for (int it = 0; it < 2; ++it)
        stage16(vbase + it * 1024 + lane * 16, (char*)vlds + it * 1024);
    __syncthreads();

    scan_prep(glds, vlds, lane);

    const float* sp = sIn + ((size_t)chain * 32 + c) * 16;
    f32x4 s4[4];
    #pragma unroll
    for (int m = 0; m < 4; ++m) s4[m] = *(const f32x4*)(sp + m * 4);

    u16* hbase = hout + ((size_t)(b * T_ + c * 32)) * D_ + hh * 16;
    for (int st = 0; st < 32; ++st) {
        const uint4* rp = (const uint4*)((const char*)glds + (st * 16 + i) * 32);
        uint4 d0 = rp[0], d1 = rp[1];
        float ne0 = blo(d0.x) * s4[0][0] + bhi(d0.x) * s4[0][1]
                  + blo(d0.y) * s4[0][2] + bhi(d0.y) * s4[0][3];
        float ne1 = blo(d0.z) * s4[1][0] + bhi(d0.z) * s4[1][1]
                  + blo(d0.w) * s4[1][2] + bhi(d0.w) * s4[1][3];
        float ne2 = blo(d1.x) * s4[2][0] + bhi(d1.x) * s4[2][1]
                  + blo(d1.y) * s4[2][2] + bhi(d1.y) * s4[2][3];
        float ne3 = blo(d1.z) * s4[3][0] + bhi(d1.z) * s4[3][1]
                  + blo(d1.w) * s4[3][2] + bhi(d1.w) * s4[3][3];
        float ne = (ne0 + ne1) + (ne2 + ne3) + vlds[st * 16 + i];
        if (q == 0) {
            slds[i] = ne;
            hbase[(size_t)st * D_ + i] = f2b(ne);
        }
        #pragma unroll
        for (int m = 0; m < 4; ++m) s4[m] = *(const f32x4*)&slds[m * 4];
    }
}

// ---------------------------------------------------------------------------
extern "C" void kernel_launch(void* const* d_in, const int* in_sizes, int n_in,
                              void* d_out, int out_size, void* d_ws, size_t ws_size,
                              hipStream_t stream)
{
    const float* x    = (const float*)d_in[0];
    const float* anw  = (const float*)d_in[1];
    const float* wqkv = (const float*)d_in[2];
    const float* wao  = (const float*)d_in[3];
    const float* lnw  = (const float*)d_in[4];
    const float* wv   = (const float*)d_in[5];
    const float* wa   = (const float*)d_in[6];
    const float* wop  = (const float*)d_in[7];

    char* ws = (char*)d_ws;
    const size_t MB = 1u << 20;
    u16*   h     = (u16*)  (ws +   0 * MB);   //  4 MB
    u16*   h2    = (u16*)  (ws +   4 * MB);   //  4 MB
    u16*   wqkvT = (u16*)  (ws +   8 * MB);   //  6 MB
    u16*   waoT  = (u16*)  (ws +  14 * MB);   //  2 MB
    u16*   wopT  = (u16*)  (ws +  16 * MB);   //  2 MB
    u16*   waT   = (u16*)  (ws +  18 * MB);   // 36 MB (wa 17408 rows + wv 1024 rows)
    float* x2    = (float*)(ws +  54 * MB);   //  8 MB
    float* vvT   = (float*)(ws +  62 * MB);   //  8 MB scan layout [chain][t][16]
    u16*   Qb    = (u16*)  (ws +  78 * MB);   //  4 MB (dead after QK^T)
    float* Pmat  = (float*)(ws +  78 * MB);   //  4 MB aliases Qb
    u16*   Kb    = (u16*)  (ws +  82 * MB);   //  4 MB (dead after QK^T)
    float* evec  = (float*)(ws +  82 * MB);   // 256 KB aliases Kb
    float* sIn   = (float*)(ws +  82 * MB + 256 * 1024); // 256 KB
    u16*   Vb    = (u16*)  (ws +  86 * MB);   //  4 MB (dead after transpose)
    u16*   Vt    = (u16*)  (ws +  90 * MB);   //  4 MB (dead after PV)
    u16*   S     = (u16*)  (ws +  94 * MB);   // 64 MB (dead after PV)
    u16*   omat  = (u16*)  (ws + 158 * MB);   //  4 MB (dead after attn_out)
    u16*   gates = (u16*)  (ws +  94 * MB);   // 68 MB aliases S+omat
    u16*   hout  = (u16*)  (ws + 162 * MB);   //  4 MB (end: 166 MB)
    (void)in_sizes; (void)n_in; (void)out_size; (void)ws_size;

    dim3 tb(32, 8);
    convT_all<<<dim3(736, 32), tb, 0, stream>>>(
        wqkv, wao, wv, wa, wop, wqkvT, waoT, waT, wopT);

    rmsnorm_k<<<2048, 256, 0, stream>>>(x, anw, h);
    // qkv GEMM with fused RoPE epilogue -> Qb, Kb, Vb directly (BK=64 now)
    gemm_bt<64, 128, 64, 6, false, false, 0><<<dim3(24, 32, 1), 256, 0, stream>>>(
        h, wqkvT, (void*)Qb, (void*)Kb, (void*)Vb, nullptr, 2048, 3072, 1024, 0, 0, 0);
    transpose_bf16_k<<<dim3(2, 32, 32), tb, 0, stream>>>(Vb, Vt, 1024, 64);

    // QK^T: K=64 -> single staging round per block
    gemm_bt<128, 128, 64, 1, false, true, 0><<<dim3(8, 8, 32), 256, 0, stream>>>(
        Qb, Kb, (void*)S, nullptr, nullptr, nullptr, 1024, 1024, 64, 65536, 65536, 1048576);
    softmax_causal_k<<<8192, 256, 0, stream>>>(S);
    // PV: BM=64, BK=64
    gemm_bt<64, 64, 64, 2, true, false, 0><<<dim3(1, 16, 32), 256, 0, stream>>>(
        S, Vt, (void*)omat, nullptr, nullptr, nullptr, 1024, 64, 1024, 1048576, 65536, 0);

    gemm_bt<64, 128, 64, 0, false, false, 0><<<dim3(8, 32, 1), 256, 0, stream>>>(
        omat, waoT, (void*)x2, nullptr, nullptr, x, 2048, 1024, 1024, 0, 0, 0);
    rmsnorm_k<<<2048, 256, 0, stream>>>(x2, lnw, h2);

    // fused gates + w_v GEMM: m97-structure 128x192, 1536 blocks, 3 blocks/CU
    gemm_gates128<<<dim3(96, 16), 256, 0, stream>>>(h2, waT, gates, vvT);

    scan_p1<<<dim3(32, 128), 64, 0, stream>>>(gates, vvT, Pmat, evec);
    scan_comb<<<128, 64, 0, stream>>>(Pmat, evec, sIn);
    scan_p2<<<dim3(32, 128), 64, 0, stream>>>(gates, vvT, sIn, hout);

    gemm_bt<64, 128, 64, 0, false, false, 0><<<dim3(8, 32, 1), 256, 0, stream>>>(
        hout, wopT, d_out, nullptr, nullptr, x2, 2048, 1024, 1024, 0, 0, 0);
}

// Round 8
// 481.437 us; speedup vs baseline: 1.0722x; 1.0722x over previous
//
#include <hip/hip_runtime.h>

// HKSABlock on MI355X (gfx950). Round 14: exact revert to R12 (measured
// 475.8 us total; gates GEMM 93.5 us / 827 TF / MfmaUtil 36.4%). R13's
// gemm_bt rewrite coincided with an unexplained -34% regression on the
// BYTE-IDENTICAL gemm_gates128 kernel (env/power-profile shift vs
// co-compilation drift — two confounds). This revert is the controlled
// re-anchor: R12 config, no other changes.
// B=2, T=1024, D=1024, NH=16, HD=64, H=64, M=16.

typedef unsigned short u16;
typedef unsigned int   u32;
typedef __bf16 bf16x8 __attribute__((ext_vector_type(8)));
typedef float  f32x4  __attribute__((ext_vector_type(4)));

#define B_  2
#define T_  1024
#define D_  1024
#define NH_ 16
#define HD_ 64
#define H_  64
#define M_  16

__device__ __forceinline__ float b2f(u16 u) {
    return __uint_as_float(((u32)u) << 16);
}
__device__ __forceinline__ u16 f2b(float f) {
    u32 u = __float_as_uint(f);
    u32 r = (u + 0x7FFFu + ((u >> 16) & 1u)) >> 16;  // RNE
    return (u16)r;
}
__device__ __forceinline__ float blo(u32 u) { return __uint_as_float(u << 16); }
__device__ __forceinline__ float bhi(u32 u) { return __uint_as_float(u & 0xFFFF0000u); }

// Async global->LDS, 16 B per lane. LDS dest must be wave-uniform base.
__device__ __forceinline__ void stage16(const void* gp, void* lp) {
    typedef __attribute__((address_space(1))) const unsigned int GU;
    typedef __attribute__((address_space(3))) unsigned int LU;
    __builtin_amdgcn_global_load_lds((GU*)gp, (LU*)lp, 16, 0, 0);
}

// ---------------------------------------------------------------------------
// Generic MFMA GEMM: C[M,N] = A[M,K] * Bt[N,K]^T  (A,Bt bf16 row-major).
// 4 waves: wr = w>>1 (m-half), wc = w&1 (n-half). MT = BM/32, NT = BN/32.
// MODE 0: C fp32 (+ optional fp32 addend). MODE 1: C bf16.
// MODE 2: bf16 scatter into o_mat[(b*T + row)*1024 + h*64 + col], z = b*16+h.
// MODE 6: qkv + fused RoPE. N=3072; region = n0>>10 (0=Q,1=K,2=V). Each wave
//         owns one head's 64 cols; RoPE pair (i,i+32) = acc nt and nt+2.
//         Writes Qb(Cout)/Kb(Cout2)/Vb(Cout3) bf16 in (b,h,t,d).
// CAUSAL: skip blocks with n0 > m0+BM-1. TRUNCK: K truncated to m0+BM.
// ---------------------------------------------------------------------------
template<int BM, int BN, int BK, int MODE, bool TRUNCK, bool CAUSAL, int SWZ>
__global__ __launch_bounds__(256) void gemm_bt(
    const u16* __restrict__ A, const u16* __restrict__ Bt,
    void* __restrict__ Cout, void* __restrict__ Cout2, void* __restrict__ Cout3,
    const float* __restrict__ addend,
    int M, int N, int K, long strideA, long strideB, long strideC)
{
    constexpr int MT = BM / 32;
    constexpr int NT = BN / 32;
    constexpr int KCH = BK / 8;                  // 16B slots per row
    const int z  = blockIdx.z;
    int bx = blockIdx.x, by = blockIdx.y;
    if (SWZ == 2) {
        int f = by * gridDim.x + bx;
        int xcd = f & 7, k = f >> 3;
        by = k & 15;                             // by innermost per XCD
        bx = xcd * (gridDim.x >> 3) + (k >> 4);  // band per XCD
    }
    const int m0 = by * BM;
    const int n0 = bx * BN;
    if (CAUSAL && n0 > m0 + BM - 1) return;
    const int Keff = TRUNCK ? (K < m0 + BM ? K : m0 + BM) : K;

    const u16* Ab = A  + (size_t)z * (size_t)strideA;
    const u16* Bb = Bt + (size_t)z * (size_t)strideB;

    __shared__ alignas(16) u16 As[BM * BK];
    __shared__ alignas(16) u16 Bs[BN * BK];

    const int tid  = threadIdx.x;
    const int lane = tid & 63, w = tid >> 6;
    const int wr = w >> 1, wc = w & 1;
    const int quad = lane >> 4, l16 = lane & 15;

    f32x4 acc[MT][NT] = {};

    constexpr int AITER = (BM * BK / 8) / 256;
    constexpr int BITER = (BN * BK / 8) / 256;

    for (int k0 = 0; k0 < Keff; k0 += BK) {
        #pragma unroll
        for (int it = 0; it < AITER; ++it) {
            int c = it * 256 + tid;
            int m = c / KCH, kc = c % KCH;
            stage16(Ab + (size_t)(m0 + m) * K + k0 + kc * 8,
                    &As[(it * 256 + w * 64) * 8]);
        }
        #pragma unroll
        for (int it = 0; it < BITER; ++it) {
            int c = it * 256 + tid;
            int n = c / KCH, kc = c % KCH;
            stage16(Bb + (size_t)(n0 + n) * K + k0 + kc * 8,
                    &Bs[(it * 256 + w * 64) * 8]);
        }
        __syncthreads();

        #pragma unroll
        for (int kk = 0; kk < BK; kk += 32) {
            bf16x8 af[MT], bfr[NT];
            #pragma unroll
            for (int mt = 0; mt < MT; ++mt)
                af[mt] = *(const bf16x8*)&As[(wr * (BM / 2) + mt * 16 + l16) * BK + kk + quad * 8];
            #pragma unroll
            for (int nt = 0; nt < NT; ++nt)
                bfr[nt] = *(const bf16x8*)&Bs[(wc * (BN / 2) + nt * 16 + l16) * BK + kk + quad * 8];
            #pragma unroll
            for (int mt = 0; mt < MT; ++mt)
                #pragma unroll
                for (int nt = 0; nt < NT; ++nt)
                    acc[mt][nt] = __builtin_amdgcn_mfma_f32_16x16x32_bf16(
                        af[mt], bfr[nt], acc[mt][nt], 0, 0, 0);
        }
        __syncthreads();
    }

    // Epilogue. C/D layout: col = lane&15, row = (lane>>4)*4 + reg  [m89]
    if (MODE == 6) {
        // dedicated RoPE epilogue (NT==4, BN==128 required)
        const int reg = n0 >> 10;                      // 0=Q, 1=K, 2=V
        const int hh  = ((n0 & 1023) >> 6) + wc;       // head
        #pragma unroll
        for (int mt = 0; mt < MT; ++mt) {
            #pragma unroll
            for (int r = 0; r < 4; ++r) {
                int row = m0 + wr * (BM / 2) + mt * 16 + quad * 4 + r;
                int t = row & (T_ - 1), bb = row >> 10;
                size_t obase = ((size_t)(bb * NH_ + hh) * T_ + t) * HD_;
                if (reg == 2) {
                    #pragma unroll
                    for (int nt = 0; nt < 4; ++nt)
                        ((u16*)Cout3)[obase + nt * 16 + l16] = f2b(acc[mt][nt][r]);
                } else {
                    u16* dst = (reg == 0) ? (u16*)Cout : (u16*)Cout2;
                    #pragma unroll
                    for (int nt = 0; nt < 2; ++nt) {
                        int i = nt * 16 + l16;
                        float ang = (float)t * exp2f(-(float)i * 0.41524101186092034f);
                        float sn, cs;
                        sincosf(ang, &sn, &cs);
                        float q1 = acc[mt][nt][r], q2 = acc[mt][nt + 2][r];
                        dst[obase + i]      = f2b(q1 * cs - q2 * sn);
                        dst[obase + i + 32] = f2b(q2 * cs + q1 * sn);
                    }
                }
            }
        }
        return;
    }
    #pragma unroll
    for (int mt = 0; mt < MT; ++mt) {
        #pragma unroll
        for (int nt = 0; nt < NT; ++nt) {
            #pragma unroll
            for (int r = 0; r < 4; ++r) {
                int row = m0 + wr * (BM / 2) + mt * 16 + quad * 4 + r;
                int col = n0 + wc * (BN / 2) + nt * 16 + l16;
                float val = acc[mt][nt][r];
                if (MODE == 0) {
                    if (addend) val += addend[(size_t)row * N + col];
                    ((float*)Cout)[(size_t)z * (size_t)strideC + (size_t)row * N + col] = val;
                } else if (MODE == 1) {
                    ((u16*)Cout)[(size_t)z * (size_t)strideC + (size_t)row * N + col] = f2b(val);
                } else if (MODE == 2) {
                    size_t idx = ((size_t)(z >> 4) * T_ + row) * (size_t)D_ + (z & 15) * HD_ + col;
                    ((u16*)Cout)[idx] = f2b(val);
                }
            }
        }
    }
}

// ---------------------------------------------------------------------------
// gates+w_v GEMM: C[2048,18432] = h2[2048,1024] x waT[18432,1024]^T.
// m97-structure port: 128x192 tile, BK=64, 256 threads (4 waves 2x2, wave
// tile 64x96), single-buffered LDS 40 KB, 3 blocks/CU (launch_bounds cap).
// Grid 96x16 = 1536 blocks = 2 exact fill-waves of 768 co-resident.
// Schedule per K-tile: 10x stage16 -> __syncthreads (vmcnt drain) ->
// 2 ksteps {4+6 ds_read_b128, 24 MFMA} -> __syncthreads. TLP (12 waves/CU)
// covers the drain; no hand vmcnt, no setprio.
// Swizzle: 16B slot phys = logical ^ (row&7); inverse-swizzled global
// source + swizzled ds_read (0 bank conflicts, verified R9-R12).
// Epilogue: cg<1088 -> gates [chain][t][272] bf16; else vvT fp32.
// ---------------------------------------------------------------------------
__global__ __launch_bounds__(256, 3) void gemm_gates128(
    const u16* __restrict__ A, const u16* __restrict__ Bt,
    u16* __restrict__ gates, float* __restrict__ vvT)
{
    constexpr int K = 1024;
    constexpr int NTILE = 16;                    // K / 64

    // bijective XCD swizzle: 1536 blocks, 192/XCD = 12 bx x 16 by, by innermost
    const int f = blockIdx.y * gridDim.x + blockIdx.x;
    const int xcd = f & 7, k8 = f >> 3;          // k8 in [0,192)
    const int by = k8 & 15;
    const int bx = xcd * 12 + (k8 >> 4);
    const int m0 = by * 128;
    const int n0 = bx * 192;

    __shared__ alignas(16) u16 As[128 * 64];     // 16 KB
    __shared__ alignas(16) u16 Bs[192 * 64];     // 24 KB

    const int tid  = threadIdx.x;                // 0..255
    const int lane = tid & 63, w = tid >> 6;     // 4 waves
    const int wr = w >> 1, wc = w & 1;           // 2 x 2 wave grid
    const int quad = lane >> 4, l16 = lane & 15;

    // staging: thread t -> row (t>>3) within each 32-row call group, physical
    // 16B slot (t&7); global source slot = (t&7) ^ (row&7)  (involution).
    const int colOff = (((tid & 7) ^ ((tid >> 3) & 7)) * 8);
    const u16* pA = A  + (size_t)(m0 + (tid >> 3)) * K + colOff;
    const u16* pB = Bt + (size_t)(n0 + (tid >> 3)) * K + colOff;
    const int wbase = w * 512;                   // wave-uniform LDS dest (u16)

    // ds-read bases (u16): row*64 + phys_slot*8; phys = (kstep*4+quad)^(l16&7)
    const int sq0 = quad ^ (l16 & 7);
    const int sq1 = sq0 ^ 4;
    const int aoff0 = (wr * 64 + l16) * 64 + sq0 * 8;
    const int aoff1 = (wr * 64 + l16) * 64 + sq1 * 8;
    const int boff0 = (wc * 96 + l16) * 64 + sq0 * 8;
    const int boff1 = (wc * 96 + l16) * 64 + sq1 * 8;

    f32x4 acc[4][6] = {};                        // [mt][nt] wave tile 64x96

    #pragma unroll 1
    for (int t = 0; t < NTILE; ++t) {
        const int kc = t * 64;
        // stage A (4 calls x 32 rows) + B (6 calls x 32 rows)
        #pragma unroll
        for (int c = 0; c < 4; ++c)
            stage16(pA + (size_t)(c * 32) * K + kc, &As[c * 2048 + wbase]);
        #pragma unroll
        for (int c = 0; c < 6; ++c)
            stage16(pB + (size_t)(c * 32) * K + kc, &Bs[c * 2048 + wbase]);
        __syncthreads();

        bf16x8 af[4], bfr[6];
        // kstep 0 (k 0..31)
        #pragma unroll
        for (int mt = 0; mt < 4; ++mt) af[mt]  = *(const bf16x8*)&As[aoff0 + mt * 1024];
        #pragma unroll
        for (int nt = 0; nt < 6; ++nt) bfr[nt] = *(const bf16x8*)&Bs[boff0 + nt * 1024];
        #pragma unroll
        for (int mt = 0; mt < 4; ++mt)
            #pragma unroll
            for (int nt = 0; nt < 6; ++nt)
                acc[mt][nt] = __builtin_amdgcn_mfma_f32_16x16x32_bf16(
                    af[mt], bfr[nt], acc[mt][nt], 0, 0, 0);
        // kstep 1 (k 32..63)
        #pragma unroll
        for (int mt = 0; mt < 4; ++mt) af[mt]  = *(const bf16x8*)&As[aoff1 + mt * 1024];
        #pragma unroll
        for (int nt = 0; nt < 6; ++nt) bfr[nt] = *(const bf16x8*)&Bs[boff1 + nt * 1024];
        #pragma unroll
        for (int mt = 0; mt < 4; ++mt)
            #pragma unroll
            for (int nt = 0; nt < 6; ++nt)
                acc[mt][nt] = __builtin_amdgcn_mfma_f32_16x16x32_bf16(
                    af[mt], bfr[nt], acc[mt][nt], 0, 0, 0);
        __syncthreads();
    }

    // Epilogue: row = m0 + wr*64 + mt*16 + quad*4 + r
    //           col-group cg = bx*12 + wc*6 + nt (lane-uniform), col = cg*16+l16
    const int cgbase = bx * 12 + wc * 6;
    #pragma unroll
    for (int mt = 0; mt < 4; ++mt) {
        #pragma unroll
        for (int r = 0; r < 4; ++r) {
            int row = m0 + wr * 64 + mt * 16 + quad * 4 + r;
            int tt = row & (T_ - 1), bb = row >> 10;
            #pragma unroll
            for (int nt = 0; nt < 6; ++nt) {
                int cg = cgbase + nt;
                float val = acc[mt][nt][r];
                if (cg >= 1088) {
                    vvT[(((size_t)(bb * 64 + (cg - 1088))) * T_ + tt) * 16 + l16] = val;
                } else {
                    int hh = cg / 17, rem = cg - hh * 17;
                    gates[(((size_t)(bb * 64 + hh)) * T_ + tt) * 272 + rem * 16 + l16] = f2b(val);
                }
            }
        }
    }
}

// ---------------------------------------------------------------------------
__global__ __launch_bounds__(256) void rmsnorm_k(
    const float* __restrict__ x, const float* __restrict__ w, u16* __restrict__ out)
{
    const int row = blockIdx.x, tid = threadIdx.x;
    float4 v = ((const float4*)(x + (size_t)row * D_))[tid];
    float ss = v.x * v.x + v.y * v.y + v.z * v.z + v.w * v.w;
    #pragma unroll
    for (int o = 32; o >= 1; o >>= 1) ss += __shfl_xor(ss, o, 64);
    __shared__ float red[4];
    if ((tid & 63) == 0) red[tid >> 6] = ss;
    __syncthreads();
    ss = red[0] + red[1] + red[2] + red[3];
    float scale = rsqrtf(ss * (1.0f / D_) + 1e-5f);
    float4 wv = ((const float4*)w)[tid];
    ushort4 o4;
    o4.x = f2b(v.x * scale * wv.x);
    o4.y = f2b(v.y * scale * wv.y);
    o4.z = f2b(v.z * scale * wv.z);
    o4.w = f2b(v.w * scale * wv.w);
    ((ushort4*)(out + (size_t)row * D_))[tid] = o4;
}

// ---------------------------------------------------------------------------
// All weight converts in one launch. Segments by blockIdx.x (all R=1024):
//   [0,96)   wqkv C=3072 -> wqkvT
//   [96,128) wao  C=1024 -> waoT
//   [128,160)wv   C=1024 -> waT + 17408*1024 (contiguous with waT)
//   [160,704)wa   C=17408-> waT
//   [704,736)wop  C=1024 -> wopT
// ---------------------------------------------------------------------------
__global__ void convT_all(
    const float* __restrict__ wqkv, const float* __restrict__ wao,
    const float* __restrict__ wv,   const float* __restrict__ wa,
    const float* __restrict__ wop,
    u16* __restrict__ wqkvT, u16* __restrict__ waoT,
    u16* __restrict__ waT,   u16* __restrict__ wopT)
{
    const int x = blockIdx.x;
    const float* in; u16* out; int C, xb;
    if (x < 96)       { in = wqkv; out = wqkvT; C = 3072;  xb = x; }
    else if (x < 128) { in = wao;  out = waoT;  C = 1024;  xb = x - 96; }
    else if (x < 160) { in = wv;   out = waT + (size_t)17408 * 1024; C = 1024; xb = x - 128; }
    else if (x < 704) { in = wa;   out = waT;   C = 17408; xb = x - 160; }
    else              { in = wop;  out = wopT;  C = 1024;  xb = x - 704; }
    constexpr int R = 1024;
    __shared__ float tile[32][33];
    const int c0 = xb * 32, r0 = blockIdx.y * 32;
    const int tx = threadIdx.x, ty = threadIdx.y;
    #pragma unroll
    for (int k = 0; k < 4; ++k)
        tile[ty + 8 * k][tx] = in[(size_t)(r0 + ty + 8 * k) * C + c0 + tx];
    __syncthreads();
    #pragma unroll
    for (int k = 0; k < 4; ++k)
        out[(size_t)(c0 + ty + 8 * k) * R + r0 + tx] = f2b(tile[tx][ty + 8 * k]);
}

__global__ void transpose_bf16_k(const u16* __restrict__ in_, u16* __restrict__ out_, int R, int C)
{
    __shared__ u16 tile[32][33];
    const u16* in = in_ + (size_t)blockIdx.z * R * C;
    u16* out      = out_ + (size_t)blockIdx.z * R * C;
    const int c0 = blockIdx.x * 32, r0 = blockIdx.y * 32;
    const int tx = threadIdx.x, ty = threadIdx.y;
    #pragma unroll
    for (int k = 0; k < 4; ++k)
        tile[ty + 8 * k][tx] = in[(size_t)(r0 + ty + 8 * k) * C + c0 + tx];
    __syncthreads();
    #pragma unroll
    for (int k = 0; k < 4; ++k)
        out[(size_t)(c0 + ty + 8 * k) * R + r0 + tx] = tile[tx][ty + 8 * k];
}

// ---------------------------------------------------------------------------
// Causal softmax, wave-per-row (4 rows/block). Only k < kmax = roundup(t+1,64)
// is read/written (PV's TRUNCK reads exactly that range).
// ---------------------------------------------------------------------------
__global__ __launch_bounds__(256) void softmax_causal_k(u16* __restrict__ S)
{
    const int w = threadIdx.x >> 6, lane = threadIdx.x & 63;
    const int z = blockIdx.x * 4 + w;
    const int t = z & (T_ - 1);
    u16* row = S + (size_t)z * T_;
    const int n = t + 1;
    const int kmax = (t & ~63) + 64;
    const int kb = lane * 4;
    float v[4][4];
    float mx = -1e30f;
    #pragma unroll
    for (int it = 0; it < 4; ++it) {
        int k = it * 256 + kb;
        if (k < kmax) {
            uint2 d = *(const uint2*)(row + k);
            v[it][0] = (k + 0 < n) ? blo(d.x) * 0.125f : -1e30f;
            v[it][1] = (k + 1 < n) ? bhi(d.x) * 0.125f : -1e30f;
            v[it][2] = (k + 2 < n) ? blo(d.y) * 0.125f : -1e30f;
            v[it][3] = (k + 3 < n) ? bhi(d.y) * 0.125f : -1e30f;
        } else {
            v[it][0] = v[it][1] = v[it][2] = v[it][3] = -1e30f;
        }
        mx = fmaxf(mx, fmaxf(fmaxf(v[it][0], v[it][1]), fmaxf(v[it][2], v[it][3])));
    }
    #pragma unroll
    for (int o = 32; o >= 1; o >>= 1) mx = fmaxf(mx, __shfl_xor(mx, o, 64));
    float sum = 0.f;
    #pragma unroll
    for (int it = 0; it < 4; ++it)
        #pragma unroll
        for (int j = 0; j < 4; ++j) {
            float e = (v[it][j] > -1e29f) ? __expf(v[it][j] - mx) : 0.f;
            v[it][j] = e;
            sum += e;
        }
    #pragma unroll
    for (int o = 32; o >= 1; o >>= 1) sum += __shfl_xor(sum, o, 64);
    float inv = 1.0f / sum;
    #pragma unroll
    for (int it = 0; it < 4; ++it) {
        int k = it * 256 + kb;
        if (k < kmax) {
            uint2 d;
            d.x = (u32)f2b(v[it][0] * inv) | ((u32)f2b(v[it][1] * inv) << 16);
            d.y = (u32)f2b(v[it][2] * inv) | ((u32)f2b(v[it][3] * inv) << 16);
            *(uint2*)(row + k) = d;
        }
    }
}

// ---------------------------------------------------------------------------
// Scan-chunk prep (shared by p1/p2): raw gate logits for a 32-step chunk in
// glds (32 x 16 rows x 17 bf16 @ 34 B). Softmax each row, repack the 16
// A-entries in place to (st*16+i)*32 B (bf16), scale vlds (v -> a0*v).
// ---------------------------------------------------------------------------
__device__ __forceinline__ void scan_prep(u16* glds, float* vlds, int lane)
{
    #pragma unroll
    for (int rnd = 0; rnd < 2; ++rnd) {
        float p[4][17];
        #pragma unroll
        for (int j = 0; j < 4; ++j) {
            int r = rnd * 256 + j * 64 + lane;
            const u16* g = &glds[r * 17];
            float vv[17];
            float mx = -1e30f;
            #pragma unroll
            for (int tt = 0; tt < 17; ++tt) { vv[tt] = b2f(g[tt]); mx = fmaxf(mx, vv[tt]); }
            float s = 0.f;
            #pragma unroll
            for (int tt = 0; tt < 17; ++tt) { vv[tt] = __expf(vv[tt] - mx); s += vv[tt]; }
            float inv = 1.0f / s;
            #pragma unroll
            for (int tt = 0; tt < 17; ++tt) p[j][tt] = vv[tt] * inv;
        }
        __syncthreads();
        #pragma unroll
        for (int j = 0; j < 4; ++j) {
            int r = rnd * 256 + j * 64 + lane;
            uint4 w0, w1;
            w0.x = (u32)f2b(p[j][1])  | ((u32)f2b(p[j][2])  << 16);
            w0.y = (u32)f2b(p[j][3])  | ((u32)f2b(p[j][4])  << 16);
            w0.z = (u32)f2b(p[j][5])  | ((u32)f2b(p[j][6])  << 16);
            w0.w = (u32)f2b(p[j][7])  | ((u32)f2b(p[j][8])  << 16);
            w1.x = (u32)f2b(p[j][9])  | ((u32)f2b(p[j][10]) << 16);
            w1.y = (u32)f2b(p[j][11]) | ((u32)f2b(p[j][12]) << 16);
            w1.z = (u32)f2b(p[j][13]) | ((u32)f2b(p[j][14]) << 16);
            w1.w = (u32)f2b(p[j][15]) | ((u32)f2b(p[j][16]) << 16);
            ((uint4*)glds)[r * 2]     = w0;
            ((uint4*)glds)[r * 2 + 1] = w1;
            vlds[r] *= p[j][0];
        }
        __syncthreads();
    }
}

// ---------------------------------------------------------------------------
// scan pass 1: per chunk of 32 steps compute P_c = A_31..A_0, e_c.
// ---------------------------------------------------------------------------
__global__ __launch_bounds__(64) void scan_p1(
    const u16* __restrict__ gates, const float* __restrict__ vvT,
    float* __restrict__ Pmat, float* __restrict__ evec)
{
    const int c = blockIdx.x, chain = blockIdx.y;
    const int lane = threadIdx.x;
    const int i = lane >> 2, q = lane & 3;
    __shared__ alignas(16) u16   glds[32 * 272];
    __shared__ alignas(16) float vlds[32 * 16];
    __shared__ alignas(16) float Pb[2][256];
    __shared__ float slds[16];

    const char* gbase = (const char*)(gates + ((size_t)chain * T_ + c * 32) * 272);
    #pragma unroll
    for (int it = 0; it < 17; ++it)
        stage16(gbase + it * 1024 + lane * 16, (char*)glds + it * 1024);
    const char* vbase = (const char*)(vvT + ((size_t)chain * T_ + c * 32) * 16);
    #pragma unroll
    for (int it = 0; it < 2; ++it)
        stage16(vbase + it * 1024 + lane * 16, (char*)vlds + it * 1024);
    __syncthreads();

    scan_prep(glds, vlds, lane);

    {
        f32x4 idq;
        #pragma unroll
        for (int m = 0; m < 4; ++m) idq[m] = (i == q * 4 + m) ? 1.f : 0.f;
        *(f32x4*)&Pb[0][i * 16 + q * 4] = idq;
    }
    f32x4 e4[4] = {};
    f32x4 np = {};
    float neLast = 0.f;
    int cur = 0;

    for (int st = 0; st < 32; ++st) {
        const uint4* rp = (const uint4*)((const char*)glds + (st * 16 + i) * 32);
        uint4 d0 = rp[0], d1 = rp[1];
        float ar[16];
        ar[0]  = blo(d0.x); ar[1]  = bhi(d0.x);
        ar[2]  = blo(d0.y); ar[3]  = bhi(d0.y);
        ar[4]  = blo(d0.z); ar[5]  = bhi(d0.z);
        ar[6]  = blo(d0.w); ar[7]  = bhi(d0.w);
        ar[8]  = blo(d1.x); ar[9]  = bhi(d1.x);
        ar[10] = blo(d1.y); ar[11] = bhi(d1.y);
        ar[12] = blo(d1.z); ar[13] = bhi(d1.z);
        ar[14] = blo(d1.w); ar[15] = bhi(d1.w);

        f32x4 pk[16];
        #pragma unroll
        for (int k = 0; k < 16; ++k)
            pk[k] = *(const f32x4*)&Pb[cur][k * 16 + q * 4];

        f32x4 a = pk[0] * ar[0];
        #pragma unroll
        for (int k = 1; k < 16; ++k) a += pk[k] * ar[k];
        np = a;

        float ne0 = ar[0] * e4[0][0] + ar[1] * e4[0][1] + ar[2] * e4[0][2] + ar[3] * e4[0][3];
        float ne1 = ar[4] * e4[1][0] + ar[5] * e4[1][1] + ar[6] * e4[1][2] + ar[7] * e4[1][3];
        float ne2 = ar[8] * e4[2][0] + ar[9] * e4[2][1] + ar[10] * e4[2][2] + ar[11] * e4[2][3];
        float ne3 = ar[12] * e4[3][0] + ar[13] * e4[3][1] + ar[14] * e4[3][2] + ar[15] * e4[3][3];
        float ne = (ne0 + ne1) + (ne2 + ne3) + vlds[st * 16 + i];

        *(f32x4*)&Pb[cur ^ 1][i * 16 + q * 4] = np;
        if (q == 0) slds[i] = ne;
        #pragma unroll
        for (int m = 0; m < 4; ++m) e4[m] = *(const f32x4*)&slds[m * 4];
        neLast = ne;
        cur ^= 1;
    }

    float* Pd = Pmat + ((size_t)chain * 32 + c) * 256;
    *(f32x4*)&Pd[i * 16 + q * 4] = np;
    if (q == 0) evec[((size_t)chain * 32 + c) * 16 + i] = neLast;
}

// ---------------------------------------------------------------------------
// scan pass 2: per chain, sequentially combine 32 chunks; sIn[c] = entry state.
// ---------------------------------------------------------------------------
__global__ __launch_bounds__(64) void scan_comb(
    const float* __restrict__ Pmat, const float* __restrict__ evec, float* __restrict__ sIn)
{
    const int chain = blockIdx.x;
    const int lane = threadIdx.x;
    const int i = lane >> 2, q = lane & 3;
    __shared__ alignas(16) float Pl[32 * 256];
    __shared__ alignas(16) float El[32 * 16];
    __shared__ float slds[16];

    const char* Pg = (const char*)(Pmat + (size_t)chain * 32 * 256);
    #pragma unroll
    for (int it = 0; it < 32; ++it)
        stage16(Pg + it * 1024 + lane * 16, (char*)Pl + it * 1024);
    const char* Eg = (const char*)(evec + (size_t)chain * 32 * 16);
    #pragma unroll
    for (int it = 0; it < 2; ++it)
        stage16(Eg + it * 1024 + lane * 16, (char*)El + it * 1024);
    __syncthreads();

    f32x4 s4[4] = {};
    if (q == 0) sIn[((size_t)chain * 32 + 0) * 16 + i] = 0.f;
    for (int cc = 0; cc < 32; ++cc) {
        f32x4 pr[4];
        #pragma unroll
        for (int m = 0; m < 4; ++m)
            pr[m] = *(const f32x4*)&Pl[cc * 256 + i * 16 + m * 4];
        float ne = 0.f;
        #pragma unroll
        for (int k = 0; k < 16; ++k) ne += pr[k >> 2][k & 3] * s4[k >> 2][k & 3];
        ne += El[cc * 16 + i];
        if (q == 0) {
            slds[i] = ne;
            if (cc < 31) sIn[((size_t)chain * 32 + cc + 1) * 16 + i] = ne;
        }
        #pragma unroll
        for (int m = 0; m < 4; ++m) s4[m] = *(const f32x4*)&slds[m * 4];
    }
}

// ---------------------------------------------------------------------------
// scan pass 3: replay each chunk from its entry state, write h_out.
// ---------------------------------------------------------------------------
__global__ __launch_bounds__(64) void scan_p2(
    const u16* __restrict__ gates, const float* __restrict__ vvT,
    const float* __restrict__ sIn, u16* __restrict__ hout)
{
    const int c = blockIdx.x, chain = blockIdx.y;
    const int b = chain >> 6, hh = chain & 63;
    const int lane = threadIdx.x;
    const int i = lane >> 2, q = lane & 3;
    __shared__ alignas(16) u16   glds[32 * 272];
    __shared__ alignas(16) float vlds[32 * 16];
    __shared__ float slds[16];

    const char* gbase = (const char*)(gates + ((size_t)chain * T_ + c * 32) * 272);
    #pragma unroll
    for (int it = 0; it < 17; ++it)
        stage16(gbase + it * 1024 + lane * 16, (char*)glds + it * 1024);
    const char* vbase = (const char*)(vvT + ((size_t)chain * T_ + c * 32) * 16);
    #pragma unroll
    for (int it = 0; it < 2; ++it)
        stage16(vbase + it * 1024 + lane * 16, (char*)vlds + it * 1024);
    __syncthreads();

    scan_prep(glds, vlds, lane);

    const float* sp = sIn + ((size_t)chain * 32 + c) * 16;
    f32x4 s4[4];
    #pragma unroll
    for (int m = 0; m < 4; ++m) s4[m] = *(const f32x4*)(sp + m * 4);

    u16* hbase = hout + ((size_t)(b * T_ + c * 32)) * D_ + hh * 16;
    for (int st = 0; st < 32; ++st) {
        const uint4* rp = (const uint4*)((const char*)glds + (st * 16 + i) * 32);
        uint4 d0 = rp[0], d1 = rp[1];
        float ne0 = blo(d0.x) * s4[0][0] + bhi(d0.x) * s4[0][1]
                  + blo(d0.y) * s4[0][2] + bhi(d0.y) * s4[0][3];
        float ne1 = blo(d0.z) * s4[1][0] + bhi(d0.z) * s4[1][1]
                  + blo(d0.w) * s4[1][2] + bhi(d0.w) * s4[1][3];
        float ne2 = blo(d1.x) * s4[2][0] + bhi(d1.x) * s4[2][1]
                  + blo(d1.y) * s4[2][2] + bhi(d1.y) * s4[2][3];
        float ne3 = blo(d1.z) * s4[3][0] + bhi(d1.z) * s4[3][1]
                  + blo(d1.w) * s4[3][2] + bhi(d1.w) * s4[3][3];
        float ne = (ne0 + ne1) + (ne2 + ne3) + vlds[st * 16 + i];
        if (q == 0) {
            slds[i] = ne;
            hbase[(size_t)st * D_ + i] = f2b(ne);
        }
        #pragma unroll
        for (int m = 0; m < 4; ++m) s4[m] = *(const f32x4*)&slds[m * 4];
    }
}

// ---------------------------------------------------------------------------
extern "C" void kernel_launch(void* const* d_in, const int* in_sizes, int n_in,
                              void* d_out, int out_size, void* d_ws, size_t ws_size,
                              hipStream_t stream)
{
    const float* x    = (const float*)d_in[0];
    const float* anw  = (const float*)d_in[1];
    const float* wqkv = (const float*)d_in[2];
    const float* wao  = (const float*)d_in[3];
    const float* lnw  = (const float*)d_in[4];
    const float* wv   = (const float*)d_in[5];
    const float* wa   = (const float*)d_in[6];
    const float* wop  = (const float*)d_in[7];

    char* ws = (char*)d_ws;
    const size_t MB = 1u << 20;
    u16*   h     = (u16*)  (ws +   0 * MB);   //  4 MB
    u16*   h2    = (u16*)  (ws +   4 * MB);   //  4 MB
    u16*   wqkvT = (u16*)  (ws +   8 * MB);   //  6 MB
    u16*   waoT  = (u16*)  (ws +  14 * MB);   //  2 MB
    u16*   wopT  = (u16*)  (ws +  16 * MB);   //  2 MB
    u16*   waT   = (u16*)  (ws +  18 * MB);   // 36 MB (wa 17408 rows + wv 1024 rows)
    float* x2    = (float*)(ws +  54 * MB);   //  8 MB
    float* vvT   = (float*)(ws +  62 * MB);   //  8 MB scan layout [chain][t][16]
    u16*   Qb    = (u16*)  (ws +  78 * MB);   //  4 MB (dead after QK^T)
    float* Pmat  = (float*)(ws +  78 * MB);   //  4 MB aliases Qb
    u16*   Kb    = (u16*)  (ws +  82 * MB);   //  4 MB (dead after QK^T)
    float* evec  = (float*)(ws +  82 * MB);   // 256 KB aliases Kb
    float* sIn   = (float*)(ws +  82 * MB + 256 * 1024); // 256 KB
    u16*   Vb    = (u16*)  (ws +  86 * MB);   //  4 MB (dead after transpose)
    u16*   Vt    = (u16*)  (ws +  90 * MB);   //  4 MB (dead after PV)
    u16*   S     = (u16*)  (ws +  94 * MB);   // 64 MB (dead after PV)
    u16*   omat  = (u16*)  (ws + 158 * MB);   //  4 MB (dead after attn_out)
    u16*   gates = (u16*)  (ws +  94 * MB);   // 68 MB aliases S+omat
    u16*   hout  = (u16*)  (ws + 162 * MB);   //  4 MB (end: 166 MB)
    (void)in_sizes; (void)n_in; (void)out_size; (void)ws_size;

    dim3 tb(32, 8);
    convT_all<<<dim3(736, 32), tb, 0, stream>>>(
        wqkv, wao, wv, wa, wop, wqkvT, waoT, waT, wopT);

    rmsnorm_k<<<2048, 256, 0, stream>>>(x, anw, h);
    // qkv GEMM with fused RoPE epilogue -> Qb, Kb, Vb directly
    gemm_bt<64, 128, 32, 6, false, false, 0><<<dim3(24, 32, 1), 256, 0, stream>>>(
        h, wqkvT, (void*)Qb, (void*)Kb, (void*)Vb, nullptr, 2048, 3072, 1024, 0, 0, 0);
    transpose_bf16_k<<<dim3(2, 32, 32), tb, 0, stream>>>(Vb, Vt, 1024, 64);

    // QK^T: K=64 -> BK=64, single staging round per block
    gemm_bt<128, 128, 64, 1, false, true, 0><<<dim3(8, 8, 32), 256, 0, stream>>>(
        Qb, Kb, (void*)S, nullptr, nullptr, nullptr, 1024, 1024, 64, 65536, 65536, 1048576);
    softmax_causal_k<<<8192, 256, 0, stream>>>(S);
    // PV: BM=64, BK=64
    gemm_bt<64, 64, 64, 2, true, false, 0><<<dim3(1, 16, 32), 256, 0, stream>>>(
        S, Vt, (void*)omat, nullptr, nullptr, nullptr, 1024, 64, 1024, 1048576, 65536, 0);

    gemm_bt<64, 128, 32, 0, false, false, 0><<<dim3(8, 32, 1), 256, 0, stream>>>(
        omat, waoT, (void*)x2, nullptr, nullptr, x, 2048, 1024, 1024, 0, 0, 0);
    rmsnorm_k<<<2048, 256, 0, stream>>>(x2, lnw, h2);

    // fused gates + w_v GEMM: m97-structure 128x192, 1536 blocks, 3 blocks/CU
    gemm_gates128<<<dim3(96, 16), 256, 0, stream>>>(h2, waT, gates, vvT);

    scan_p1<<<dim3(32, 128), 64, 0, stream>>>(gates, vvT, Pmat, evec);
    scan_comb<<<128, 64, 0, stream>>>(Pmat, evec, sIn);
    scan_p2<<<dim3(32, 128), 64, 0, stream>>>(gates, vvT, sIn, hout);

    gemm_bt<64, 128, 32, 0, false, false, 0><<<dim3(8, 32, 1), 256, 0, stream>>>(
        hout, wopT, d_out, nullptr, nullptr, x2, 2048, 1024, 1024, 0, 0, 0);
}

// Round 9
// 454.605 us; speedup vs baseline: 1.1355x; 1.0590x over previous
//
#include <hip/hip_runtime.h>

// HKSABlock on MI355X (gfx950). Round 15: fused flash attention replaces
// QK^T + softmax + PV (3 launches, ~130 MB HBM S-traffic) with one kernel.
// Base = R12/R14 anchor (475-481 us, gates 92 us verified).
// attn_flash: block = 64 q-rows x one (b,h); 4 waves, wave owns 16 q.
//   S^T = mfma(A=K, B=Q) -> q=l16 lane-fixed, kv=mt*16+quad*4+r ->
//   softmax = 16 in-lane + 2 shfl_xor. P->bf16: 4 consecutive kv/lane ->
//   ds_write_b64 into per-wave Ps[16][64] w/ proven slot^(row&7) involution;
//   same-wave readback as A-frag (lgkmcnt only, no barrier).
//   PV: O = mfma(A=P, B=Vt), fp32 acc, online rescale via shfl.
//   Causal mask only on diagonal tile. Balanced launch: CU pairing
//   (qb+1)+(16-qb)=17 tiles. LDS 32 KB, ~110 VGPR -> 3 blocks/CU TLP.
// Everything else identical to R14.
// B=2, T=1024, D=1024, NH=16, HD=64, H=64, M=16.

typedef unsigned short u16;
typedef unsigned int   u32;
typedef __bf16 bf16x8 __attribute__((ext_vector_type(8)));
typedef float  f32x4  __attribute__((ext_vector_type(4)));

#define B_  2
#define T_  1024
#define D_  1024
#define NH_ 16
#define HD_ 64
#define H_  64
#define M_  16

__device__ __forceinline__ float b2f(u16 u) {
    return __uint_as_float(((u32)u) << 16);
}
__device__ __forceinline__ u16 f2b(float f) {
    u32 u = __float_as_uint(f);
    u32 r = (u + 0x7FFFu + ((u >> 16) & 1u)) >> 16;  // RNE
    return (u16)r;
}
__device__ __forceinline__ float blo(u32 u) { return __uint_as_float(u << 16); }
__device__ __forceinline__ float bhi(u32 u) { return __uint_as_float(u & 0xFFFF0000u); }

// Async global->LDS, 16 B per lane. LDS dest must be wave-uniform base.
__device__ __forceinline__ void stage16(const void* gp, void* lp) {
    typedef __attribute__((address_space(1))) const unsigned int GU;
    typedef __attribute__((address_space(3))) unsigned int LU;
    __builtin_amdgcn_global_load_lds((GU*)gp, (LU*)lp, 16, 0, 0);
}

// ---------------------------------------------------------------------------
// Generic MFMA GEMM: C[M,N] = A[M,K] * Bt[N,K]^T  (A,Bt bf16 row-major).
// 4 waves: wr = w>>1 (m-half), wc = w&1 (n-half). MT = BM/32, NT = BN/32.
// MODE 0: C fp32 (+ optional fp32 addend). MODE 1: C bf16.
// MODE 2: bf16 scatter into o_mat[(b*T + row)*1024 + h*64 + col], z = b*16+h.
// MODE 6: qkv + fused RoPE. N=3072; region = n0>>10 (0=Q,1=K,2=V). Each wave
//         owns one head's 64 cols; RoPE pair (i,i+32) = acc nt and nt+2.
//         Writes Qb(Cout)/Kb(Cout2)/Vb(Cout3) bf16 in (b,h,t,d).
// CAUSAL: skip blocks with n0 > m0+BM-1. TRUNCK: K truncated to m0+BM.
// ---------------------------------------------------------------------------
template<int BM, int BN, int BK, int MODE, bool TRUNCK, bool CAUSAL, int SWZ>
__global__ __launch_bounds__(256) void gemm_bt(
    const u16* __restrict__ A, const u16* __restrict__ Bt,
    void* __restrict__ Cout, void* __restrict__ Cout2, void* __restrict__ Cout3,
    const float* __restrict__ addend,
    int M, int N, int K, long strideA, long strideB, long strideC)
{
    constexpr int MT = BM / 32;
    constexpr int NT = BN / 32;
    constexpr int KCH = BK / 8;                  // 16B slots per row
    const int z  = blockIdx.z;
    int bx = blockIdx.x, by = blockIdx.y;
    if (SWZ == 2) {
        int f = by * gridDim.x + bx;
        int xcd = f & 7, k = f >> 3;
        by = k & 15;                             // by innermost per XCD
        bx = xcd * (gridDim.x >> 3) + (k >> 4);  // band per XCD
    }
    const int m0 = by * BM;
    const int n0 = bx * BN;
    if (CAUSAL && n0 > m0 + BM - 1) return;
    const int Keff = TRUNCK ? (K < m0 + BM ? K : m0 + BM) : K;

    const u16* Ab = A  + (size_t)z * (size_t)strideA;
    const u16* Bb = Bt + (size_t)z * (size_t)strideB;

    __shared__ alignas(16) u16 As[BM * BK];
    __shared__ alignas(16) u16 Bs[BN * BK];

    const int tid  = threadIdx.x;
    const int lane = tid & 63, w = tid >> 6;
    const int wr = w >> 1, wc = w & 1;
    const int quad = lane >> 4, l16 = lane & 15;

    f32x4 acc[MT][NT] = {};

    constexpr int AITER = (BM * BK / 8) / 256;
    constexpr int BITER = (BN * BK / 8) / 256;

    for (int k0 = 0; k0 < Keff; k0 += BK) {
        #pragma unroll
        for (int it = 0; it < AITER; ++it) {
            int c = it * 256 + tid;
            int m = c / KCH, kc = c % KCH;
            stage16(Ab + (size_t)(m0 + m) * K + k0 + kc * 8,
                    &As[(it * 256 + w * 64) * 8]);
        }
        #pragma unroll
        for (int it = 0; it < BITER; ++it) {
            int c = it * 256 + tid;
            int n = c / KCH, kc = c % KCH;
            stage16(Bb + (size_t)(n0 + n) * K + k0 + kc * 8,
                    &Bs[(it * 256 + w * 64) * 8]);
        }
        __syncthreads();

        #pragma unroll
        for (int kk = 0; kk < BK; kk += 32) {
            bf16x8 af[MT], bfr[NT];
            #pragma unroll
            for (int mt = 0; mt < MT; ++mt)
                af[mt] = *(const bf16x8*)&As[(wr * (BM / 2) + mt * 16 + l16) * BK + kk + quad * 8];
            #pragma unroll
            for (int nt = 0; nt < NT; ++nt)
                bfr[nt] = *(const bf16x8*)&Bs[(wc * (BN / 2) + nt * 16 + l16) * BK + kk + quad * 8];
            #pragma unroll
            for (int mt = 0; mt < MT; ++mt)
                #pragma unroll
                for (int nt = 0; nt < NT; ++nt)
                    acc[mt][nt] = __builtin_amdgcn_mfma_f32_16x16x32_bf16(
                        af[mt], bfr[nt], acc[mt][nt], 0, 0, 0);
        }
        __syncthreads();
    }

    // Epilogue. C/D layout: col = lane&15, row = (lane>>4)*4 + reg  [m89]
    if (MODE == 6) {
        // dedicated RoPE epilogue (NT==4, BN==128 required)
        const int reg = n0 >> 10;                      // 0=Q, 1=K, 2=V
        const int hh  = ((n0 & 1023) >> 6) + wc;       // head
        #pragma unroll
        for (int mt = 0; mt < MT; ++mt) {
            #pragma unroll
            for (int r = 0; r < 4; ++r) {
                int row = m0 + wr * (BM / 2) + mt * 16 + quad * 4 + r;
                int t = row & (T_ - 1), bb = row >> 10;
                size_t obase = ((size_t)(bb * NH_ + hh) * T_ + t) * HD_;
                if (reg == 2) {
                    #pragma unroll
                    for (int nt = 0; nt < 4; ++nt)
                        ((u16*)Cout3)[obase + nt * 16 + l16] = f2b(acc[mt][nt][r]);
                } else {
                    u16* dst = (reg == 0) ? (u16*)Cout : (u16*)Cout2;
                    #pragma unroll
                    for (int nt = 0; nt < 2; ++nt) {
                        int i = nt * 16 + l16;
                        float ang = (float)t * exp2f(-(float)i * 0.41524101186092034f);
                        float sn, cs;
                        sincosf(ang, &sn, &cs);
                        float q1 = acc[mt][nt][r], q2 = acc[mt][nt + 2][r];
                        dst[obase + i]      = f2b(q1 * cs - q2 * sn);
                        dst[obase + i + 32] = f2b(q2 * cs + q1 * sn);
                    }
                }
            }
        }
        return;
    }
    #pragma unroll
    for (int mt = 0; mt < MT; ++mt) {
        #pragma unroll
        for (int nt = 0; nt < NT; ++nt) {
            #pragma unroll
            for (int r = 0; r < 4; ++r) {
                int row = m0 + wr * (BM / 2) + mt * 16 + quad * 4 + r;
                int col = n0 + wc * (BN / 2) + nt * 16 + l16;
                float val = acc[mt][nt][r];
                if (MODE == 0) {
                    if (addend) val += addend[(size_t)row * N + col];
                    ((float*)Cout)[(size_t)z * (size_t)strideC + (size_t)row * N + col] = val;
                } else if (MODE == 1) {
                    ((u16*)Cout)[(size_t)z * (size_t)strideC + (size_t)row * N + col] = f2b(val);
                } else if (MODE == 2) {
                    size_t idx = ((size_t)(z >> 4) * T_ + row) * (size_t)D_ + (z & 15) * HD_ + col;
                    ((u16*)Cout)[idx] = f2b(val);
                }
            }
        }
    }
}

// ---------------------------------------------------------------------------
// Fused flash attention: omat[q][h*64+d] = softmax(QK^T * 0.125, causal) @ V.
// Block = 64 q-rows of one (b,h) chain z; 4 waves, wave w owns q [w*16,+16).
// Per kv-tile (64): S^T via mfma(A=K-frag rows kv, B=Q-frag rows q):
//   C/D: q = l16 (lane-fixed), kv = mt*16 + quad*4 + r -> row softmax =
//   in-lane over 16 + shfl_xor(16) + shfl_xor(32).
// P bf16 -> per-wave Ps[16 q][64 kv] via ds_write_b64 (4 consecutive kv per
// lane), slot swizzle phys = slot ^ (q&7); same-wave readback as A-frag
// (write h*4+(kv&3) == read kv&7, verified).  O += mfma(A=P, B=Vt-frag),
// online rescale exp(m_old-m_new) redistributed by __shfl(sc, quad*4+r).
// Causal mask only on diagonal tile kt==qb.  Balanced grid: flat f ->
// r=f>>8, u=f&255: r==0 -> (z=u>>4,      qb=u&15)
//                  r==1 -> (z=16+(u>>4), qb=15-(u&15))   (17 tiles per CU).
// LDS: Qs 8K + Ks 8K + Vs 8K + Ps 8K = 32 KB.
// ---------------------------------------------------------------------------
__global__ __launch_bounds__(256) void attn_flash(
    const u16* __restrict__ Qb, const u16* __restrict__ Kb,
    const u16* __restrict__ Vt, u16* __restrict__ omat)
{
    const int f = blockIdx.x;
    const int u = f & 255, rr2 = f >> 8;
    const int z  = (rr2 == 0) ? (u >> 4) : 16 + (u >> 4);
    const int qb = (rr2 == 0) ? (u & 15) : 15 - (u & 15);

    const u16* Qz = Qb + (size_t)z * 65536;   // [1024 t][64 d]
    const u16* Kz = Kb + (size_t)z * 65536;   // [1024 t][64 d]
    const u16* Vz = Vt + (size_t)z * 65536;   // [64 d][1024 t]

    __shared__ alignas(16) u16 Qs[64 * 64];
    __shared__ alignas(16) u16 Ks[64 * 64];
    __shared__ alignas(16) u16 Vs[64 * 64];
    __shared__ alignas(16) u16 Ps[4][16 * 64];

    const int tid  = threadIdx.x;
    const int lane = tid & 63, w = tid >> 6;
    const int quad = lane >> 4, l16 = lane & 15;

    // staging geometry (32 rows per call): thread t -> row t>>3, phys slot t&7,
    // source slot = (t&7) ^ (row&7)  (involution, 0 conflicts R9-R14).
    const int srow   = tid >> 3;
    const int colOff = (((tid & 7) ^ (srow & 7)) * 8);
    const int wbase  = w * 512;               // wave-uniform LDS dest (u16)

    // stage Q tile (rows qb*64 + srow [+32])
    #pragma unroll
    for (int c = 0; c < 2; ++c)
        stage16(Qz + (size_t)(qb * 64 + c * 32 + srow) * 64 + colOff,
                &Qs[c * 2048 + wbase]);
    __syncthreads();

    // hoist Q B-frags: rows q = w*16 + l16, k-slot = ks*4+quad (swizzled)
    const int qrow = w * 16 + l16;
    bf16x8 qf[2];
    #pragma unroll
    for (int ks = 0; ks < 2; ++ks)
        qf[ks] = *(const bf16x8*)&Qs[qrow * 64 + (((ks * 4 + quad) ^ (l16 & 7)) * 8)];

    f32x4 acc_o[4] = {};                      // O[q 16][d 64]: nt frags, fp32
    float m_run = -1e30f, l_run = 0.f;        // per lane, q = l16

    const int sq0 = (quad ^ (l16 & 7)) * 8;   // swizzled k-slot bases (u16)
    const int sq1 = ((4 + quad) ^ (l16 & 7)) * 8;

    u16* Pw = &Ps[w][0];
    // P write addr: row q=l16; frag mt covers kv mt*16+quad*4+[0,4):
    //   8B granule g = mt*4+quad -> slot s8 = g>>1, half h = g&1
    //   addr_u16 = l16*64 + ((s8 ^ (l16&7))*8 + h*4)
    int pwa[4];
    #pragma unroll
    for (int mt = 0; mt < 4; ++mt) {
        int g = mt * 4 + quad;
        pwa[mt] = l16 * 64 + (((g >> 1) ^ (l16 & 7)) * 8) + (g & 1) * 4;
    }

    for (int kt = 0; kt <= qb; ++kt) {
        __syncthreads();                      // protect Ks/Vs from prev reads
        #pragma unroll
        for (int c = 0; c < 2; ++c)
            stage16(Kz + (size_t)(kt * 64 + c * 32 + srow) * 64 + colOff,
                    &Ks[c * 2048 + wbase]);
        #pragma unroll
        for (int c = 0; c < 2; ++c)
            stage16(Vz + (size_t)(c * 32 + srow) * 1024 + kt * 64 + colOff,
                    &Vs[c * 2048 + wbase]);
        __syncthreads();                      // vmcnt drained by compiler

        // ---- S^T = K @ Q^T (per wave: kv 64 x q 16) -------------------
        f32x4 accs[4] = {};
        #pragma unroll
        for (int ks = 0; ks < 2; ++ks) {
            const int so = ks ? sq1 : sq0;
            bf16x8 af[4];
            #pragma unroll
            for (int mt = 0; mt < 4; ++mt)
                af[mt] = *(const bf16x8*)&Ks[(mt * 16 + l16) * 64 + so];
            #pragma unroll
            for (int mt = 0; mt < 4; ++mt)
                accs[mt] = __builtin_amdgcn_mfma_f32_16x16x32_bf16(
                    af[mt], qf[ks], accs[mt], 0, 0, 0);
        }

        // ---- scale + causal mask + row max (q = l16) ------------------
        float sv[4][4];
        float mx = -1e30f;
        const bool diag = (kt == qb);
        #pragma unroll
        for (int mt = 0; mt < 4; ++mt)
            #pragma unroll
            for (int r = 0; r < 4; ++r) {
                int kv = mt * 16 + quad * 4 + r;     // within tile
                float s = accs[mt][r] * 0.125f;
                if (diag && kv > qrow) s = -1e30f;   // q within tile = qrow? no:
                sv[mt][r] = s;
                mx = fmaxf(mx, s);
            }
        mx = fmaxf(mx, __shfl_xor(mx, 16, 64));
        mx = fmaxf(mx, __shfl_xor(mx, 32, 64));

        const float m_new = fmaxf(m_run, mx);
        const float sc    = __expf(m_run - m_new);

        // ---- P = exp(S - m_new), tile sum -----------------------------
        float tsum = 0.f;
        u16 pb[4][4];
        #pragma unroll
        for (int mt = 0; mt < 4; ++mt)
            #pragma unroll
            for (int r = 0; r < 4; ++r) {
                float p = (sv[mt][r] > -1e29f) ? __expf(sv[mt][r] - m_new) : 0.f;
                tsum += p;
                pb[mt][r] = f2b(p);
            }
        tsum += __shfl_xor(tsum, 16, 64);
        tsum += __shfl_xor(tsum, 32, 64);
        l_run = l_run * sc + tsum;
        m_run = m_new;

        // ---- write P tile (per-wave, b64, swizzled) -------------------
        #pragma unroll
        for (int mt = 0; mt < 4; ++mt) {
            ushort4 pk = { pb[mt][0], pb[mt][1], pb[mt][2], pb[mt][3] };
            *(ushort4*)&Pw[pwa[mt]] = pk;
        }

        // ---- rescale O by sc (per O-row q' = quad*4+r) ----------------
        #pragma unroll
        for (int r = 0; r < 4; ++r) {
            float scr = __shfl(sc, quad * 4 + r, 64);
            #pragma unroll
            for (int nt = 0; nt < 4; ++nt) acc_o[nt][r] *= scr;
        }

        // ---- O += P @ V  (A = P rows q, B = Vt rows d) ----------------
        #pragma unroll
        for (int ks = 0; ks < 2; ++ks) {
            const int so = ks ? sq1 : sq0;
            bf16x8 pf = *(const bf16x8*)&Pw[l16 * 64 + so];
            bf16x8 vf[4];
            #pragma unroll
            for (int nt = 0; nt < 4; ++nt)
                vf[nt] = *(const bf16x8*)&Vs[(nt * 16 + l16) * 64 + so];
            #pragma unroll
            for (int nt = 0; nt < 4; ++nt)
                acc_o[nt] = __builtin_amdgcn_mfma_f32_16x16x32_bf16(
                    pf, vf[nt], acc_o[nt], 0, 0, 0);
        }
    }

    // epilogue: O /= l (l indexed by q=l16 -> shfl), write omat
    const float linv = 1.0f / l_run;
    const int qg0 = qb * 64 + w * 16;
    #pragma unroll
    for (int r = 0; r < 4; ++r) {
        float li = __shfl(linv, quad * 4 + r, 64);
        int row = qg0 + quad * 4 + r;
        size_t obase = ((size_t)(z >> 4) * T_ + row) * D_ + (z & 15) * HD_;
        #pragma unroll
        for (int nt = 0; nt < 4; ++nt)
            omat[obase + nt * 16 + l16] = f2b(acc_o[nt][r] * li);
    }
}

// ---------------------------------------------------------------------------
// gates+w_v GEMM: C[2048,18432] = h2[2048,1024] x waT[18432,1024]^T.
// m97-structure (R12/R14, measured 92 us / 827 TF): 128x192 tile, BK=64,
// 256 threads (4 waves 2x2, wave tile 64x96), single-buffered LDS 40 KB,
// 3 blocks/CU, grid 96x16 = 1536 blocks = 2 exact fill-waves.
// Swizzle: 16B slot phys = logical ^ (row&7) (0 conflicts).
// Epilogue: cg<1088 -> gates [chain][t][272] bf16; else vvT fp32.
// ---------------------------------------------------------------------------
__global__ __launch_bounds__(256, 3) void gemm_gates128(
    const u16* __restrict__ A, const u16* __restrict__ Bt,
    u16* __restrict__ gates, float* __restrict__ vvT)
{
    constexpr int K = 1024;
    constexpr int NTILE = 16;                    // K / 64

    // bijective XCD swizzle: 1536 blocks, 192/XCD = 12 bx x 16 by, by innermost
    const int f = blockIdx.y * gridDim.x + blockIdx.x;
    const int xcd = f & 7, k8 = f >> 3;          // k8 in [0,192)
    const int by = k8 & 15;
    const int bx = xcd * 12 + (k8 >> 4);
    const int m0 = by * 128;
    const int n0 = bx * 192;

    __shared__ alignas(16) u16 As[128 * 64];     // 16 KB
    __shared__ alignas(16) u16 Bs[192 * 64];     // 24 KB

    const int tid  = threadIdx.x;                // 0..255
    const int lane = tid & 63, w = tid >> 6;     // 4 waves
    const int wr = w >> 1, wc = w & 1;           // 2 x 2 wave grid
    const int quad = lane >> 4, l16 = lane & 15;

    // staging: thread t -> row (t>>3) within each 32-row call group, physical
    // 16B slot (t&7); global source slot = (t&7) ^ (row&7)  (involution).
    const int colOff = (((tid & 7) ^ ((tid >> 3) & 7)) * 8);
    const u16* pA = A  + (size_t)(m0 + (tid >> 3)) * K + colOff;
    const u16* pB = Bt + (size_t)(n0 + (tid >> 3)) * K + colOff;
    const int wbase = w * 512;                   // wave-uniform LDS dest (u16)

    // ds-read bases (u16): row*64 + phys_slot*8; phys = (kstep*4+quad)^(l16&7)
    const int sq0 = quad ^ (l16 & 7);
    const int sq1 = sq0 ^ 4;
    const int aoff0 = (wr * 64 + l16) * 64 + sq0 * 8;
    const int aoff1 = (wr * 64 + l16) * 64 + sq1 * 8;
    const int boff0 = (wc * 96 + l16) * 64 + sq0 * 8;
    const int boff1 = (wc * 96 + l16) * 64 + sq1 * 8;

    f32x4 acc[4][6] = {};                        // [mt][nt] wave tile 64x96

    #pragma unroll 1
    for (int t = 0; t < NTILE; ++t) {
        const int kc = t * 64;
        // stage A (4 calls x 32 rows) + B (6 calls x 32 rows)
        #pragma unroll
        for (int c = 0; c < 4; ++c)
            stage16(pA + (size_t)(c * 32) * K + kc, &As[c * 2048 + wbase]);
        #pragma unroll
        for (int c = 0; c < 6; ++c)
            stage16(pB + (size_t)(c * 32) * K + kc, &Bs[c * 2048 + wbase]);
        __syncthreads();

        bf16x8 af[4], bfr[6];
        // kstep 0 (k 0..31)
        #pragma unroll
        for (int mt = 0; mt < 4; ++mt) af[mt]  = *(const bf16x8*)&As[aoff0 + mt * 1024];
        #pragma unroll
        for (int nt = 0; nt < 6; ++nt) bfr[nt] = *(const bf16x8*)&Bs[boff0 + nt * 1024];
        #pragma unroll
        for (int mt = 0; mt < 4; ++mt)
            #pragma unroll
            for (int nt = 0; nt < 6; ++nt)
                acc[mt][nt] = __builtin_amdgcn_mfma_f32_16x16x32_bf16(
                    af[mt], bfr[nt], acc[mt][nt], 0, 0, 0);
        // kstep 1 (k 32..63)
        #pragma unroll
        for (int mt = 0; mt < 4; ++mt) af[mt]  = *(const bf16x8*)&As[aoff1 + mt * 1024];
        #pragma unroll
        for (int nt = 0; nt < 6; ++nt) bfr[nt] = *(const bf16x8*)&Bs[boff1 + nt * 1024];
        #pragma unroll
        for (int mt = 0; mt < 4; ++mt)
            #pragma unroll
            for (int nt = 0; nt < 6; ++nt)
                acc[mt][nt] = __builtin_amdgcn_mfma_f32_16x16x32_bf16(
                    af[mt], bfr[nt], acc[mt][nt], 0, 0, 0);
        __syncthreads();
    }

    // Epilogue: row = m0 + wr*64 + mt*16 + quad*4 + r
    //           col-group cg = bx*12 + wc*6 + nt (lane-uniform), col = cg*16+l16
    const int cgbase = bx * 12 + wc * 6;
    #pragma unroll
    for (int mt = 0; mt < 4; ++mt) {
        #pragma unroll
        for (int r = 0; r < 4; ++r) {
            int row = m0 + wr * 64 + mt * 16 + quad * 4 + r;
            int tt = row & (T_ - 1), bb = row >> 10;
            #pragma unroll
            for (int nt = 0; nt < 6; ++nt) {
                int cg = cgbase + nt;
                float val = acc[mt][nt][r];
                if (cg >= 1088) {
                    vvT[(((size_t)(bb * 64 + (cg - 1088))) * T_ + tt) * 16 + l16] = val;
                } else {
                    int hh = cg / 17, rem = cg - hh * 17;
                    gates[(((size_t)(bb * 64 + hh)) * T_ + tt) * 272 + rem * 16 + l16] = f2b(val);
                }
            }
        }
    }
}

// ---------------------------------------------------------------------------
__global__ __launch_bounds__(256) void rmsnorm_k(
    const float* __restrict__ x, const float* __restrict__ w, u16* __restrict__ out)
{
    const int row = blockIdx.x, tid = threadIdx.x;
    float4 v = ((const float4*)(x + (size_t)row * D_))[tid];
    float ss = v.x * v.x + v.y * v.y + v.z * v.z + v.w * v.w;
    #pragma unroll
    for (int o = 32; o >= 1; o >>= 1) ss += __shfl_xor(ss, o, 64);
    __shared__ float red[4];
    if ((tid & 63) == 0) red[tid >> 6] = ss;
    __syncthreads();
    ss = red[0] + red[1] + red[2] + red[3];
    float scale = rsqrtf(ss * (1.0f / D_) + 1e-5f);
    float4 wv = ((const float4*)w)[tid];
    ushort4 o4;
    o4.x = f2b(v.x * scale * wv.x);
    o4.y = f2b(v.y * scale * wv.y);
    o4.z = f2b(v.z * scale * wv.z);
    o4.w = f2b(v.w * scale * wv.w);
    ((ushort4*)(out + (size_t)row * D_))[tid] = o4;
}

// ---------------------------------------------------------------------------
// All weight converts in one launch. Segments by blockIdx.x (all R=1024):
//   [0,96)   wqkv C=3072 -> wqkvT
//   [96,128) wao  C=1024 -> waoT
//   [128,160)wv   C=1024 -> waT + 17408*1024 (contiguous with waT)
//   [160,704)wa   C=17408-> waT
//   [704,736)wop  C=1024 -> wopT
// ---------------------------------------------------------------------------
__global__ void convT_all(
    const float* __restrict__ wqkv, const float* __restrict__ wao,
    const float* __restrict__ wv,   const float* __restrict__ wa,
    const float* __restrict__ wop,
    u16* __restrict__ wqkvT, u16* __restrict__ waoT,
    u16* __restrict__ waT,   u16* __restrict__ wopT)
{
    const int x = blockIdx.x;
    const float* in; u16* out; int C, xb;
    if (x < 96)       { in = wqkv; out = wqkvT; C = 3072;  xb = x; }
    else if (x < 128) { in = wao;  out = waoT;  C = 1024;  xb = x - 96; }
    else if (x < 160) { in = wv;   out = waT + (size_t)17408 * 1024; C = 1024; xb = x - 128; }
    else if (x < 704) { in = wa;   out = waT;   C = 17408; xb = x - 160; }
    else              { in = wop;  out = wopT;  C = 1024;  xb = x - 704; }
    constexpr int R = 1024;
    __shared__ float tile[32][33];
    const int c0 = xb * 32, r0 = blockIdx.y * 32;
    const int tx = threadIdx.x, ty = threadIdx.y;
    #pragma unroll
    for (int k = 0; k < 4; ++k)
        tile[ty + 8 * k][tx] = in[(size_t)(r0 + ty + 8 * k) * C + c0 + tx];
    __syncthreads();
    #pragma unroll
    for (int k = 0; k < 4; ++k)
        out[(size_t)(c0 + ty + 8 * k) * R + r0 + tx] = f2b(tile[tx][ty + 8 * k]);
}

__global__ void transpose_bf16_k(const u16* __restrict__ in_, u16* __restrict__ out_, int R, int C)
{
    __shared__ u16 tile[32][33];
    const u16* in = in_ + (size_t)blockIdx.z * R * C;
    u16* out      = out_ + (size_t)blockIdx.z * R * C;
    const int c0 = blockIdx.x * 32, r0 = blockIdx.y * 32;
    const int tx = threadIdx.x, ty = threadIdx.y;
    #pragma unroll
    for (int k = 0; k < 4; ++k)
        tile[ty + 8 * k][tx] = in[(size_t)(r0 + ty + 8 * k) * C + c0 + tx];
    __syncthreads();
    #pragma unroll
    for (int k = 0; k < 4; ++k)
        out[(size_t)(c0 + ty + 8 * k) * R + r0 + tx] = tile[tx][ty + 8 * k];
}

// ---------------------------------------------------------------------------
// Scan-chunk prep (shared by p1/p2): raw gate logits for a 32-step chunk in
// glds (32 x 16 rows x 17 bf16 @ 34 B). Softmax each row, repack the 16
// A-entries in place to (st*16+i)*32 B (bf16), scale vlds (v -> a0*v).
// ---------------------------------------------------------------------------
__device__ __forceinline__ void scan_prep(u16* glds, float* vlds, int lane)
{
    #pragma unroll
    for (int rnd = 0; rnd < 2; ++rnd) {
        float p[4][17];
        #pragma unroll
        for (int j = 0; j < 4; ++j) {
            int r = rnd * 256 + j * 64 + lane;
            const u16* g = &glds[r * 17];
            float vv[17];
            float mx = -1e30f;
            #pragma unroll
            for (int tt = 0; tt < 17; ++tt) { vv[tt] = b2f(g[tt]); mx = fmaxf(mx, vv[tt]); }
            float s = 0.f;
            #pragma unroll
            for (int tt = 0; tt < 17; ++tt) { vv[tt] = __expf(vv[tt] - mx); s += vv[tt]; }
            float inv = 1.0f / s;
            #pragma unroll
            for (int tt = 0; tt < 17; ++tt) p[j][tt] = vv[tt] * inv;
        }
        __syncthreads();
        #pragma unroll
        for (int j = 0; j < 4; ++j) {
            int r = rnd * 256 + j * 64 + lane;
            uint4 w0, w1;
            w0.x = (u32)f2b(p[j][1])  | ((u32)f2b(p[j][2])  << 16);
            w0.y = (u32)f2b(p[j][3])  | ((u32)f2b(p[j][4])  << 16);
            w0.z = (u32)f2b(p[j][5])  | ((u32)f2b(p[j][6])  << 16);
            w0.w = (u32)f2b(p[j][7])  | ((u32)f2b(p[j][8])  << 16);
            w1.x = (u32)f2b(p[j][9])  | ((u32)f2b(p[j][10]) << 16);
            w1.y = (u32)f2b(p[j][11]) | ((u32)f2b(p[j][12]) << 16);
            w1.z = (u32)f2b(p[j][13]) | ((u32)f2b(p[j][14]) << 16);
            w1.w = (u32)f2b(p[j][15]) | ((u32)f2b(p[j][16]) << 16);
            ((uint4*)glds)[r * 2]     = w0;
            ((uint4*)glds)[r * 2 + 1] = w1;
            vlds[r] *= p[j][0];
        }
        __syncthreads();
    }
}

// ---------------------------------------------------------------------------
// scan pass 1: per chunk of 32 steps compute P_c = A_31..A_0, e_c.
// ---------------------------------------------------------------------------
__global__ __launch_bounds__(64) void scan_p1(
    const u16* __restrict__ gates, const float* __restrict__ vvT,
    float* __restrict__ Pmat, float* __restrict__ evec)
{
    const int c = blockIdx.x, chain = blockIdx.y;
    const int lane = threadIdx.x;
    const int i = lane >> 2, q = lane & 3;
    __shared__ alignas(16) u16   glds[32 * 272];
    __shared__ alignas(16) float vlds[32 * 16];
    __shared__ alignas(16) float Pb[2][256];
    __shared__ float slds[16];

    const char* gbase = (const char*)(gates + ((size_t)chain * T_ + c * 32) * 272);
    #pragma unroll
    for (int it = 0; it < 17; ++it)
        stage16(gbase + it * 1024 + lane * 16, (char*)glds + it * 1024);
    const char* vbase = (const char*)(vvT + ((size_t)chain * T_ + c * 32) * 16);
    #pragma unroll
    for (int it = 0; it < 2; ++it)
        stage16(vbase + it * 1024 + lane * 16, (char*)vlds + it * 1024);
    __syncthreads();

    scan_prep(glds, vlds, lane);

    {
        f32x4 idq;
        #pragma unroll
        for (int m = 0; m < 4; ++m) idq[m] = (i == q * 4 + m) ? 1.f : 0.f;
        *(f32x4*)&Pb[0][i * 16 + q * 4] = idq;
    }
    f32x4 e4[4] = {};
    f32x4 np = {};
    float neLast = 0.f;
    int cur = 0;

    for (int st = 0; st < 32; ++st) {
        const uint4* rp = (const uint4*)((const char*)glds + (st * 16 + i) * 32);
        uint4 d0 = rp[0], d1 = rp[1];
        float ar[16];
        ar[0]  = blo(d0.x); ar[1]  = bhi(d0.x);
        ar[2]  = blo(d0.y); ar[3]  = bhi(d0.y);
        ar[4]  = blo(d0.z); ar[5]  = bhi(d0.z);
        ar[6]  = blo(d0.w); ar[7]  = bhi(d0.w);
        ar[8]  = blo(d1.x); ar[9]  = bhi(d1.x);
        ar[10] = blo(d1.y); ar[11] = bhi(d1.y);
        ar[12] = blo(d1.z); ar[13] = bhi(d1.z);
        ar[14] = blo(d1.w); ar[15] = bhi(d1.w);

        f32x4 pk[16];
        #pragma unroll
        for (int k = 0; k < 16; ++k)
            pk[k] = *(const f32x4*)&Pb[cur][k * 16 + q * 4];

        f32x4 a = pk[0] * ar[0];
        #pragma unroll
        for (int k = 1; k < 16; ++k) a += pk[k] * ar[k];
        np = a;

        float ne0 = ar[0] * e4[0][0] + ar[1] * e4[0][1] + ar[2] * e4[0][2] + ar[3] * e4[0][3];
        float ne1 = ar[4] * e4[1][0] + ar[5] * e4[1][1] + ar[6] * e4[1][2] + ar[7] * e4[1][3];
        float ne2 = ar[8] * e4[2][0] + ar[9] * e4[2][1] + ar[10] * e4[2][2] + ar[11] * e4[2][3];
        float ne3 = ar[12] * e4[3][0] + ar[13] * e4[3][1] + ar[14] * e4[3][2] + ar[15] * e4[3][3];
        float ne = (ne0 + ne1) + (ne2 + ne3) + vlds[st * 16 + i];

        *(f32x4*)&Pb[cur ^ 1][i * 16 + q * 4] = np;
        if (q == 0) slds[i] = ne;
        #pragma unroll
        for (int m = 0; m < 4; ++m) e4[m] = *(const f32x4*)&slds[m * 4];
        neLast = ne;
        cur ^= 1;
    }

    float* Pd = Pmat + ((size_t)chain * 32 + c) * 256;
    *(f32x4*)&Pd[i * 16 + q * 4] = np;
    if (q == 0) evec[((size_t)chain * 32 + c) * 16 + i] = neLast;
}

// ---------------------------------------------------------------------------
// scan pass 2: per chain, sequentially combine 32 chunks; sIn[c] = entry state.
// ---------------------------------------------------------------------------
__global__ __launch_bounds__(64) void scan_comb(
    const float* __restrict__ Pmat, const float* __restrict__ evec, float* __restrict__ sIn)
{
    const int chain = blockIdx.x;
    const int lane = threadIdx.x;
    const int i = lane >> 2, q = lane & 3;
    __shared__ alignas(16) float Pl[32 * 256];
    __shared__ alignas(16) float El[32 * 16];
    __shared__ float slds[16];

    const char* Pg = (const char*)(Pmat + (size_t)chain * 32 * 256);
    #pragma unroll
    for (int it = 0; it < 32; ++it)
        stage16(Pg + it * 1024 + lane * 16, (char*)Pl + it * 1024);
    const char* Eg = (const char*)(evec + (size_t)chain * 32 * 16);
    #pragma unroll
    for (int it = 0; it < 2; ++it)
        stage16(Eg + it * 1024 + lane * 16, (char*)El + it * 1024);
    __syncthreads();

    f32x4 s4[4] = {};
    if (q == 0) sIn[((size_t)chain * 32 + 0) * 16 + i] = 0.f;
    for (int cc = 0; cc < 32; ++cc) {
        f32x4 pr[4];
        #pragma unroll
        for (int m = 0; m < 4; ++m)
            pr[m] = *(const f32x4*)&Pl[cc * 256 + i * 16 + m * 4];
        float ne = 0.f;
        #pragma unroll
        for (int k = 0; k < 16; ++k) ne += pr[k >> 2][k & 3] * s4[k >> 2][k & 3];
        ne += El[cc * 16 + i];
        if (q == 0) {
            slds[i] = ne;
            if (cc < 31) sIn[((size_t)chain * 32 + cc + 1) * 16 + i] = ne;
        }
        #pragma unroll
        for (int m = 0; m < 4; ++m) s4[m] = *(const f32x4*)&slds[m * 4];
    }
}

// ---------------------------------------------------------------------------
// scan pass 3: replay each chunk from its entry state, write h_out.
// ---------------------------------------------------------------------------
__global__ __launch_bounds__(64) void scan_p2(
    const u16* __restrict__ gates, const float* __restrict__ vvT,
    const float* __restrict__ sIn, u16* __restrict__ hout)
{
    const int c = blockIdx.x, chain = blockIdx.y;
    const int b = chain >> 6, hh = chain & 63;
    const int lane = threadIdx.x;
    const int i = lane >> 2, q = lane & 3;
    __shared__ alignas(16) u16   glds[32 * 272];
    __shared__ alignas(16) float vlds[32 * 16];
    __shared__ float slds[16];

    const char* gbase = (const char*)(gates + ((size_t)chain * T_ + c * 32) * 272);
    #pragma unroll
    for (int it = 0; it < 17; ++it)
        stage16(gbase + it * 1024 + lane * 16, (char*)glds + it * 1024);
    const char* vbase = (const char*)(vvT + ((size_t)chain * T_ + c * 32) * 16);
    #pragma unroll
    for (int it = 0; it < 2; ++it)
        stage16(vbase + it * 1024 + lane * 16, (char*)vlds + it * 1024);
    __syncthreads();

    scan_prep(glds, vlds, lane);

    const float* sp = sIn + ((size_t)chain * 32 + c) * 16;
    f32x4 s4[4];
    #pragma unroll
    for (int m = 0; m < 4; ++m) s4[m] = *(const f32x4*)(sp + m * 4);

    u16* hbase = hout + ((size_t)(b * T_ + c * 32)) * D_ + hh * 16;
    for (int st = 0; st < 32; ++st) {
        const uint4* rp = (const uint4*)((const char*)glds + (st * 16 + i) * 32);
        uint4 d0 = rp[0], d1 = rp[1];
        float ne0 = blo(d0.x) * s4[0][0] + bhi(d0.x) * s4[0][1]
                  + blo(d0.y) * s4[0][2] + bhi(d0.y) * s4[0][3];
        float ne1 = blo(d0.z) * s4[1][0] + bhi(d0.z) * s4[1][1]
                  + blo(d0.w) * s4[1][2] + bhi(d0.w) * s4[1][3];
        float ne2 = blo(d1.x) * s4[2][0] + bhi(d1.x) * s4[2][1]
                  + blo(d1.y) * s4[2][2] + bhi(d1.y) * s4[2][3];
        float ne3 = blo(d1.z) * s4[3][0] + bhi(d1.z) * s4[3][1]
                  + blo(d1.w) * s4[3][2] + bhi(d1.w) * s4[3][3];
        float ne = (ne0 + ne1) + (ne2 + ne3) + vlds[st * 16 + i];
        if (q == 0) {
            slds[i] = ne;
            hbase[(size_t)st * D_ + i] = f2b(ne);
        }
        #pragma unroll
        for (int m = 0; m < 4; ++m) s4[m] = *(const f32x4*)&slds[m * 4];
    }
}

// ---------------------------------------------------------------------------
extern "C" void kernel_launch(void* const* d_in, const int* in_sizes, int n_in,
                              void* d_out, int out_size, void* d_ws, size_t ws_size,
                              hipStream_t stream)
{
    const float* x    = (const float*)d_in[0];
    const float* anw  = (const float*)d_in[1];
    const float* wqkv = (const float*)d_in[2];
    const float* wao  = (const float*)d_in[3];
    const float* lnw  = (const float*)d_in[4];
    const float* wv   = (const float*)d_in[5];
    const float* wa   = (const float*)d_in[6];
    const float* wop  = (const float*)d_in[7];

    char* ws = (char*)d_ws;
    const size_t MB = 1u << 20;
    u16*   h     = (u16*)  (ws +   0 * MB);   //  4 MB
    u16*   h2    = (u16*)  (ws +   4 * MB);   //  4 MB
    u16*   wqkvT = (u16*)  (ws +   8 * MB);   //  6 MB
    u16*   waoT  = (u16*)  (ws +  14 * MB);   //  2 MB
    u16*   wopT  = (u16*)  (ws +  16 * MB);   //  2 MB
    u16*   waT   = (u16*)  (ws +  18 * MB);   // 36 MB (wa 17408 rows + wv 1024 rows)
    float* x2    = (float*)(ws +  54 * MB);   //  8 MB
    float* vvT   = (float*)(ws +  62 * MB);   //  8 MB scan layout [chain][t][16]
    u16*   Qb    = (u16*)  (ws +  78 * MB);   //  4 MB (dead after attn)
    float* Pmat  = (float*)(ws +  78 * MB);   //  4 MB aliases Qb
    u16*   Kb    = (u16*)  (ws +  82 * MB);   //  4 MB (dead after attn)
    float* evec  = (float*)(ws +  82 * MB);   // 256 KB aliases Kb
    float* sIn   = (float*)(ws +  82 * MB + 256 * 1024); // 256 KB
    u16*   Vb    = (u16*)  (ws +  86 * MB);   //  4 MB (dead after transpose)
    u16*   Vt    = (u16*)  (ws +  90 * MB);   //  4 MB (dead after attn)
    u16*   omat  = (u16*)  (ws + 158 * MB);   //  4 MB (dead after attn_out)
    u16*   gates = (u16*)  (ws +  94 * MB);   // 68 MB aliases old S region
    u16*   hout  = (u16*)  (ws + 162 * MB);   //  4 MB (end: 166 MB)
    (void)in_sizes; (void)n_in; (void)out_size; (void)ws_size;

    dim3 tb(32, 8);
    convT_all<<<dim3(736, 32), tb, 0, stream>>>(
        wqkv, wao, wv, wa, wop, wqkvT, waoT, waT, wopT);

    rmsnorm_k<<<2048, 256, 0, stream>>>(x, anw, h);
    // qkv GEMM with fused RoPE epilogue -> Qb, Kb, Vb directly
    gemm_bt<64, 128, 32, 6, false, false, 0><<<dim3(24, 32, 1), 256, 0, stream>>>(
        h, wqkvT, (void*)Qb, (void*)Kb, (void*)Vb, nullptr, 2048, 3072, 1024, 0, 0, 0);
    transpose_bf16_k<<<dim3(2, 32, 32), tb, 0, stream>>>(Vb, Vt, 1024, 64);

    // fused flash attention: QK^T + causal softmax + PV in one launch
    attn_flash<<<512, 256, 0, stream>>>(Qb, Kb, Vt, omat);

    gemm_bt<64, 128, 32, 0, false, false, 0><<<dim3(8, 32, 1), 256, 0, stream>>>(
        omat, waoT, (void*)x2, nullptr, nullptr, x, 2048, 1024, 1024, 0, 0, 0);
    rmsnorm_k<<<2048, 256, 0, stream>>>(x2, lnw, h2);

    // fused gates + w_v GEMM: m97-structure 128x192, 1536 blocks, 3 blocks/CU
    gemm_gates128<<<dim3(96, 16), 256, 0, stream>>>(h2, waT, gates, vvT);

    scan_p1<<<dim3(32, 128), 64, 0, stream>>>(gates, vvT, Pmat, evec);
    scan_comb<<<128, 64, 0, stream>>>(Pmat, evec, sIn);
    scan_p2<<<dim3(32, 128), 64, 0, stream>>>(gates, vvT, sIn, hout);

    gemm_bt<64, 128, 32, 0, false, false, 0><<<dim3(8, 32, 1), 256, 0, stream>>>(
        hout, wopT, d_out, nullptr, nullptr, x2, 2048, 1024, 1024, 0, 0, 0);
}

// Round 10
// 454.157 us; speedup vs baseline: 1.1366x; 1.0010x over previous
//
#include <hip/hip_runtime.h>

// HKSABlock on MI355X (gfx950). Round 16: attn_flash double-buffered.
// R15 (454.6 us) fused flash attention worked; its loop had 2 barriers/tile
// with staging issued AFTER a barrier (zero latency cover) at only 2
// blocks/CU TLP. Now: Ks/Vs ping-pong (LDS 40 KB), next tile's 4 stage16
// issued at top of iteration (covered by ~800 cyc of MFMA+softmax), ONE
// __syncthreads per tile (vmcnt(0) drain makes next tile visible; buffer
// overwrite is one-iteration delayed -> race-free). Math unchanged.
// Everything else byte-identical to R15 (gates anchor 93 us / 36%).
// B=2, T=1024, D=1024, NH=16, HD=64, H=64, M=16.

typedef unsigned short u16;
typedef unsigned int   u32;
typedef __bf16 bf16x8 __attribute__((ext_vector_type(8)));
typedef float  f32x4  __attribute__((ext_vector_type(4)));

#define B_  2
#define T_  1024
#define D_  1024
#define NH_ 16
#define HD_ 64
#define H_  64
#define M_  16

__device__ __forceinline__ float b2f(u16 u) {
    return __uint_as_float(((u32)u) << 16);
}
__device__ __forceinline__ u16 f2b(float f) {
    u32 u = __float_as_uint(f);
    u32 r = (u + 0x7FFFu + ((u >> 16) & 1u)) >> 16;  // RNE
    return (u16)r;
}
__device__ __forceinline__ float blo(u32 u) { return __uint_as_float(u << 16); }
__device__ __forceinline__ float bhi(u32 u) { return __uint_as_float(u & 0xFFFF0000u); }

// Async global->LDS, 16 B per lane. LDS dest must be wave-uniform base.
__device__ __forceinline__ void stage16(const void* gp, void* lp) {
    typedef __attribute__((address_space(1))) const unsigned int GU;
    typedef __attribute__((address_space(3))) unsigned int LU;
    __builtin_amdgcn_global_load_lds((GU*)gp, (LU*)lp, 16, 0, 0);
}

// ---------------------------------------------------------------------------
// Generic MFMA GEMM: C[M,N] = A[M,K] * Bt[N,K]^T  (A,Bt bf16 row-major).
// 4 waves: wr = w>>1 (m-half), wc = w&1 (n-half). MT = BM/32, NT = BN/32.
// MODE 0: C fp32 (+ optional fp32 addend). MODE 1: C bf16.
// MODE 2: bf16 scatter into o_mat[(b*T + row)*1024 + h*64 + col], z = b*16+h.
// MODE 6: qkv + fused RoPE. N=3072; region = n0>>10 (0=Q,1=K,2=V). Each wave
//         owns one head's 64 cols; RoPE pair (i,i+32) = acc nt and nt+2.
//         Writes Qb(Cout)/Kb(Cout2)/Vb(Cout3) bf16 in (b,h,t,d).
// CAUSAL: skip blocks with n0 > m0+BM-1. TRUNCK: K truncated to m0+BM.
// ---------------------------------------------------------------------------
template<int BM, int BN, int BK, int MODE, bool TRUNCK, bool CAUSAL, int SWZ>
__global__ __launch_bounds__(256) void gemm_bt(
    const u16* __restrict__ A, const u16* __restrict__ Bt,
    void* __restrict__ Cout, void* __restrict__ Cout2, void* __restrict__ Cout3,
    const float* __restrict__ addend,
    int M, int N, int K, long strideA, long strideB, long strideC)
{
    constexpr int MT = BM / 32;
    constexpr int NT = BN / 32;
    constexpr int KCH = BK / 8;                  // 16B slots per row
    const int z  = blockIdx.z;
    int bx = blockIdx.x, by = blockIdx.y;
    if (SWZ == 2) {
        int f = by * gridDim.x + bx;
        int xcd = f & 7, k = f >> 3;
        by = k & 15;                             // by innermost per XCD
        bx = xcd * (gridDim.x >> 3) + (k >> 4);  // band per XCD
    }
    const int m0 = by * BM;
    const int n0 = bx * BN;
    if (CAUSAL && n0 > m0 + BM - 1) return;
    const int Keff = TRUNCK ? (K < m0 + BM ? K : m0 + BM) : K;

    const u16* Ab = A  + (size_t)z * (size_t)strideA;
    const u16* Bb = Bt + (size_t)z * (size_t)strideB;

    __shared__ alignas(16) u16 As[BM * BK];
    __shared__ alignas(16) u16 Bs[BN * BK];

    const int tid  = threadIdx.x;
    const int lane = tid & 63, w = tid >> 6;
    const int wr = w >> 1, wc = w & 1;
    const int quad = lane >> 4, l16 = lane & 15;

    f32x4 acc[MT][NT] = {};

    constexpr int AITER = (BM * BK / 8) / 256;
    constexpr int BITER = (BN * BK / 8) / 256;

    for (int k0 = 0; k0 < Keff; k0 += BK) {
        #pragma unroll
        for (int it = 0; it < AITER; ++it) {
            int c = it * 256 + tid;
            int m = c / KCH, kc = c % KCH;
            stage16(Ab + (size_t)(m0 + m) * K + k0 + kc * 8,
                    &As[(it * 256 + w * 64) * 8]);
        }
        #pragma unroll
        for (int it = 0; it < BITER; ++it) {
            int c = it * 256 + tid;
            int n = c / KCH, kc = c % KCH;
            stage16(Bb + (size_t)(n0 + n) * K + k0 + kc * 8,
                    &Bs[(it * 256 + w * 64) * 8]);
        }
        __syncthreads();

        #pragma unroll
        for (int kk = 0; kk < BK; kk += 32) {
            bf16x8 af[MT], bfr[NT];
            #pragma unroll
            for (int mt = 0; mt < MT; ++mt)
                af[mt] = *(const bf16x8*)&As[(wr * (BM / 2) + mt * 16 + l16) * BK + kk + quad * 8];
            #pragma unroll
            for (int nt = 0; nt < NT; ++nt)
                bfr[nt] = *(const bf16x8*)&Bs[(wc * (BN / 2) + nt * 16 + l16) * BK + kk + quad * 8];
            #pragma unroll
            for (int mt = 0; mt < MT; ++mt)
                #pragma unroll
                for (int nt = 0; nt < NT; ++nt)
                    acc[mt][nt] = __builtin_amdgcn_mfma_f32_16x16x32_bf16(
                        af[mt], bfr[nt], acc[mt][nt], 0, 0, 0);
        }
        __syncthreads();
    }

    // Epilogue. C/D layout: col = lane&15, row = (lane>>4)*4 + reg  [m89]
    if (MODE == 6) {
        // dedicated RoPE epilogue (NT==4, BN==128 required)
        const int reg = n0 >> 10;                      // 0=Q, 1=K, 2=V
        const int hh  = ((n0 & 1023) >> 6) + wc;       // head
        #pragma unroll
        for (int mt = 0; mt < MT; ++mt) {
            #pragma unroll
            for (int r = 0; r < 4; ++r) {
                int row = m0 + wr * (BM / 2) + mt * 16 + quad * 4 + r;
                int t = row & (T_ - 1), bb = row >> 10;
                size_t obase = ((size_t)(bb * NH_ + hh) * T_ + t) * HD_;
                if (reg == 2) {
                    #pragma unroll
                    for (int nt = 0; nt < 4; ++nt)
                        ((u16*)Cout3)[obase + nt * 16 + l16] = f2b(acc[mt][nt][r]);
                } else {
                    u16* dst = (reg == 0) ? (u16*)Cout : (u16*)Cout2;
                    #pragma unroll
                    for (int nt = 0; nt < 2; ++nt) {
                        int i = nt * 16 + l16;
                        float ang = (float)t * exp2f(-(float)i * 0.41524101186092034f);
                        float sn, cs;
                        sincosf(ang, &sn, &cs);
                        float q1 = acc[mt][nt][r], q2 = acc[mt][nt + 2][r];
                        dst[obase + i]      = f2b(q1 * cs - q2 * sn);
                        dst[obase + i + 32] = f2b(q2 * cs + q1 * sn);
                    }
                }
            }
        }
        return;
    }
    #pragma unroll
    for (int mt = 0; mt < MT; ++mt) {
        #pragma unroll
        for (int nt = 0; nt < NT; ++nt) {
            #pragma unroll
            for (int r = 0; r < 4; ++r) {
                int row = m0 + wr * (BM / 2) + mt * 16 + quad * 4 + r;
                int col = n0 + wc * (BN / 2) + nt * 16 + l16;
                float val = acc[mt][nt][r];
                if (MODE == 0) {
                    if (addend) val += addend[(size_t)row * N + col];
                    ((float*)Cout)[(size_t)z * (size_t)strideC + (size_t)row * N + col] = val;
                } else if (MODE == 1) {
                    ((u16*)Cout)[(size_t)z * (size_t)strideC + (size_t)row * N + col] = f2b(val);
                } else if (MODE == 2) {
                    size_t idx = ((size_t)(z >> 4) * T_ + row) * (size_t)D_ + (z & 15) * HD_ + col;
                    ((u16*)Cout)[idx] = f2b(val);
                }
            }
        }
    }
}

// ---------------------------------------------------------------------------
// Fused flash attention (double-buffered): omat = softmax(QK^T*0.125,causal)@V.
// Block = 64 q-rows of one (b,h) chain z; 4 waves, wave w owns q [w*16,+16).
// Per kv-tile: S^T via mfma(A=K-frag, B=Q-frag): q=l16 lane-fixed,
// kv=mt*16+quad*4+r; row softmax = 16 in-lane + shfl_xor(16,32).
// P bf16 -> per-wave Ps[16][64] via ds_write_b64, slot^(q&7) involution;
// same-wave readback as A-frag. O += mfma(A=P, B=Vt), fp32 acc, online
// rescale via shfl. Causal mask only on diagonal tile.
// DBUF: Ks/Vs[2] ping-pong; next tile's 4 stage16 issued at top of iter
// (covered by MFMA+softmax); ONE __syncthreads/tile (vmcnt(0) drain).
// Balanced grid pairing: (qb+1)+(16-qb)=17 tiles per CU pair.
// LDS: Qs 8K + Ks 16K + Vs 16K + Ps 8K = 48 KB total? (Qs8+2*8+2*8+8=40KB).
// ---------------------------------------------------------------------------
__global__ __launch_bounds__(256) void attn_flash(
    const u16* __restrict__ Qb, const u16* __restrict__ Kb,
    const u16* __restrict__ Vt, u16* __restrict__ omat)
{
    const int f = blockIdx.x;
    const int u = f & 255, rr2 = f >> 8;
    const int z  = (rr2 == 0) ? (u >> 4) : 16 + (u >> 4);
    const int qb = (rr2 == 0) ? (u & 15) : 15 - (u & 15);

    const u16* Qz = Qb + (size_t)z * 65536;   // [1024 t][64 d]
    const u16* Kz = Kb + (size_t)z * 65536;   // [1024 t][64 d]
    const u16* Vz = Vt + (size_t)z * 65536;   // [64 d][1024 t]

    __shared__ alignas(16) u16 Qs[64 * 64];
    __shared__ alignas(16) u16 Ks[2][64 * 64];
    __shared__ alignas(16) u16 Vs[2][64 * 64];
    __shared__ alignas(16) u16 Ps[4][16 * 64];

    const int tid  = threadIdx.x;
    const int lane = tid & 63, w = tid >> 6;
    const int quad = lane >> 4, l16 = lane & 15;

    // staging geometry (32 rows per call): thread t -> row t>>3, phys slot t&7,
    // source slot = (t&7) ^ (row&7)  (involution, 0 conflicts R9-R15).
    const int srow   = tid >> 3;
    const int colOff = (((tid & 7) ^ (srow & 7)) * 8);
    const int wbase  = w * 512;               // wave-uniform LDS dest (u16)

    // prologue: stage Q tile + K/V tile 0, single drain
    #pragma unroll
    for (int c = 0; c < 2; ++c)
        stage16(Qz + (size_t)(qb * 64 + c * 32 + srow) * 64 + colOff,
                &Qs[c * 2048 + wbase]);
    #pragma unroll
    for (int c = 0; c < 2; ++c)
        stage16(Kz + (size_t)(c * 32 + srow) * 64 + colOff,
                &Ks[0][c * 2048 + wbase]);
    #pragma unroll
    for (int c = 0; c < 2; ++c)
        stage16(Vz + (size_t)(c * 32 + srow) * 1024 + colOff,
                &Vs[0][c * 2048 + wbase]);
    __syncthreads();

    // hoist Q B-frags: rows q = w*16 + l16, k-slot = ks*4+quad (swizzled)
    const int qrow = w * 16 + l16;
    bf16x8 qf[2];
    #pragma unroll
    for (int ks = 0; ks < 2; ++ks)
        qf[ks] = *(const bf16x8*)&Qs[qrow * 64 + (((ks * 4 + quad) ^ (l16 & 7)) * 8)];

    f32x4 acc_o[4] = {};                      // O[q 16][d 64]: nt frags, fp32
    float m_run = -1e30f, l_run = 0.f;        // per lane, q = l16

    const int sq0 = (quad ^ (l16 & 7)) * 8;   // swizzled k-slot bases (u16)
    const int sq1 = ((4 + quad) ^ (l16 & 7)) * 8;

    u16* Pw = &Ps[w][0];
    // P write addr: row q=l16; frag mt covers kv mt*16+quad*4+[0,4):
    //   8B granule g = mt*4+quad -> slot s8 = g>>1, half h = g&1
    //   addr_u16 = l16*64 + ((s8 ^ (l16&7))*8 + h*4)
    int pwa[4];
    #pragma unroll
    for (int mt = 0; mt < 4; ++mt) {
        int g = mt * 4 + quad;
        pwa[mt] = l16 * 64 + (((g >> 1) ^ (l16 & 7)) * 8) + (g & 1) * 4;
    }

    for (int kt = 0; kt <= qb; ++kt) {
        const int cur = kt & 1, nxt = cur ^ 1;
        // prefetch next tile's K/V early: covered by S^T + softmax + PV below.
        // Write target Ks[nxt]/Vs[nxt] was last READ at iteration kt-1, and a
        // barrier separates kt-1 from here -> race-free.
        if (kt < qb) {
            #pragma unroll
            for (int c = 0; c < 2; ++c)
                stage16(Kz + (size_t)((kt + 1) * 64 + c * 32 + srow) * 64 + colOff,
                        &Ks[nxt][c * 2048 + wbase]);
            #pragma unroll
            for (int c = 0; c < 2; ++c)
                stage16(Vz + (size_t)(c * 32 + srow) * 1024 + (kt + 1) * 64 + colOff,
                        &Vs[nxt][c * 2048 + wbase]);
        }

        // ---- S^T = K @ Q^T (per wave: kv 64 x q 16) -------------------
        f32x4 accs[4] = {};
        #pragma unroll
        for (int ks = 0; ks < 2; ++ks) {
            const int so = ks ? sq1 : sq0;
            bf16x8 af[4];
            #pragma unroll
            for (int mt = 0; mt < 4; ++mt)
                af[mt] = *(const bf16x8*)&Ks[cur][(mt * 16 + l16) * 64 + so];
            #pragma unroll
            for (int mt = 0; mt < 4; ++mt)
                accs[mt] = __builtin_amdgcn_mfma_f32_16x16x32_bf16(
                    af[mt], qf[ks], accs[mt], 0, 0, 0);
        }

        // ---- scale + causal mask + row max (q = l16) ------------------
        float sv[4][4];
        float mx = -1e30f;
        const bool diag = (kt == qb);
        #pragma unroll
        for (int mt = 0; mt < 4; ++mt)
            #pragma unroll
            for (int r = 0; r < 4; ++r) {
                int kv = mt * 16 + quad * 4 + r;     // within tile
                float s = accs[mt][r] * 0.125f;
                if (diag && kv > qrow) s = -1e30f;
                sv[mt][r] = s;
                mx = fmaxf(mx, s);
            }
        mx = fmaxf(mx, __shfl_xor(mx, 16, 64));
        mx = fmaxf(mx, __shfl_xor(mx, 32, 64));

        const float m_new = fmaxf(m_run, mx);
        const float sc    = __expf(m_run - m_new);

        // ---- P = exp(S - m_new), tile sum -----------------------------
        float tsum = 0.f;
        u16 pb[4][4];
        #pragma unroll
        for (int mt = 0; mt < 4; ++mt)
            #pragma unroll
            for (int r = 0; r < 4; ++r) {
                float p = (sv[mt][r] > -1e29f) ? __expf(sv[mt][r] - m_new) : 0.f;
                tsum += p;
                pb[mt][r] = f2b(p);
            }
        tsum += __shfl_xor(tsum, 16, 64);
        tsum += __shfl_xor(tsum, 32, 64);
        l_run = l_run * sc + tsum;
        m_run = m_new;

        // ---- write P tile (per-wave, b64, swizzled) -------------------
        #pragma unroll
        for (int mt = 0; mt < 4; ++mt) {
            ushort4 pk = { pb[mt][0], pb[mt][1], pb[mt][2], pb[mt][3] };
            *(ushort4*)&Pw[pwa[mt]] = pk;
        }

        // ---- rescale O by sc (per O-row q' = quad*4+r) ----------------
        #pragma unroll
        for (int r = 0; r < 4; ++r) {
            float scr = __shfl(sc, quad * 4 + r, 64);
            #pragma unroll
            for (int nt = 0; nt < 4; ++nt) acc_o[nt][r] *= scr;
        }

        // ---- O += P @ V  (A = P rows q, B = Vt rows d) ----------------
        #pragma unroll
        for (int ks = 0; ks < 2; ++ks) {
            const int so = ks ? sq1 : sq0;
            bf16x8 pf = *(const bf16x8*)&Pw[l16 * 64 + so];
            bf16x8 vf[4];
            #pragma unroll
            for (int nt = 0; nt < 4; ++nt)
                vf[nt] = *(const bf16x8*)&Vs[cur][(nt * 16 + l16) * 64 + so];
            #pragma unroll
            for (int nt = 0; nt < 4; ++nt)
                acc_o[nt] = __builtin_amdgcn_mfma_f32_16x16x32_bf16(
                    pf, vf[nt], acc_o[nt], 0, 0, 0);
        }

        // one barrier per tile: drains the prefetch (vmcnt 0) AND guarantees
        // all waves are done reading Ks/Vs[cur] before iteration kt+1
        // overwrites them.
        __syncthreads();
    }

    // epilogue: O /= l (l indexed by q=l16 -> shfl), write omat
    const float linv = 1.0f / l_run;
    const int qg0 = qb * 64 + w * 16;
    #pragma unroll
    for (int r = 0; r < 4; ++r) {
        float li = __shfl(linv, quad * 4 + r, 64);
        int row = qg0 + quad * 4 + r;
        size_t obase = ((size_t)(z >> 4) * T_ + row) * D_ + (z & 15) * HD_;
        #pragma unroll
        for (int nt = 0; nt < 4; ++nt)
            omat[obase + nt * 16 + l16] = f2b(acc_o[nt][r] * li);
    }
}

// ---------------------------------------------------------------------------
// gates+w_v GEMM: C[2048,18432] = h2[2048,1024] x waT[18432,1024]^T.
// m97-structure (R12/R14/R15, measured 92-93 us / 827 TF): 128x192 tile,
// BK=64, 256 threads (4 waves 2x2, wave tile 64x96), single-buffered LDS
// 40 KB, 3 blocks/CU, grid 96x16 = 1536 blocks = 2 exact fill-waves.
// Swizzle: 16B slot phys = logical ^ (row&7) (0 conflicts).
// Epilogue: cg<1088 -> gates [chain][t][272] bf16; else vvT fp32.
// ---------------------------------------------------------------------------
__global__ __launch_bounds__(256, 3) void gemm_gates128(
    const u16* __restrict__ A, const u16* __restrict__ Bt,
    u16* __restrict__ gates, float* __restrict__ vvT)
{
    constexpr int K = 1024;
    constexpr int NTILE = 16;                    // K / 64

    // bijective XCD swizzle: 1536 blocks, 192/XCD = 12 bx x 16 by, by innermost
    const int f = blockIdx.y * gridDim.x + blockIdx.x;
    const int xcd = f & 7, k8 = f >> 3;          // k8 in [0,192)
    const int by = k8 & 15;
    const int bx = xcd * 12 + (k8 >> 4);
    const int m0 = by * 128;
    const int n0 = bx * 192;

    __shared__ alignas(16) u16 As[128 * 64];     // 16 KB
    __shared__ alignas(16) u16 Bs[192 * 64];     // 24 KB

    const int tid  = threadIdx.x;                // 0..255
    const int lane = tid & 63, w = tid >> 6;     // 4 waves
    const int wr = w >> 1, wc = w & 1;           // 2 x 2 wave grid
    const int quad = lane >> 4, l16 = lane & 15;

    // staging: thread t -> row (t>>3) within each 32-row call group, physical
    // 16B slot (t&7); global source slot = (t&7) ^ (row&7)  (involution).
    const int colOff = (((tid & 7) ^ ((tid >> 3) & 7)) * 8);
    const u16* pA = A  + (size_t)(m0 + (tid >> 3)) * K + colOff;
    const u16* pB = Bt + (size_t)(n0 + (tid >> 3)) * K + colOff;
    const int wbase = w * 512;                   // wave-uniform LDS dest (u16)

    // ds-read bases (u16): row*64 + phys_slot*8; phys = (kstep*4+quad)^(l16&7)
    const int sq0 = quad ^ (l16 & 7);
    const int sq1 = sq0 ^ 4;
    const int aoff0 = (wr * 64 + l16) * 64 + sq0 * 8;
    const int aoff1 = (wr * 64 + l16) * 64 + sq1 * 8;
    const int boff0 = (wc * 96 + l16) * 64 + sq0 * 8;
    const int boff1 = (wc * 96 + l16) * 64 + sq1 * 8;

    f32x4 acc[4][6] = {};                        // [mt][nt] wave tile 64x96

    #pragma unroll 1
    for (int t = 0; t < NTILE; ++t) {
        const int kc = t * 64;
        // stage A (4 calls x 32 rows) + B (6 calls x 32 rows)
        #pragma unroll
        for (int c = 0; c < 4; ++c)
            stage16(pA + (size_t)(c * 32) * K + kc, &As[c * 2048 + wbase]);
        #pragma unroll
        for (int c = 0; c < 6; ++c)
            stage16(pB + (size_t)(c * 32) * K + kc, &Bs[c * 2048 + wbase]);
        __syncthreads();

        bf16x8 af[4], bfr[6];
        // kstep 0 (k 0..31)
        #pragma unroll
        for (int mt = 0; mt < 4; ++mt) af[mt]  = *(const bf16x8*)&As[aoff0 + mt * 1024];
        #pragma unroll
        for (int nt = 0; nt < 6; ++nt) bfr[nt] = *(const bf16x8*)&Bs[boff0 + nt * 1024];
        #pragma unroll
        for (int mt = 0; mt < 4; ++mt)
            #pragma unroll
            for (int nt = 0; nt < 6; ++nt)
                acc[mt][nt] = __builtin_amdgcn_mfma_f32_16x16x32_bf16(
                    af[mt], bfr[nt], acc[mt][nt], 0, 0, 0);
        // kstep 1 (k 32..63)
        #pragma unroll
        for (int mt = 0; mt < 4; ++mt) af[mt]  = *(const bf16x8*)&As[aoff1 + mt * 1024];
        #pragma unroll
        for (int nt = 0; nt < 6; ++nt) bfr[nt] = *(const bf16x8*)&Bs[boff1 + nt * 1024];
        #pragma unroll
        for (int mt = 0; mt < 4; ++mt)
            #pragma unroll
            for (int nt = 0; nt < 6; ++nt)
                acc[mt][nt] = __builtin_amdgcn_mfma_f32_16x16x32_bf16(
                    af[mt], bfr[nt], acc[mt][nt], 0, 0, 0);
        __syncthreads();
    }

    // Epilogue: row = m0 + wr*64 + mt*16 + quad*4 + r
    //           col-group cg = bx*12 + wc*6 + nt (lane-uniform), col = cg*16+l16
    const int cgbase = bx * 12 + wc * 6;
    #pragma unroll
    for (int mt = 0; mt < 4; ++mt) {
        #pragma unroll
        for (int r = 0; r < 4; ++r) {
            int row = m0 + wr * 64 + mt * 16 + quad * 4 + r;
            int tt = row & (T_ - 1), bb = row >> 10;
            #pragma unroll
            for (int nt = 0; nt < 6; ++nt) {
                int cg = cgbase + nt;
                float val = acc[mt][nt][r];
                if (cg >= 1088) {
                    vvT[(((size_t)(bb * 64 + (cg - 1088))) * T_ + tt) * 16 + l16] = val;
                } else {
                    int hh = cg / 17, rem = cg - hh * 17;
                    gates[(((size_t)(bb * 64 + hh)) * T_ + tt) * 272 + rem * 16 + l16] = f2b(val);
                }
            }
        }
    }
}

// ---------------------------------------------------------------------------
__global__ __launch_bounds__(256) void rmsnorm_k(
    const float* __restrict__ x, const float* __restrict__ w, u16* __restrict__ out)
{
    const int row = blockIdx.x, tid = threadIdx.x;
    float4 v = ((const float4*)(x + (size_t)row * D_))[tid];
    float ss = v.x * v.x + v.y * v.y + v.z * v.z + v.w * v.w;
    #pragma unroll
    for (int o = 32; o >= 1; o >>= 1) ss += __shfl_xor(ss, o, 64);
    __shared__ float red[4];
    if ((tid & 63) == 0) red[tid >> 6] = ss;
    __syncthreads();
    ss = red[0] + red[1] + red[2] + red[3];
    float scale = rsqrtf(ss * (1.0f / D_) + 1e-5f);
    float4 wv = ((const float4*)w)[tid];
    ushort4 o4;
    o4.x = f2b(v.x * scale * wv.x);
    o4.y = f2b(v.y * scale * wv.y);
    o4.z = f2b(v.z * scale * wv.z);
    o4.w = f2b(v.w * scale * wv.w);
    ((ushort4*)(out + (size_t)row * D_))[tid] = o4;
}

// ---------------------------------------------------------------------------
// All weight converts in one launch. Segments by blockIdx.x (all R=1024):
//   [0,96)   wqkv C=3072 -> wqkvT
//   [96,128) wao  C=1024 -> waoT
//   [128,160)wv   C=1024 -> waT + 17408*1024 (contiguous with waT)
//   [160,704)wa   C=17408-> waT
//   [704,736)wop  C=1024 -> wopT
// ---------------------------------------------------------------------------
__global__ void convT_all(
    const float* __restrict__ wqkv, const float* __restrict__ wao,
    const float* __restrict__ wv,   const float* __restrict__ wa,
    const float* __restrict__ wop,
    u16* __restrict__ wqkvT, u16* __restrict__ waoT,
    u16* __restrict__ waT,   u16* __restrict__ wopT)
{
    const int x = blockIdx.x;
    const float* in; u16* out; int C, xb;
    if (x < 96)       { in = wqkv; out = wqkvT; C = 3072;  xb = x; }
    else if (x < 128) { in = wao;  out = waoT;  C = 1024;  xb = x - 96; }
    else if (x < 160) { in = wv;   out = waT + (size_t)17408 * 1024; C = 1024; xb = x - 128; }
    else if (x < 704) { in = wa;   out = waT;   C = 17408; xb = x - 160; }
    else              { in = wop;  out = wopT;  C = 1024;  xb = x - 704; }
    constexpr int R = 1024;
    __shared__ float tile[32][33];
    const int c0 = xb * 32, r0 = blockIdx.y * 32;
    const int tx = threadIdx.x, ty = threadIdx.y;
    #pragma unroll
    for (int k = 0; k < 4; ++k)
        tile[ty + 8 * k][tx] = in[(size_t)(r0 + ty + 8 * k) * C + c0 + tx];
    __syncthreads();
    #pragma unroll
    for (int k = 0; k < 4; ++k)
        out[(size_t)(c0 + ty + 8 * k) * R + r0 + tx] = f2b(tile[tx][ty + 8 * k]);
}

__global__ void transpose_bf16_k(const u16* __restrict__ in_, u16* __restrict__ out_, int R, int C)
{
    __shared__ u16 tile[32][33];
    const u16* in = in_ + (size_t)blockIdx.z * R * C;
    u16* out      = out_ + (size_t)blockIdx.z * R * C;
    const int c0 = blockIdx.x * 32, r0 = blockIdx.y * 32;
    const int tx = threadIdx.x, ty = threadIdx.y;
    #pragma unroll
    for (int k = 0; k < 4; ++k)
        tile[ty + 8 * k][tx] = in[(size_t)(r0 + ty + 8 * k) * C + c0 + tx];
    __syncthreads();
    #pragma unroll
    for (int k = 0; k < 4; ++k)
        out[(size_t)(c0 + ty + 8 * k) * R + r0 + tx] = tile[tx][ty + 8 * k];
}

// ---------------------------------------------------------------------------
// Scan-chunk prep (shared by p1/p2): raw gate logits for a 32-step chunk in
// glds (32 x 16 rows x 17 bf16 @ 34 B). Softmax each row, repack the 16
// A-entries in place to (st*16+i)*32 B (bf16), scale vlds (v -> a0*v).
// ---------------------------------------------------------------------------
__device__ __forceinline__ void scan_prep(u16* glds, float* vlds, int lane)
{
    #pragma unroll
    for (int rnd = 0; rnd < 2; ++rnd) {
        float p[4][17];
        #pragma unroll
        for (int j = 0; j < 4; ++j) {
            int r = rnd * 256 + j * 64 + lane;
            const u16* g = &glds[r * 17];
            float vv[17];
            float mx = -1e30f;
            #pragma unroll
            for (int tt = 0; tt < 17; ++tt) { vv[tt] = b2f(g[tt]); mx = fmaxf(mx, vv[tt]); }
            float s = 0.f;
            #pragma unroll
            for (int tt = 0; tt < 17; ++tt) { vv[tt] = __expf(vv[tt] - mx); s += vv[tt]; }
            float inv = 1.0f / s;
            #pragma unroll
            for (int tt = 0; tt < 17; ++tt) p[j][tt] = vv[tt] * inv;
        }
        __syncthreads();
        #pragma unroll
        for (int j = 0; j < 4; ++j) {
            int r = rnd * 256 + j * 64 + lane;
            uint4 w0, w1;
            w0.x = (u32)f2b(p[j][1])  | ((u32)f2b(p[j][2])  << 16);
            w0.y = (u32)f2b(p[j][3])  | ((u32)f2b(p[j][4])  << 16);
            w0.z = (u32)f2b(p[j][5])  | ((u32)f2b(p[j][6])  << 16);
            w0.w = (u32)f2b(p[j][7])  | ((u32)f2b(p[j][8])  << 16);
            w1.x = (u32)f2b(p[j][9])  | ((u32)f2b(p[j][10]) << 16);
            w1.y = (u32)f2b(p[j][11]) | ((u32)f2b(p[j][12]) << 16);
            w1.z = (u32)f2b(p[j][13]) | ((u32)f2b(p[j][14]) << 16);
            w1.w = (u32)f2b(p[j][15]) | ((u32)f2b(p[j][16]) << 16);
            ((uint4*)glds)[r * 2]     = w0;
            ((uint4*)glds)[r * 2 + 1] = w1;
            vlds[r] *= p[j][0];
        }
        __syncthreads();
    }
}

// ---------------------------------------------------------------------------
// scan pass 1: per chunk of 32 steps compute P_c = A_31..A_0, e_c.
// ---------------------------------------------------------------------------
__global__ __launch_bounds__(64) void scan_p1(
    const u16* __restrict__ gates, const float* __restrict__ vvT,
    float* __restrict__ Pmat, float* __restrict__ evec)
{
    const int c = blockIdx.x, chain = blockIdx.y;
    const int lane = threadIdx.x;
    const int i = lane >> 2, q = lane & 3;
    __shared__ alignas(16) u16   glds[32 * 272];
    __shared__ alignas(16) float vlds[32 * 16];
    __shared__ alignas(16) float Pb[2][256];
    __shared__ float slds[16];

    const char* gbase = (const char*)(gates + ((size_t)chain * T_ + c * 32) * 272);
    #pragma unroll
    for (int it = 0; it < 17; ++it)
        stage16(gbase + it * 1024 + lane * 16, (char*)glds + it * 1024);
    const char* vbase = (const char*)(vvT + ((size_t)chain * T_ + c * 32) * 16);
    #pragma unroll
    for (int it = 0; it < 2; ++it)
        stage16(vbase + it * 1024 + lane * 16, (char*)vlds + it * 1024);
    __syncthreads();

    scan_prep(glds, vlds, lane);

    {
        f32x4 idq;
        #pragma unroll
        for (int m = 0; m < 4; ++m) idq[m] = (i == q * 4 + m) ? 1.f : 0.f;
        *(f32x4*)&Pb[0][i * 16 + q * 4] = idq;
    }
    f32x4 e4[4] = {};
    f32x4 np = {};
    float neLast = 0.f;
    int cur = 0;

    for (int st = 0; st < 32; ++st) {
        const uint4* rp = (const uint4*)((const char*)glds + (st * 16 + i) * 32);
        uint4 d0 = rp[0], d1 = rp[1];
        float ar[16];
        ar[0]  = blo(d0.x); ar[1]  = bhi(d0.x);
        ar[2]  = blo(d0.y); ar[3]  = bhi(d0.y);
        ar[4]  = blo(d0.z); ar[5]  = bhi(d0.z);
        ar[6]  = blo(d0.w); ar[7]  = bhi(d0.w);
        ar[8]  = blo(d1.x); ar[9]  = bhi(d1.x);
        ar[10] = blo(d1.y); ar[11] = bhi(d1.y);
        ar[12] = blo(d1.z); ar[13] = bhi(d1.z);
        ar[14] = blo(d1.w); ar[15] = bhi(d1.w);

        f32x4 pk[16];
        #pragma unroll
        for (int k = 0; k < 16; ++k)
            pk[k] = *(const f32x4*)&Pb[cur][k * 16 + q * 4];

        f32x4 a = pk[0] * ar[0];
        #pragma unroll
        for (int k = 1; k < 16; ++k) a += pk[k] * ar[k];
        np = a;

        float ne0 = ar[0] * e4[0][0] + ar[1] * e4[0][1] + ar[2] * e4[0][2] + ar[3] * e4[0][3];
        float ne1 = ar[4] * e4[1][0] + ar[5] * e4[1][1] + ar[6] * e4[1][2] + ar[7] * e4[1][3];
        float ne2 = ar[8] * e4[2][0] + ar[9] * e4[2][1] + ar[10] * e4[2][2] + ar[11] * e4[2][3];
        float ne3 = ar[12] * e4[3][0] + ar[13] * e4[3][1] + ar[14] * e4[3][2] + ar[15] * e4[3][3];
        float ne = (ne0 + ne1) + (ne2 + ne3) + vlds[st * 16 + i];

        *(f32x4*)&Pb[cur ^ 1][i * 16 + q * 4] = np;
        if (q == 0) slds[i] = ne;
        #pragma unroll
        for (int m = 0; m < 4; ++m) e4[m] = *(const f32x4*)&slds[m * 4];
        neLast = ne;
        cur ^= 1;
    }

    float* Pd = Pmat + ((size_t)chain * 32 + c) * 256;
    *(f32x4*)&Pd[i * 16 + q * 4] = np;
    if (q == 0) evec[((size_t)chain * 32 + c) * 16 + i] = neLast;
}

// ---------------------------------------------------------------------------
// scan pass 2: per chain, sequentially combine 32 chunks; sIn[c] = entry state.
// ---------------------------------------------------------------------------
__global__ __launch_bounds__(64) void scan_comb(
    const float* __restrict__ Pmat, const float* __restrict__ evec, float* __restrict__ sIn)
{
    const int chain = blockIdx.x;
    const int lane = threadIdx.x;
    const int i = lane >> 2, q = lane & 3;
    __shared__ alignas(16) float Pl[32 * 256];
    __shared__ alignas(16) float El[32 * 16];
    __shared__ float slds[16];

    const char* Pg = (const char*)(Pmat + (size_t)chain * 32 * 256);
    #pragma unroll
    for (int it = 0; it < 32; ++it)
        stage16(Pg + it * 1024 + lane * 16, (char*)Pl + it * 1024);
    const char* Eg = (const char*)(evec + (size_t)chain * 32 * 16);
    #pragma unroll
    for (int it = 0; it < 2; ++it)
        stage16(Eg + it * 1024 + lane * 16, (char*)El + it * 1024);
    __syncthreads();

    f32x4 s4[4] = {};
    if (q == 0) sIn[((size_t)chain * 32 + 0) * 16 + i] = 0.f;
    for (int cc = 0; cc < 32; ++cc) {
        f32x4 pr[4];
        #pragma unroll
        for (int m = 0; m < 4; ++m)
            pr[m] = *(const f32x4*)&Pl[cc * 256 + i * 16 + m * 4];
        float ne = 0.f;
        #pragma unroll
        for (int k = 0; k < 16; ++k) ne += pr[k >> 2][k & 3] * s4[k >> 2][k & 3];
        ne += El[cc * 16 + i];
        if (q == 0) {
            slds[i] = ne;
            if (cc < 31) sIn[((size_t)chain * 32 + cc + 1) * 16 + i] = ne;
        }
        #pragma unroll
        for (int m = 0; m < 4; ++m) s4[m] = *(const f32x4*)&slds[m * 4];
    }
}

// ---------------------------------------------------------------------------
// scan pass 3: replay each chunk from its entry state, write h_out.
// ---------------------------------------------------------------------------
__global__ __launch_bounds__(64) void scan_p2(
    const u16* __restrict__ gates, const float* __restrict__ vvT,
    const float* __restrict__ sIn, u16* __restrict__ hout)
{
    const int c = blockIdx.x, chain = blockIdx.y;
    const int b = chain >> 6, hh = chain & 63;
    const int lane = threadIdx.x;
    const int i = lane >> 2, q = lane & 3;
    __shared__ alignas(16) u16   glds[32 * 272];
    __shared__ alignas(16) float vlds[32 * 16];
    __shared__ float slds[16];

    const char* gbase = (const char*)(gates + ((size_t)chain * T_ + c * 32) * 272);
    #pragma unroll
    for (int it = 0; it < 17; ++it)
        stage16(gbase + it * 1024 + lane * 16, (char*)glds + it * 1024);
    const char* vbase = (const char*)(vvT + ((size_t)chain * T_ + c * 32) * 16);
    #pragma unroll
    for (int it = 0; it < 2; ++it)
        stage16(vbase + it * 1024 + lane * 16, (char*)vlds + it * 1024);
    __syncthreads();

    scan_prep(glds, vlds, lane);

    const float* sp = sIn + ((size_t)chain * 32 + c) * 16;
    f32x4 s4[4];
    #pragma unroll
    for (int m = 0; m < 4; ++m) s4[m] = *(const f32x4*)(sp + m * 4);

    u16* hbase = hout + ((size_t)(b * T_ + c * 32)) * D_ + hh * 16;
    for (int st = 0; st < 32; ++st) {
        const uint4* rp = (const uint4*)((const char*)glds + (st * 16 + i) * 32);
        uint4 d0 = rp[0], d1 = rp[1];
        float ne0 = blo(d0.x) * s4[0][0] + bhi(d0.x) * s4[0][1]
                  + blo(d0.y) * s4[0][2] + bhi(d0.y) * s4[0][3];
        float ne1 = blo(d0.z) * s4[1][0] + bhi(d0.z) * s4[1][1]
                  + blo(d0.w) * s4[1][2] + bhi(d0.w) * s4[1][3];
        float ne2 = blo(d1.x) * s4[2][0] + bhi(d1.x) * s4[2][1]
                  + blo(d1.y) * s4[2][2] + bhi(d1.y) * s4[2][3];
        float ne3 = blo(d1.z) * s4[3][0] + bhi(d1.z) * s4[3][1]
                  + blo(d1.w) * s4[3][2] + bhi(d1.w) * s4[3][3];
        float ne = (ne0 + ne1) + (ne2 + ne3) + vlds[st * 16 + i];
        if (q == 0) {
            slds[i] = ne;
            hbase[(size_t)st * D_ + i] = f2b(ne);
        }
        #pragma unroll
        for (int m = 0; m < 4; ++m) s4[m] = *(const f32x4*)&slds[m * 4];
    }
}

// ---------------------------------------------------------------------------
extern "C" void kernel_launch(void* const* d_in, const int* in_sizes, int n_in,
                              void* d_out, int out_size, void* d_ws, size_t ws_size,
                              hipStream_t stream)
{
    const float* x    = (const float*)d_in[0];
    const float* anw  = (const float*)d_in[1];
    const float* wqkv = (const float*)d_in[2];
    const float* wao  = (const float*)d_in[3];
    const float* lnw  = (const float*)d_in[4];
    const float* wv   = (const float*)d_in[5];
    const float* wa   = (const float*)d_in[6];
    const float* wop  = (const float*)d_in[7];

    char* ws = (char*)d_ws;
    const size_t MB = 1u << 20;
    u16*   h     = (u16*)  (ws +   0 * MB);   //  4 MB
    u16*   h2    = (u16*)  (ws +   4 * MB);   //  4 MB
    u16*   wqkvT = (u16*)  (ws +   8 * MB);   //  6 MB
    u16*   waoT  = (u16*)  (ws +  14 * MB);   //  2 MB
    u16*   wopT  = (u16*)  (ws +  16 * MB);   //  2 MB
    u16*   waT   = (u16*)  (ws +  18 * MB);   // 36 MB (wa 17408 rows + wv 1024 rows)
    float* x2    = (float*)(ws +  54 * MB);   //  8 MB
    float* vvT   = (float*)(ws +  62 * MB);   //  8 MB scan layout [chain][t][16]
    u16*   Qb    = (u16*)  (ws +  78 * MB);   //  4 MB (dead after attn)
    float* Pmat  = (float*)(ws +  78 * MB);   //  4 MB aliases Qb
    u16*   Kb    = (u16*)  (ws +  82 * MB);   //  4 MB (dead after attn)
    float* evec  = (float*)(ws +  82 * MB);   // 256 KB aliases Kb
    float* sIn   = (float*)(ws +  82 * MB + 256 * 1024); // 256 KB
    u16*   Vb    = (u16*)  (ws +  86 * MB);   //  4 MB (dead after transpose)
    u16*   Vt    = (u16*)  (ws +  90 * MB);   //  4 MB (dead after attn)
    u16*   omat  = (u16*)  (ws + 158 * MB);   //  4 MB (dead after attn_out)
    u16*   gates = (u16*)  (ws +  94 * MB);   // 68 MB aliases old S region
    u16*   hout  = (u16*)  (ws + 162 * MB);   //  4 MB (end: 166 MB)
    (void)in_sizes; (void)n_in; (void)out_size; (void)ws_size;

    dim3 tb(32, 8);
    convT_all<<<dim3(736, 32), tb, 0, stream>>>(
        wqkv, wao, wv, wa, wop, wqkvT, waoT, waT, wopT);

    rmsnorm_k<<<2048, 256, 0, stream>>>(x, anw, h);
    // qkv GEMM with fused RoPE epilogue -> Qb, Kb, Vb directly
    gemm_bt<64, 128, 32, 6, false, false, 0><<<dim3(24, 32, 1), 256, 0, stream>>>(
        h, wqkvT, (void*)Qb, (void*)Kb, (void*)Vb, nullptr, 2048, 3072, 1024, 0, 0, 0);
    transpose_bf16_k<<<dim3(2, 32, 32), tb, 0, stream>>>(Vb, Vt, 1024, 64);

    // fused flash attention (double-buffered): QK^T + softmax + PV, 1 launch
    attn_flash<<<512, 256, 0, stream>>>(Qb, Kb, Vt, omat);

    gemm_bt<64, 128, 32, 0, false, false, 0><<<dim3(8, 32, 1), 256, 0, stream>>>(
        omat, waoT, (void*)x2, nullptr, nullptr, x, 2048, 1024, 1024, 0, 0, 0);
    rmsnorm_k<<<2048, 256, 0, stream>>>(x2, lnw, h2);

    // fused gates + w_v GEMM: m97-structure 128x192, 1536 blocks, 3 blocks/CU
    gemm_gates128<<<dim3(96, 16), 256, 0, stream>>>(h2, waT, gates, vvT);

    scan_p1<<<dim3(32, 128), 64, 0, stream>>>(gates, vvT, Pmat, evec);
    scan_comb<<<128, 64, 0, stream>>>(Pmat, evec, sIn);
    scan_p2<<<dim3(32, 128), 64, 0, stream>>>(gates, vvT, sIn, hout);

    gemm_bt<64, 128, 32, 0, false, false, 0><<<dim3(8, 32, 1), 256, 0, stream>>>(
        hout, wopT, d_out, nullptr, nullptr, x2, 2048, 1024, 1024, 0, 0, 0);
}

// Round 11
// 447.412 us; speedup vs baseline: 1.1537x; 1.0151x over previous
//
#include <hip/hip_runtime.h>

// HKSABlock on MI355X (gfx950). Round 17: R16 pipeline (454.2 us) + R13's
// correctness-verified gemm_bt upgrade (BK=64, 32-row staging, involution
// slot-swizzle, 0-conflict reads) for the remaining small GEMMs
// (qkv/attn_out/outproj; QK^T/softmax/PV are gone since R15's attn_flash).
// R13 coincided with an unexplained -34% on the byte-identical gates kernel
// (env vs co-compile drift unresolved); env now stable 3 runs (gates
// 91.9/93.0/92.9). Gates is the canary: >105 us => drift confirmed, revert.
// B=2, T=1024, D=1024, NH=16, HD=64, H=64, M=16.

typedef unsigned short u16;
typedef unsigned int   u32;
typedef __bf16 bf16x8 __attribute__((ext_vector_type(8)));
typedef float  f32x4  __attribute__((ext_vector_type(4)));

#define B_  2
#define T_  1024
#define D_  1024
#define NH_ 16
#define HD_ 64
#define H_  64
#define M_  16

__device__ __forceinline__ float b2f(u16 u) {
    return __uint_as_float(((u32)u) << 16);
}
__device__ __forceinline__ u16 f2b(float f) {
    u32 u = __float_as_uint(f);
    u32 r = (u + 0x7FFFu + ((u >> 16) & 1u)) >> 16;  // RNE
    return (u16)r;
}
__device__ __forceinline__ float blo(u32 u) { return __uint_as_float(u << 16); }
__device__ __forceinline__ float bhi(u32 u) { return __uint_as_float(u & 0xFFFF0000u); }

// Async global->LDS, 16 B per lane. LDS dest must be wave-uniform base.
__device__ __forceinline__ void stage16(const void* gp, void* lp) {
    typedef __attribute__((address_space(1))) const unsigned int GU;
    typedef __attribute__((address_space(3))) unsigned int LU;
    __builtin_amdgcn_global_load_lds((GU*)gp, (LU*)lp, 16, 0, 0);
}

// ---------------------------------------------------------------------------
// Generic MFMA GEMM: C[M,N] = A[M,K] * Bt[N,K]^T  (A,Bt bf16 row-major).
// BK = 64 (required). 4 waves: wr = w>>1 (m-half), wc = w&1 (n-half).
// Staging: 32-row groups, thread t -> row (t>>3), phys slot (t&7), global
// source slot = (t&7)^(row&7) (involution). Reads: phys = (ks*4+quad)^(l16&7)
// -> 0 LDS bank conflicts (verified R9-R16 on the gates kernel; this exact
// gemm_bt body passed correctness in R13).
// MODE 0: C fp32 (+ optional fp32 addend). MODE 1: C bf16.
// MODE 2: bf16 scatter into o_mat[(b*T + row)*1024 + h*64 + col], z = b*16+h.
// MODE 6: qkv + fused RoPE. N=3072; region = n0>>10 (0=Q,1=K,2=V). Each wave
//         owns one head's 64 cols; RoPE pair (i,i+32) = acc nt and nt+2.
//         Writes Qb(Cout)/Kb(Cout2)/Vb(Cout3) bf16 in (b,h,t,d).
// CAUSAL: skip blocks with n0 > m0+BM-1. TRUNCK: K truncated to m0+BM.
// ---------------------------------------------------------------------------
template<int BM, int BN, int BK, int MODE, bool TRUNCK, bool CAUSAL, int SWZ>
__global__ __launch_bounds__(256) void gemm_bt(
    const u16* __restrict__ A, const u16* __restrict__ Bt,
    void* __restrict__ Cout, void* __restrict__ Cout2, void* __restrict__ Cout3,
    const float* __restrict__ addend,
    int M, int N, int K, long strideA, long strideB, long strideC)
{
    static_assert(BK == 64, "gemm_bt requires BK=64");
    constexpr int MT = BM / 32;
    constexpr int NT = BN / 32;
    const int z  = blockIdx.z;
    const int bx = blockIdx.x, by = blockIdx.y;
    const int m0 = by * BM;
    const int n0 = bx * BN;
    if (CAUSAL && n0 > m0 + BM - 1) return;
    const int Keff = TRUNCK ? (K < m0 + BM ? K : m0 + BM) : K;

    const u16* Ab = A  + (size_t)z * (size_t)strideA;
    const u16* Bb = Bt + (size_t)z * (size_t)strideB;

    __shared__ alignas(16) u16 As[BM * 64];
    __shared__ alignas(16) u16 Bs[BN * 64];

    const int tid  = threadIdx.x;
    const int lane = tid & 63, w = tid >> 6;
    const int wr = w >> 1, wc = w & 1;
    const int quad = lane >> 4, l16 = lane & 15;

    // staging geometry (32 rows per call)
    const int srow   = tid >> 3;                          // 0..31
    const int colOff = (((tid & 7) ^ (srow & 7)) * 8);    // involution source slot
    const u16* pA = Ab + (size_t)(m0 + srow) * K + colOff;
    const u16* pB = Bb + (size_t)(n0 + srow) * K + colOff;
    const int wbase = w * 512;                            // wave-uniform dest (u16)

    // swizzled read slots: phys = (kstep*4 + quad) ^ (l16&7)
    const int sq0 = quad ^ (l16 & 7);
    const int sq1 = sq0 ^ 4;

    f32x4 acc[MT][NT] = {};

    for (int k0 = 0; k0 < Keff; k0 += 64) {
        #pragma unroll
        for (int c = 0; c < BM / 32; ++c)
            stage16(pA + (size_t)(c * 32) * K + k0, &As[c * 2048 + wbase]);
        #pragma unroll
        for (int c = 0; c < BN / 32; ++c)
            stage16(pB + (size_t)(c * 32) * K + k0, &Bs[c * 2048 + wbase]);
        __syncthreads();

        bf16x8 af[MT], bfr[NT];
        // kstep 0 (k 0..31 of tile)
        #pragma unroll
        for (int mt = 0; mt < MT; ++mt)
            af[mt] = *(const bf16x8*)&As[(wr * (BM / 2) + mt * 16 + l16) * 64 + sq0 * 8];
        #pragma unroll
        for (int nt = 0; nt < NT; ++nt)
            bfr[nt] = *(const bf16x8*)&Bs[(wc * (BN / 2) + nt * 16 + l16) * 64 + sq0 * 8];
        #pragma unroll
        for (int mt = 0; mt < MT; ++mt)
            #pragma unroll
            for (int nt = 0; nt < NT; ++nt)
                acc[mt][nt] = __builtin_amdgcn_mfma_f32_16x16x32_bf16(
                    af[mt], bfr[nt], acc[mt][nt], 0, 0, 0);
        // kstep 1 (k 32..63 of tile)
        #pragma unroll
        for (int mt = 0; mt < MT; ++mt)
            af[mt] = *(const bf16x8*)&As[(wr * (BM / 2) + mt * 16 + l16) * 64 + sq1 * 8];
        #pragma unroll
        for (int nt = 0; nt < NT; ++nt)
            bfr[nt] = *(const bf16x8*)&Bs[(wc * (BN / 2) + nt * 16 + l16) * 64 + sq1 * 8];
        #pragma unroll
        for (int mt = 0; mt < MT; ++mt)
            #pragma unroll
            for (int nt = 0; nt < NT; ++nt)
                acc[mt][nt] = __builtin_amdgcn_mfma_f32_16x16x32_bf16(
                    af[mt], bfr[nt], acc[mt][nt], 0, 0, 0);
        __syncthreads();
    }

    // Epilogue. C/D layout: col = lane&15, row = (lane>>4)*4 + reg  [m89]
    if (MODE == 6) {
        // dedicated RoPE epilogue (NT==4, BN==128 required)
        const int reg = n0 >> 10;                      // 0=Q, 1=K, 2=V
        const int hh  = ((n0 & 1023) >> 6) + wc;       // head
        #pragma unroll
        for (int mt = 0; mt < MT; ++mt) {
            #pragma unroll
            for (int r = 0; r < 4; ++r) {
                int row = m0 + wr * (BM / 2) + mt * 16 + quad * 4 + r;
                int t = row & (T_ - 1), bb = row >> 10;
                size_t obase = ((size_t)(bb * NH_ + hh) * T_ + t) * HD_;
                if (reg == 2) {
                    #pragma unroll
                    for (int nt = 0; nt < 4; ++nt)
                        ((u16*)Cout3)[obase + nt * 16 + l16] = f2b(acc[mt][nt][r]);
                } else {
                    u16* dst = (reg == 0) ? (u16*)Cout : (u16*)Cout2;
                    #pragma unroll
                    for (int nt = 0; nt < 2; ++nt) {
                        int i = nt * 16 + l16;
                        float ang = (float)t * exp2f(-(float)i * 0.41524101186092034f);
                        float sn, cs;
                        sincosf(ang, &sn, &cs);
                        float q1 = acc[mt][nt][r], q2 = acc[mt][nt + 2][r];
                        dst[obase + i]      = f2b(q1 * cs - q2 * sn);
                        dst[obase + i + 32] = f2b(q2 * cs + q1 * sn);
                    }
                }
            }
        }
        return;
    }
    #pragma unroll
    for (int mt = 0; mt < MT; ++mt) {
        #pragma unroll
        for (int nt = 0; nt < NT; ++nt) {
            #pragma unroll
            for (int r = 0; r < 4; ++r) {
                int row = m0 + wr * (BM / 2) + mt * 16 + quad * 4 + r;
                int col = n0 + wc * (BN / 2) + nt * 16 + l16;
                float val = acc[mt][nt][r];
                if (MODE == 0) {
                    if (addend) val += addend[(size_t)row * N + col];
                    ((float*)Cout)[(size_t)z * (size_t)strideC + (size_t)row * N + col] = val;
                } else if (MODE == 1) {
                    ((u16*)Cout)[(size_t)z * (size_t)strideC + (size_t)row * N + col] = f2b(val);
                } else if (MODE == 2) {
                    size_t idx = ((size_t)(z >> 4) * T_ + row) * (size_t)D_ + (z & 15) * HD_ + col;
                    ((u16*)Cout)[idx] = f2b(val);
                }
            }
        }
    }
}

// ---------------------------------------------------------------------------
// Fused flash attention (double-buffered): omat = softmax(QK^T*0.125,causal)@V.
// Block = 64 q-rows of one (b,h) chain z; 4 waves, wave w owns q [w*16,+16).
// Per kv-tile: S^T via mfma(A=K-frag, B=Q-frag): q=l16 lane-fixed,
// kv=mt*16+quad*4+r; row softmax = 16 in-lane + shfl_xor(16,32).
// P bf16 -> per-wave Ps[16][64] via ds_write_b64, slot^(q&7) involution;
// same-wave readback as A-frag. O += mfma(A=P, B=Vt), fp32 acc, online
// rescale via shfl. Causal mask only on diagonal tile.
// DBUF: Ks/Vs[2] ping-pong; next tile's 4 stage16 issued at top of iter;
// ONE __syncthreads/tile. Balanced grid pairing: (qb+1)+(16-qb)=17.
// LDS: Qs 8K + Ks 16K + Vs 16K + Ps 8K = 48 KB.
// ---------------------------------------------------------------------------
__global__ __launch_bounds__(256) void attn_flash(
    const u16* __restrict__ Qb, const u16* __restrict__ Kb,
    const u16* __restrict__ Vt, u16* __restrict__ omat)
{
    const int f = blockIdx.x;
    const int u = f & 255, rr2 = f >> 8;
    const int z  = (rr2 == 0) ? (u >> 4) : 16 + (u >> 4);
    const int qb = (rr2 == 0) ? (u & 15) : 15 - (u & 15);

    const u16* Qz = Qb + (size_t)z * 65536;   // [1024 t][64 d]
    const u16* Kz = Kb + (size_t)z * 65536;   // [1024 t][64 d]
    const u16* Vz = Vt + (size_t)z * 65536;   // [64 d][1024 t]

    __shared__ alignas(16) u16 Qs[64 * 64];
    __shared__ alignas(16) u16 Ks[2][64 * 64];
    __shared__ alignas(16) u16 Vs[2][64 * 64];
    __shared__ alignas(16) u16 Ps[4][16 * 64];

    const int tid  = threadIdx.x;
    const int lane = tid & 63, w = tid >> 6;
    const int quad = lane >> 4, l16 = lane & 15;

    // staging geometry (32 rows per call): thread t -> row t>>3, phys slot t&7,
    // source slot = (t&7) ^ (row&7)  (involution, 0 conflicts R9-R16).
    const int srow   = tid >> 3;
    const int colOff = (((tid & 7) ^ (srow & 7)) * 8);
    const int wbase  = w * 512;               // wave-uniform LDS dest (u16)

    // prologue: stage Q tile + K/V tile 0, single drain
    #pragma unroll
    for (int c = 0; c < 2; ++c)
        stage16(Qz + (size_t)(qb * 64 + c * 32 + srow) * 64 + colOff,
                &Qs[c * 2048 + wbase]);
    #pragma unroll
    for (int c = 0; c < 2; ++c)
        stage16(Kz + (size_t)(c * 32 + srow) * 64 + colOff,
                &Ks[0][c * 2048 + wbase]);
    #pragma unroll
    for (int c = 0; c < 2; ++c)
        stage16(Vz + (size_t)(c * 32 + srow) * 1024 + colOff,
                &Vs[0][c * 2048 + wbase]);
    __syncthreads();

    // hoist Q B-frags: rows q = w*16 + l16, k-slot = ks*4+quad (swizzled)
    const int qrow = w * 16 + l16;
    bf16x8 qf[2];
    #pragma unroll
    for (int ks = 0; ks < 2; ++ks)
        qf[ks] = *(const bf16x8*)&Qs[qrow * 64 + (((ks * 4 + quad) ^ (l16 & 7)) * 8)];

    f32x4 acc_o[4] = {};                      // O[q 16][d 64]: nt frags, fp32
    float m_run = -1e30f, l_run = 0.f;        // per lane, q = l16

    const int sq0 = (quad ^ (l16 & 7)) * 8;   // swizzled k-slot bases (u16)
    const int sq1 = ((4 + quad) ^ (l16 & 7)) * 8;

    u16* Pw = &Ps[w][0];
    // P write addr: row q=l16; frag mt covers kv mt*16+quad*4+[0,4):
    //   8B granule g = mt*4+quad -> slot s8 = g>>1, half h = g&1
    //   addr_u16 = l16*64 + ((s8 ^ (l16&7))*8 + h*4)
    int pwa[4];
    #pragma unroll
    for (int mt = 0; mt < 4; ++mt) {
        int g = mt * 4 + quad;
        pwa[mt] = l16 * 64 + (((g >> 1) ^ (l16 & 7)) * 8) + (g & 1) * 4;
    }

    for (int kt = 0; kt <= qb; ++kt) {
        const int cur = kt & 1, nxt = cur ^ 1;
        // prefetch next tile's K/V early: covered by S^T + softmax + PV below.
        if (kt < qb) {
            #pragma unroll
            for (int c = 0; c < 2; ++c)
                stage16(Kz + (size_t)((kt + 1) * 64 + c * 32 + srow) * 64 + colOff,
                        &Ks[nxt][c * 2048 + wbase]);
            #pragma unroll
            for (int c = 0; c < 2; ++c)
                stage16(Vz + (size_t)(c * 32 + srow) * 1024 + (kt + 1) * 64 + colOff,
                        &Vs[nxt][c * 2048 + wbase]);
        }

        // ---- S^T = K @ Q^T (per wave: kv 64 x q 16) -------------------
        f32x4 accs[4] = {};
        #pragma unroll
        for (int ks = 0; ks < 2; ++ks) {
            const int so = ks ? sq1 : sq0;
            bf16x8 af[4];
            #pragma unroll
            for (int mt = 0; mt < 4; ++mt)
                af[mt] = *(const bf16x8*)&Ks[cur][(mt * 16 + l16) * 64 + so];
            #pragma unroll
            for (int mt = 0; mt < 4; ++mt)
                accs[mt] = __builtin_amdgcn_mfma_f32_16x16x32_bf16(
                    af[mt], qf[ks], accs[mt], 0, 0, 0);
        }

        // ---- scale + causal mask + row max (q = l16) ------------------
        float sv[4][4];
        float mx = -1e30f;
        const bool diag = (kt == qb);
        #pragma unroll
        for (int mt = 0; mt < 4; ++mt)
            #pragma unroll
            for (int r = 0; r < 4; ++r) {
                int kv = mt * 16 + quad * 4 + r;     // within tile
                float s = accs[mt][r] * 0.125f;
                if (diag && kv > qrow) s = -1e30f;
                sv[mt][r] = s;
                mx = fmaxf(mx, s);
            }
        mx = fmaxf(mx, __shfl_xor(mx, 16, 64));
        mx = fmaxf(mx, __shfl_xor(mx, 32, 64));

        const float m_new = fmaxf(m_run, mx);
        const float sc    = __expf(m_run - m_new);

        // ---- P = exp(S - m_new), tile sum -----------------------------
        float tsum = 0.f;
        u16 pb[4][4];
        #pragma unroll
        for (int mt = 0; mt < 4; ++mt)
            #pragma unroll
            for (int r = 0; r < 4; ++r) {
                float p = (sv[mt][r] > -1e29f) ? __expf(sv[mt][r] - m_new) : 0.f;
                tsum += p;
                pb[mt][r] = f2b(p);
            }
        tsum += __shfl_xor(tsum, 16, 64);
        tsum += __shfl_xor(tsum, 32, 64);
        l_run = l_run * sc + tsum;
        m_run = m_new;

        // ---- write P tile (per-wave, b64, swizzled) -------------------
        #pragma unroll
        for (int mt = 0; mt < 4; ++mt) {
            ushort4 pk = { pb[mt][0], pb[mt][1], pb[mt][2], pb[mt][3] };
            *(ushort4*)&Pw[pwa[mt]] = pk;
        }

        // ---- rescale O by sc (per O-row q' = quad*4+r) ----------------
        #pragma unroll
        for (int r = 0; r < 4; ++r) {
            float scr = __shfl(sc, quad * 4 + r, 64);
            #pragma unroll
            for (int nt = 0; nt < 4; ++nt) acc_o[nt][r] *= scr;
        }

        // ---- O += P @ V  (A = P rows q, B = Vt rows d) ----------------
        #pragma unroll
        for (int ks = 0; ks < 2; ++ks) {
            const int so = ks ? sq1 : sq0;
            bf16x8 pf = *(const bf16x8*)&Pw[l16 * 64 + so];
            bf16x8 vf[4];
            #pragma unroll
            for (int nt = 0; nt < 4; ++nt)
                vf[nt] = *(const bf16x8*)&Vs[cur][(nt * 16 + l16) * 64 + so];
            #pragma unroll
            for (int nt = 0; nt < 4; ++nt)
                acc_o[nt] = __builtin_amdgcn_mfma_f32_16x16x32_bf16(
                    pf, vf[nt], acc_o[nt], 0, 0, 0);
        }

        // one barrier per tile: drains the prefetch AND guarantees all waves
        // are done reading Ks/Vs[cur] before iteration kt+1 overwrites them.
        __syncthreads();
    }

    // epilogue: O /= l (l indexed by q=l16 -> shfl), write omat
    const float linv = 1.0f / l_run;
    const int qg0 = qb * 64 + w * 16;
    #pragma unroll
    for (int r = 0; r < 4; ++r) {
        float li = __shfl(linv, quad * 4 + r, 64);
        int row = qg0 + quad * 4 + r;
        size_t obase = ((size_t)(z >> 4) * T_ + row) * D_ + (z & 15) * HD_;
        #pragma unroll
        for (int nt = 0; nt < 4; ++nt)
            omat[obase + nt * 16 + l16] = f2b(acc_o[nt][r] * li);
    }
}

// ---------------------------------------------------------------------------
// gates+w_v GEMM: C[2048,18432] = h2[2048,1024] x waT[18432,1024]^T.
// m97-structure (stable anchor: 91.9/93.0/92.9 us, 0 conflicts): 128x192,
// BK=64, 256 threads (4 waves 2x2, wave tile 64x96), single-buffered 40 KB,
// 3 blocks/CU, grid 96x16 = 1536 blocks = 2 exact fill-waves.
// Swizzle: 16B slot phys = logical ^ (row&7).
// Epilogue: cg<1088 -> gates [chain][t][272] bf16; else vvT fp32.
// ---------------------------------------------------------------------------
__global__ __launch_bounds__(256, 3) void gemm_gates128(
    const u16* __restrict__ A, const u16* __restrict__ Bt,
    u16* __restrict__ gates, float* __restrict__ vvT)
{
    constexpr int K = 1024;
    constexpr int NTILE = 16;                    // K / 64

    // bijective XCD swizzle: 1536 blocks, 192/XCD = 12 bx x 16 by, by innermost
    const int f = blockIdx.y * gridDim.x + blockIdx.x;
    const int xcd = f & 7, k8 = f >> 3;          // k8 in [0,192)
    const int by = k8 & 15;
    const int bx = xcd * 12 + (k8 >> 4);
    const int m0 = by * 128;
    const int n0 = bx * 192;

    __shared__ alignas(16) u16 As[128 * 64];     // 16 KB
    __shared__ alignas(16) u16 Bs[192 * 64];     // 24 KB

    const int tid  = threadIdx.x;                // 0..255
    const int lane = tid & 63, w = tid >> 6;     // 4 waves
    const int wr = w >> 1, wc = w & 1;           // 2 x 2 wave grid
    const int quad = lane >> 4, l16 = lane & 15;

    // staging: thread t -> row (t>>3) within each 32-row call group, physical
    // 16B slot (t&7); global source slot = (t&7) ^ (row&7)  (involution).
    const int colOff = (((tid & 7) ^ ((tid >> 3) & 7)) * 8);
    const u16* pA = A  + (size_t)(m0 + (tid >> 3)) * K + colOff;
    const u16* pB = Bt + (size_t)(n0 + (tid >> 3)) * K + colOff;
    const int wbase = w * 512;                   // wave-uniform LDS dest (u16)

    // ds-read bases (u16): row*64 + phys_slot*8; phys = (kstep*4+quad)^(l16&7)
    const int sq0 = quad ^ (l16 & 7);
    const int sq1 = sq0 ^ 4;
    const int aoff0 = (wr * 64 + l16) * 64 + sq0 * 8;
    const int aoff1 = (wr * 64 + l16) * 64 + sq1 * 8;
    const int boff0 = (wc * 96 + l16) * 64 + sq0 * 8;
    const int boff1 = (wc * 96 + l16) * 64 + sq1 * 8;

    f32x4 acc[4][6] = {};                        // [mt][nt] wave tile 64x96

    #pragma unroll 1
    for (int t = 0; t < NTILE; ++t) {
        const int kc = t * 64;
        // stage A (4 calls x 32 rows) + B (6 calls x 32 rows)
        #pragma unroll
        for (int c = 0; c < 4; ++c)
            stage16(pA + (size_t)(c * 32) * K + kc, &As[c * 2048 + wbase]);
        #pragma unroll
        for (int c = 0; c < 6; ++c)
            stage16(pB + (size_t)(c * 32) * K + kc, &Bs[c * 2048 + wbase]);
        __syncthreads();

        bf16x8 af[4], bfr[6];
        // kstep 0 (k 0..31)
        #pragma unroll
        for (int mt = 0; mt < 4; ++mt) af[mt]  = *(const bf16x8*)&As[aoff0 + mt * 1024];
        #pragma unroll
        for (int nt = 0; nt < 6; ++nt) bfr[nt] = *(const bf16x8*)&Bs[boff0 + nt * 1024];
        #pragma unroll
        for (int mt = 0; mt < 4; ++mt)
            #pragma unroll
            for (int nt = 0; nt < 6; ++nt)
                acc[mt][nt] = __builtin_amdgcn_mfma_f32_16x16x32_bf16(
                    af[mt], bfr[nt], acc[mt][nt], 0, 0, 0);
        // kstep 1 (k 32..63)
        #pragma unroll
        for (int mt = 0; mt < 4; ++mt) af[mt]  = *(const bf16x8*)&As[aoff1 + mt * 1024];
        #pragma unroll
        for (int nt = 0; nt < 6; ++nt) bfr[nt] = *(const bf16x8*)&Bs[boff1 + nt * 1024];
        #pragma unroll
        for (int mt = 0; mt < 4; ++mt)
            #pragma unroll
            for (int nt = 0; nt < 6; ++nt)
                acc[mt][nt] = __builtin_amdgcn_mfma_f32_16x16x32_bf16(
                    af[mt], bfr[nt], acc[mt][nt], 0, 0, 0);
        __syncthreads();
    }

    // Epilogue: row = m0 + wr*64 + mt*16 + quad*4 + r
    //           col-group cg = bx*12 + wc*6 + nt (lane-uniform), col = cg*16+l16
    const int cgbase = bx * 12 + wc * 6;
    #pragma unroll
    for (int mt = 0; mt < 4; ++mt) {
        #pragma unroll
        for (int r = 0; r < 4; ++r) {
            int row = m0 + wr * 64 + mt * 16 + quad * 4 + r;
            int tt = row & (T_ - 1), bb = row >> 10;
            #pragma unroll
            for (int nt = 0; nt < 6; ++nt) {
                int cg = cgbase + nt;
                float val = acc[mt][nt][r];
                if (cg >= 1088) {
                    vvT[(((size_t)(bb * 64 + (cg - 1088))) * T_ + tt) * 16 + l16] = val;
                } else {
                    int hh = cg / 17, rem = cg - hh * 17;
                    gates[(((size_t)(bb * 64 + hh)) * T_ + tt) * 272 + rem * 16 + l16] = f2b(val);
                }
            }
        }
    }
}

// ---------------------------------------------------------------------------
__global__ __launch_bounds__(256) void rmsnorm_k(
    const float* __restrict__ x, const float* __restrict__ w, u16* __restrict__ out)
{
    const int row = blockIdx.x, tid = threadIdx.x;
    float4 v = ((const float4*)(x + (size_t)row * D_))[tid];
    float ss = v.x * v.x + v.y * v.y + v.z * v.z + v.w * v.w;
    #pragma unroll
    for (int o = 32; o >= 1; o >>= 1) ss += __shfl_xor(ss, o, 64);
    __shared__ float red[4];
    if ((tid & 63) == 0) red[tid >> 6] = ss;
    __syncthreads();
    ss = red[0] + red[1] + red[2] + red[3];
    float scale = rsqrtf(ss * (1.0f / D_) + 1e-5f);
    float4 wv = ((const float4*)w)[tid];
    ushort4 o4;
    o4.x = f2b(v.x * scale * wv.x);
    o4.y = f2b(v.y * scale * wv.y);
    o4.z = f2b(v.z * scale * wv.z);
    o4.w = f2b(v.w * scale * wv.w);
    ((ushort4*)(out + (size_t)row * D_))[tid] = o4;
}

// ---------------------------------------------------------------------------
// All weight converts in one launch. Segments by blockIdx.x (all R=1024):
//   [0,96)   wqkv C=3072 -> wqkvT
//   [96,128) wao  C=1024 -> waoT
//   [128,160)wv   C=1024 -> waT + 17408*1024 (contiguous with waT)
//   [160,704)wa   C=17408-> waT
//   [704,736)wop  C=1024 -> wopT
// ---------------------------------------------------------------------------
__global__ void convT_all(
    const float* __restrict__ wqkv, const float* __restrict__ wao,
    const float* __restrict__ wv,   const float* __restrict__ wa,
    const float* __restrict__ wop,
    u16* __restrict__ wqkvT, u16* __restrict__ waoT,
    u16* __restrict__ waT,   u16* __restrict__ wopT)
{
    const int x = blockIdx.x;
    const float* in; u16* out; int C, xb;
    if (x < 96)       { in = wqkv; out = wqkvT; C = 3072;  xb = x; }
    else if (x < 128) { in = wao;  out = waoT;  C = 1024;  xb = x - 96; }
    else if (x < 160) { in = wv;   out = waT + (size_t)17408 * 1024; C = 1024; xb = x - 128; }
    else if (x < 704) { in = wa;   out = waT;   C = 17408; xb = x - 160; }
    else              { in = wop;  out = wopT;  C = 1024;  xb = x - 704; }
    constexpr int R = 1024;
    __shared__ float tile[32][33];
    const int c0 = xb * 32, r0 = blockIdx.y * 32;
    const int tx = threadIdx.x, ty = threadIdx.y;
    #pragma unroll
    for (int k = 0; k < 4; ++k)
        tile[ty + 8 * k][tx] = in[(size_t)(r0 + ty + 8 * k) * C + c0 + tx];
    __syncthreads();
    #pragma unroll
    for (int k = 0; k < 4; ++k)
        out[(size_t)(c0 + ty + 8 * k) * R + r0 + tx] = f2b(tile[tx][ty + 8 * k]);
}

__global__ void transpose_bf16_k(const u16* __restrict__ in_, u16* __restrict__ out_, int R, int C)
{
    __shared__ u16 tile[32][33];
    const u16* in = in_ + (size_t)blockIdx.z * R * C;
    u16* out      = out_ + (size_t)blockIdx.z * R * C;
    const int c0 = blockIdx.x * 32, r0 = blockIdx.y * 32;
    const int tx = threadIdx.x, ty = threadIdx.y;
    #pragma unroll
    for (int k = 0; k < 4; ++k)
        tile[ty + 8 * k][tx] = in[(size_t)(r0 + ty + 8 * k) * C + c0 + tx];
    __syncthreads();
    #pragma unroll
    for (int k = 0; k < 4; ++k)
        out[(size_t)(c0 + ty + 8 * k) * R + r0 + tx] = tile[tx][ty + 8 * k];
}

// ---------------------------------------------------------------------------
// Scan-chunk prep (shared by p1/p2): raw gate logits for a 32-step chunk in
// glds (32 x 16 rows x 17 bf16 @ 34 B). Softmax each row, repack the 16
// A-entries in place to (st*16+i)*32 B (bf16), scale vlds (v -> a0*v).
// ---------------------------------------------------------------------------
__device__ __forceinline__ void scan_prep(u16* glds, float* vlds, int lane)
{
    #pragma unroll
    for (int rnd = 0; rnd < 2; ++rnd) {
        float p[4][17];
        #pragma unroll
        for (int j = 0; j < 4; ++j) {
            int r = rnd * 256 + j * 64 + lane;
            const u16* g = &glds[r * 17];
            float vv[17];
            float mx = -1e30f;
            #pragma unroll
            for (int tt = 0; tt < 17; ++tt) { vv[tt] = b2f(g[tt]); mx = fmaxf(mx, vv[tt]); }
            float s = 0.f;
            #pragma unroll
            for (int tt = 0; tt < 17; ++tt) { vv[tt] = __expf(vv[tt] - mx); s += vv[tt]; }
            float inv = 1.0f / s;
            #pragma unroll
            for (int tt = 0; tt < 17; ++tt) p[j][tt] = vv[tt] * inv;
        }
        __syncthreads();
        #pragma unroll
        for (int j = 0; j < 4; ++j) {
            int r = rnd * 256 + j * 64 + lane;
            uint4 w0, w1;
            w0.x = (u32)f2b(p[j][1])  | ((u32)f2b(p[j][2])  << 16);
            w0.y = (u32)f2b(p[j][3])  | ((u32)f2b(p[j][4])  << 16);
            w0.z = (u32)f2b(p[j][5])  | ((u32)f2b(p[j][6])  << 16);
            w0.w = (u32)f2b(p[j][7])  | ((u32)f2b(p[j][8])  << 16);
            w1.x = (u32)f2b(p[j][9])  | ((u32)f2b(p[j][10]) << 16);
            w1.y = (u32)f2b(p[j][11]) | ((u32)f2b(p[j][12]) << 16);
            w1.z = (u32)f2b(p[j][13]) | ((u32)f2b(p[j][14]) << 16);
            w1.w = (u32)f2b(p[j][15]) | ((u32)f2b(p[j][16]) << 16);
            ((uint4*)glds)[r * 2]     = w0;
            ((uint4*)glds)[r * 2 + 1] = w1;
            vlds[r] *= p[j][0];
        }
        __syncthreads();
    }
}

// ---------------------------------------------------------------------------
// scan pass 1: per chunk of 32 steps compute P_c = A_31..A_0, e_c.
// ---------------------------------------------------------------------------
__global__ __launch_bounds__(64) void scan_p1(
    const u16* __restrict__ gates, const float* __restrict__ vvT,
    float* __restrict__ Pmat, float* __restrict__ evec)
{
    const int c = blockIdx.x, chain = blockIdx.y;
    const int lane = threadIdx.x;
    const int i = lane >> 2, q = lane & 3;
    __shared__ alignas(16) u16   glds[32 * 272];
    __shared__ alignas(16) float vlds[32 * 16];
    __shared__ alignas(16) float Pb[2][256];
    __shared__ float slds[16];

    const char* gbase = (const char*)(gates + ((size_t)chain * T_ + c * 32) * 272);
    #pragma unroll
    for (int it = 0; it < 17; ++it)
        stage16(gbase + it * 1024 + lane * 16, (char*)glds + it * 1024);
    const char* vbase = (const char*)(vvT + ((size_t)chain * T_ + c * 32) * 16);
    #pragma unroll
    for (int it = 0; it < 2; ++it)
        stage16(vbase + it * 1024 + lane * 16, (char*)vlds + it * 1024);
    __syncthreads();

    scan_prep(glds, vlds, lane);

    {
        f32x4 idq;
        #pragma unroll
        for (int m = 0; m < 4; ++m) idq[m] = (i == q * 4 + m) ? 1.f : 0.f;
        *(f32x4*)&Pb[0][i * 16 + q * 4] = idq;
    }
    f32x4 e4[4] = {};
    f32x4 np = {};
    float neLast = 0.f;
    int cur = 0;

    for (int st = 0; st < 32; ++st) {
        const uint4* rp = (const uint4*)((const char*)glds + (st * 16 + i) * 32);
        uint4 d0 = rp[0], d1 = rp[1];
        float ar[16];
        ar[0]  = blo(d0.x); ar[1]  = bhi(d0.x);
        ar[2]  = blo(d0.y); ar[3]  = bhi(d0.y);
        ar[4]  = blo(d0.z); ar[5]  = bhi(d0.z);
        ar[6]  = blo(d0.w); ar[7]  = bhi(d0.w);
        ar[8]  = blo(d1.x); ar[9]  = bhi(d1.x);
        ar[10] = blo(d1.y); ar[11] = bhi(d1.y);
        ar[12] = blo(d1.z); ar[13] = bhi(d1.z);
        ar[14] = blo(d1.w); ar[15] = bhi(d1.w);

        f32x4 pk[16];
        #pragma unroll
        for (int k = 0; k < 16; ++k)
            pk[k] = *(const f32x4*)&Pb[cur][k * 16 + q * 4];

        f32x4 a = pk[0] * ar[0];
        #pragma unroll
        for (int k = 1; k < 16; ++k) a += pk[k] * ar[k];
        np = a;

        float ne0 = ar[0] * e4[0][0] + ar[1] * e4[0][1] + ar[2] * e4[0][2] + ar[3] * e4[0][3];
        float ne1 = ar[4] * e4[1][0] + ar[5] * e4[1][1] + ar[6] * e4[1][2] + ar[7] * e4[1][3];
        float ne2 = ar[8] * e4[2][0] + ar[9] * e4[2][1] + ar[10] * e4[2][2] + ar[11] * e4[2][3];
        float ne3 = ar[12] * e4[3][0] + ar[13] * e4[3][1] + ar[14] * e4[3][2] + ar[15] * e4[3][3];
        float ne = (ne0 + ne1) + (ne2 + ne3) + vlds[st * 16 + i];

        *(f32x4*)&Pb[cur ^ 1][i * 16 + q * 4] = np;
        if (q == 0) slds[i] = ne;
        #pragma unroll
        for (int m = 0; m < 4; ++m) e4[m] = *(const f32x4*)&slds[m * 4];
        neLast = ne;
        cur ^= 1;
    }

    float* Pd = Pmat + ((size_t)chain * 32 + c) * 256;
    *(f32x4*)&Pd[i * 16 + q * 4] = np;
    if (q == 0) evec[((size_t)chain * 32 + c) * 16 + i] = neLast;
}

// ---------------------------------------------------------------------------
// scan pass 2: per chain, sequentially combine 32 chunks; sIn[c] = entry state.
// ---------------------------------------------------------------------------
__global__ __launch_bounds__(64) void scan_comb(
    const float* __restrict__ Pmat, const float* __restrict__ evec, float* __restrict__ sIn)
{
    const int chain = blockIdx.x;
    const int lane = threadIdx.x;
    const int i = lane >> 2, q = lane & 3;
    __shared__ alignas(16) float Pl[32 * 256];
    __shared__ alignas(16) float El[32 * 16];
    __shared__ float slds[16];

    const char* Pg = (const char*)(Pmat + (size_t)chain * 32 * 256);
    #pragma unroll
    for (int it = 0; it < 32; ++it)
        stage16(Pg + it * 1024 + lane * 16, (char*)Pl + it * 1024);
    const char* Eg = (const char*)(evec + (size_t)chain * 32 * 16);
    #pragma unroll
    for (int it = 0; it < 2; ++it)
        stage16(Eg + it * 1024 + lane * 16, (char*)El + it * 1024);
    __syncthreads();

    f32x4 s4[4] = {};
    if (q == 0) sIn[((size_t)chain * 32 + 0) * 16 + i] = 0.f;
    for (int cc = 0; cc < 32; ++cc) {
        f32x4 pr[4];
        #pragma unroll
        for (int m = 0; m < 4; ++m)
            pr[m] = *(const f32x4*)&Pl[cc * 256 + i * 16 + m * 4];
        float ne = 0.f;
        #pragma unroll
        for (int k = 0; k < 16; ++k) ne += pr[k >> 2][k & 3] * s4[k >> 2][k & 3];
        ne += El[cc * 16 + i];
        if (q == 0) {
            slds[i] = ne;
            if (cc < 31) sIn[((size_t)chain * 32 + cc + 1) * 16 + i] = ne;
        }
        #pragma unroll
        for (int m = 0; m < 4; ++m) s4[m] = *(const f32x4*)&slds[m * 4];
    }
}

// ---------------------------------------------------------------------------
// scan pass 3: replay each chunk from its entry state, write h_out.
// ---------------------------------------------------------------------------
__global__ __launch_bounds__(64) void scan_p2(
    const u16* __restrict__ gates, const float* __restrict__ vvT,
    const float* __restrict__ sIn, u16* __restrict__ hout)
{
    const int c = blockIdx.x, chain = blockIdx.y;
    const int b = chain >> 6, hh = chain & 63;
    const int lane = threadIdx.x;
    const int i = lane >> 2, q = lane & 3;
    __shared__ alignas(16) u16   glds[32 * 272];
    __shared__ alignas(16) float vlds[32 * 16];
    __shared__ float slds[16];

    const char* gbase = (const char*)(gates + ((size_t)chain * T_ + c * 32) * 272);
    #pragma unroll
    for (int it = 0; it < 17; ++it)
        stage16(gbase + it * 1024 + lane * 16, (char*)glds + it * 1024);
    const char* vbase = (const char*)(vvT + ((size_t)chain * T_ + c * 32) * 16);
    #pragma unroll
    for (int it = 0; it < 2; ++it)
        stage16(vbase + it * 1024 + lane * 16, (char*)vlds + it * 1024);
    __syncthreads();

    scan_prep(glds, vlds, lane);

    const float* sp = sIn + ((size_t)chain * 32 + c) * 16;
    f32x4 s4[4];
    #pragma unroll
    for (int m = 0; m < 4; ++m) s4[m] = *(const f32x4*)(sp + m * 4);

    u16* hbase = hout + ((size_t)(b * T_ + c * 32)) * D_ + hh * 16;
    for (int st = 0; st < 32; ++st) {
        const uint4* rp = (const uint4*)((const char*)glds + (st * 16 + i) * 32);
        uint4 d0 = rp[0], d1 = rp[1];
        float ne0 = blo(d0.x) * s4[0][0] + bhi(d0.x) * s4[0][1]
                  + blo(d0.y) * s4[0][2] + bhi(d0.y) * s4[0][3];
        float ne1 = blo(d0.z) * s4[1][0] + bhi(d0.z) * s4[1][1]
                  + blo(d0.w) * s4[1][2] + bhi(d0.w) * s4[1][3];
        float ne2 = blo(d1.x) * s4[2][0] + bhi(d1.x) * s4[2][1]
                  + blo(d1.y) * s4[2][2] + bhi(d1.y) * s4[2][3];
        float ne3 = blo(d1.z) * s4[3][0] + bhi(d1.z) * s4[3][1]
                  + blo(d1.w) * s4[3][2] + bhi(d1.w) * s4[3][3];
        float ne = (ne0 + ne1) + (ne2 + ne3) + vlds[st * 16 + i];
        if (q == 0) {
            slds[i] = ne;
            hbase[(size_t)st * D_ + i] = f2b(ne);
        }
        #pragma unroll
        for (int m = 0; m < 4; ++m) s4[m] = *(const f32x4*)&slds[m * 4];
    }
}

// ---------------------------------------------------------------------------
extern "C" void kernel_launch(void* const* d_in, const int* in_sizes, int n_in,
                              void* d_out, int out_size, void* d_ws, size_t ws_size,
                              hipStream_t stream)
{
    const float* x    = (const float*)d_in[0];
    const float* anw  = (const float*)d_in[1];
    const float* wqkv = (const float*)d_in[2];
    const float* wao  = (const float*)d_in[3];
    const float* lnw  = (const float*)d_in[4];
    const float* wv   = (const float*)d_in[5];
    const float* wa   = (const float*)d_in[6];
    const float* wop  = (const float*)d_in[7];

    char* ws = (char*)d_ws;
    const size_t MB = 1u << 20;
    u16*   h     = (u16*)  (ws +   0 * MB);   //  4 MB
    u16*   h2    = (u16*)  (ws +   4 * MB);   //  4 MB
    u16*   wqkvT = (u16*)  (ws +   8 * MB);   //  6 MB
    u16*   waoT  = (u16*)  (ws +  14 * MB);   //  2 MB
    u16*   wopT  = (u16*)  (ws +  16 * MB);   //  2 MB
    u16*   waT   = (u16*)  (ws +  18 * MB);   // 36 MB (wa 17408 rows + wv 1024 rows)
    float* x2    = (float*)(ws +  54 * MB);   //  8 MB
    float* vvT   = (float*)(ws +  62 * MB);   //  8 MB scan layout [chain][t][16]
    u16*   Qb    = (u16*)  (ws +  78 * MB);   //  4 MB (dead after attn)
    float* Pmat  = (float*)(ws +  78 * MB);   //  4 MB aliases Qb
    u16*   Kb    = (u16*)  (ws +  82 * MB);   //  4 MB (dead after attn)
    float* evec  = (float*)(ws +  82 * MB);   // 256 KB aliases Kb
    float* sIn   = (float*)(ws +  82 * MB + 256 * 1024); // 256 KB
    u16*   Vb    = (u16*)  (ws +  86 * MB);   //  4 MB (dead after transpose)
    u16*   Vt    = (u16*)  (ws +  90 * MB);   //  4 MB (dead after attn)
    u16*   omat  = (u16*)  (ws + 158 * MB);   //  4 MB (dead after attn_out)
    u16*   gates = (u16*)  (ws +  94 * MB);   // 68 MB aliases old S region
    u16*   hout  = (u16*)  (ws + 162 * MB);   //  4 MB (end: 166 MB)
    (void)in_sizes; (void)n_in; (void)out_size; (void)ws_size;

    dim3 tb(32, 8);
    convT_all<<<dim3(736, 32), tb, 0, stream>>>(
        wqkv, wao, wv, wa, wop, wqkvT, waoT, waT, wopT);

    rmsnorm_k<<<2048, 256, 0, stream>>>(x, anw, h);
    // qkv GEMM with fused RoPE epilogue -> Qb, Kb, Vb directly (BK=64)
    gemm_bt<64, 128, 64, 6, false, false, 0><<<dim3(24, 32, 1), 256, 0, stream>>>(
        h, wqkvT, (void*)Qb, (void*)Kb, (void*)Vb, nullptr, 2048, 3072, 1024, 0, 0, 0);
    transpose_bf16_k<<<dim3(2, 32, 32), tb, 0, stream>>>(Vb, Vt, 1024, 64);

    // fused flash attention (double-buffered): QK^T + softmax + PV, 1 launch
    attn_flash<<<512, 256, 0, stream>>>(Qb, Kb, Vt, omat);

    gemm_bt<64, 128, 64, 0, false, false, 0><<<dim3(8, 32, 1), 256, 0, stream>>>(
        omat, waoT, (void*)x2, nullptr, nullptr, x, 2048, 1024, 1024, 0, 0, 0);
    rmsnorm_k<<<2048, 256, 0, stream>>>(x2, lnw, h2);

    // fused gates + w_v GEMM: m97-structure 128x192, 1536 blocks, 3 blocks/CU
    gemm_gates128<<<dim3(96, 16), 256, 0, stream>>>(h2, waT, gates, vvT);

    scan_p1<<<dim3(32, 128), 64, 0, stream>>>(gates, vvT, Pmat, evec);
    scan_comb<<<128, 64, 0, stream>>>(Pmat, evec, sIn);
    scan_p2<<<dim3(32, 128), 64, 0, stream>>>(gates, vvT, sIn, hout);

    gemm_bt<64, 128, 64, 0, false, false, 0><<<dim3(8, 32, 1), 256, 0, stream>>>(
        hout, wopT, d_out, nullptr, nullptr, x2, 2048, 1024, 1024, 0, 0, 0);
}

// Round 12
// 437.146 us; speedup vs baseline: 1.1808x; 1.0235x over previous
//
#include <hip/hip_runtime.h>

// HKSABlock on MI355X (gfx950). Round 18: qkv GEMM tile 64x128 -> 128x128
// (m92 tile curve: 64-row tiles ~343-500 TF vs 517-900 at 128^2; qkv is the
// biggest non-gates GEMM at 12.9 GFLOP) + RoPE cos/sin table (G13: on-device
// sincosf is ~20+ VALU ops x 32/thread in the MODE-6 epilogue; table = one
// 8B coalesced load, bit-identical values). Table lives in the gates region
// (free until gemm_gates128). Everything else byte-identical to R17
// (447.4 us; gates canary 93.5-94.2 / 36% / 0 conflicts).
// B=2, T=1024, D=1024, NH=16, HD=64, H=64, M=16.

typedef unsigned short u16;
typedef unsigned int   u32;
typedef __bf16 bf16x8 __attribute__((ext_vector_type(8)));
typedef float  f32x4  __attribute__((ext_vector_type(4)));

#define B_  2
#define T_  1024
#define D_  1024
#define NH_ 16
#define HD_ 64
#define H_  64
#define M_  16

__device__ __forceinline__ float b2f(u16 u) {
    return __uint_as_float(((u32)u) << 16);
}
__device__ __forceinline__ u16 f2b(float f) {
    u32 u = __float_as_uint(f);
    u32 r = (u + 0x7FFFu + ((u >> 16) & 1u)) >> 16;  // RNE
    return (u16)r;
}
__device__ __forceinline__ float blo(u32 u) { return __uint_as_float(u << 16); }
__device__ __forceinline__ float bhi(u32 u) { return __uint_as_float(u & 0xFFFF0000u); }

// Async global->LDS, 16 B per lane. LDS dest must be wave-uniform base.
__device__ __forceinline__ void stage16(const void* gp, void* lp) {
    typedef __attribute__((address_space(1))) const unsigned int GU;
    typedef __attribute__((address_space(3))) unsigned int LU;
    __builtin_amdgcn_global_load_lds((GU*)gp, (LU*)lp, 16, 0, 0);
}

// ---------------------------------------------------------------------------
// RoPE table: tab[t][i] = (cos, sin) of t * 10000^(-i/32), t<1024, i<32.
// Same sincosf as the old inline epilogue path -> bit-identical results.
// ---------------------------------------------------------------------------
__global__ void rope_tab_k(float2* __restrict__ tab)
{
    const int idx = blockIdx.x * 256 + threadIdx.x;   // 0..32767
    const int t = idx >> 5, i = idx & 31;
    float ang = (float)t * exp2f(-(float)i * 0.41524101186092034f);
    float sn, cs;
    sincosf(ang, &sn, &cs);
    tab[idx] = make_float2(cs, sn);
}

// ---------------------------------------------------------------------------
// Generic MFMA GEMM: C[M,N] = A[M,K] * Bt[N,K]^T  (A,Bt bf16 row-major).
// BK = 64 (required). 4 waves: wr = w>>1 (m-half), wc = w&1 (n-half).
// Staging: 32-row groups, thread t -> row (t>>3), phys slot (t&7), global
// source slot = (t&7)^(row&7) (involution). Reads: phys = (ks*4+quad)^(l16&7)
// -> 0 LDS bank conflicts (verified R9-R17).
// MODE 0: C fp32 (+ optional fp32 addend). MODE 1: C bf16.
// MODE 2: bf16 scatter into o_mat[(b*T + row)*1024 + h*64 + col], z = b*16+h.
// MODE 6: qkv + fused RoPE. N=3072; region = n0>>10 (0=Q,1=K,2=V). BN=128
//         required (head mapping); RoPE pair (i,i+32) = acc nt and nt+2;
//         cos/sin from table passed via `addend` ([1024][32] float2).
//         Writes Qb(Cout)/Kb(Cout2)/Vb(Cout3) bf16 in (b,h,t,d).
// CAUSAL: skip blocks with n0 > m0+BM-1. TRUNCK: K truncated to m0+BM.
// ---------------------------------------------------------------------------
template<int BM, int BN, int BK, int MODE, bool TRUNCK, bool CAUSAL, int SWZ>
__global__ __launch_bounds__(256) void gemm_bt(
    const u16* __restrict__ A, const u16* __restrict__ Bt,
    void* __restrict__ Cout, void* __restrict__ Cout2, void* __restrict__ Cout3,
    const float* __restrict__ addend,
    int M, int N, int K, long strideA, long strideB, long strideC)
{
    static_assert(BK == 64, "gemm_bt requires BK=64");
    constexpr int MT = BM / 32;
    constexpr int NT = BN / 32;
    const int z  = blockIdx.z;
    const int bx = blockIdx.x, by = blockIdx.y;
    const int m0 = by * BM;
    const int n0 = bx * BN;
    if (CAUSAL && n0 > m0 + BM - 1) return;
    const int Keff = TRUNCK ? (K < m0 + BM ? K : m0 + BM) : K;

    const u16* Ab = A  + (size_t)z * (size_t)strideA;
    const u16* Bb = Bt + (size_t)z * (size_t)strideB;

    __shared__ alignas(16) u16 As[BM * 64];
    __shared__ alignas(16) u16 Bs[BN * 64];

    const int tid  = threadIdx.x;
    const int lane = tid & 63, w = tid >> 6;
    const int wr = w >> 1, wc = w & 1;
    const int quad = lane >> 4, l16 = lane & 15;

    // staging geometry (32 rows per call)
    const int srow   = tid >> 3;                          // 0..31
    const int colOff = (((tid & 7) ^ (srow & 7)) * 8);    // involution source slot
    const u16* pA = Ab + (size_t)(m0 + srow) * K + colOff;
    const u16* pB = Bb + (size_t)(n0 + srow) * K + colOff;
    const int wbase = w * 512;                            // wave-uniform dest (u16)

    // swizzled read slots: phys = (kstep*4 + quad) ^ (l16&7)
    const int sq0 = quad ^ (l16 & 7);
    const int sq1 = sq0 ^ 4;

    f32x4 acc[MT][NT] = {};

    for (int k0 = 0; k0 < Keff; k0 += 64) {
        #pragma unroll
        for (int c = 0; c < BM / 32; ++c)
            stage16(pA + (size_t)(c * 32) * K + k0, &As[c * 2048 + wbase]);
        #pragma unroll
        for (int c = 0; c < BN / 32; ++c)
            stage16(pB + (size_t)(c * 32) * K + k0, &Bs[c * 2048 + wbase]);
        __syncthreads();

        bf16x8 af[MT], bfr[NT];
        // kstep 0 (k 0..31 of tile)
        #pragma unroll
        for (int mt = 0; mt < MT; ++mt)
            af[mt] = *(const bf16x8*)&As[(wr * (BM / 2) + mt * 16 + l16) * 64 + sq0 * 8];
        #pragma unroll
        for (int nt = 0; nt < NT; ++nt)
            bfr[nt] = *(const bf16x8*)&Bs[(wc * (BN / 2) + nt * 16 + l16) * 64 + sq0 * 8];
        #pragma unroll
        for (int mt = 0; mt < MT; ++mt)
            #pragma unroll
            for (int nt = 0; nt < NT; ++nt)
                acc[mt][nt] = __builtin_amdgcn_mfma_f32_16x16x32_bf16(
                    af[mt], bfr[nt], acc[mt][nt], 0, 0, 0);
        // kstep 1 (k 32..63 of tile)
        #pragma unroll
        for (int mt = 0; mt < MT; ++mt)
            af[mt] = *(const bf16x8*)&As[(wr * (BM / 2) + mt * 16 + l16) * 64 + sq1 * 8];
        #pragma unroll
        for (int nt = 0; nt < NT; ++nt)
            bfr[nt] = *(const bf16x8*)&Bs[(wc * (BN / 2) + nt * 16 + l16) * 64 + sq1 * 8];
        #pragma unroll
        for (int mt = 0; mt < MT; ++mt)
            #pragma unroll
            for (int nt = 0; nt < NT; ++nt)
                acc[mt][nt] = __builtin_amdgcn_mfma_f32_16x16x32_bf16(
                    af[mt], bfr[nt], acc[mt][nt], 0, 0, 0);
        __syncthreads();
    }

    // Epilogue. C/D layout: col = lane&15, row = (lane>>4)*4 + reg  [m89]
    if (MODE == 6) {
        // dedicated RoPE epilogue (NT==4, BN==128 required)
        const float2* tab = (const float2*)addend;     // [1024][32] cos/sin
        const int reg = n0 >> 10;                      // 0=Q, 1=K, 2=V
        const int hh  = ((n0 & 1023) >> 6) + wc;       // head
        #pragma unroll
        for (int mt = 0; mt < MT; ++mt) {
            #pragma unroll
            for (int r = 0; r < 4; ++r) {
                int row = m0 + wr * (BM / 2) + mt * 16 + quad * 4 + r;
                int t = row & (T_ - 1), bb = row >> 10;
                size_t obase = ((size_t)(bb * NH_ + hh) * T_ + t) * HD_;
                if (reg == 2) {
                    #pragma unroll
                    for (int nt = 0; nt < 4; ++nt)
                        ((u16*)Cout3)[obase + nt * 16 + l16] = f2b(acc[mt][nt][r]);
                } else {
                    u16* dst = (reg == 0) ? (u16*)Cout : (u16*)Cout2;
                    #pragma unroll
                    for (int nt = 0; nt < 2; ++nt) {
                        int i = nt * 16 + l16;
                        float2 cssn = tab[t * 32 + i];
                        float q1 = acc[mt][nt][r], q2 = acc[mt][nt + 2][r];
                        dst[obase + i]      = f2b(q1 * cssn.x - q2 * cssn.y);
                        dst[obase + i + 32] = f2b(q2 * cssn.x + q1 * cssn.y);
                    }
                }
            }
        }
        return;
    }
    #pragma unroll
    for (int mt = 0; mt < MT; ++mt) {
        #pragma unroll
        for (int nt = 0; nt < NT; ++nt) {
            #pragma unroll
            for (int r = 0; r < 4; ++r) {
                int row = m0 + wr * (BM / 2) + mt * 16 + quad * 4 + r;
                int col = n0 + wc * (BN / 2) + nt * 16 + l16;
                float val = acc[mt][nt][r];
                if (MODE == 0) {
                    if (addend) val += addend[(size_t)row * N + col];
                    ((float*)Cout)[(size_t)z * (size_t)strideC + (size_t)row * N + col] = val;
                } else if (MODE == 1) {
                    ((u16*)Cout)[(size_t)z * (size_t)strideC + (size_t)row * N + col] = f2b(val);
                } else if (MODE == 2) {
                    size_t idx = ((size_t)(z >> 4) * T_ + row) * (size_t)D_ + (z & 15) * HD_ + col;
                    ((u16*)Cout)[idx] = f2b(val);
                }
            }
        }
    }
}

// ---------------------------------------------------------------------------
// Fused flash attention (double-buffered): omat = softmax(QK^T*0.125,causal)@V.
// Block = 64 q-rows of one (b,h) chain z; 4 waves, wave w owns q [w*16,+16).
// Per kv-tile: S^T via mfma(A=K-frag, B=Q-frag): q=l16 lane-fixed,
// kv=mt*16+quad*4+r; row softmax = 16 in-lane + shfl_xor(16,32).
// P bf16 -> per-wave Ps[16][64] via ds_write_b64, slot^(q&7) involution;
// same-wave readback as A-frag. O += mfma(A=P, B=Vt), fp32 acc, online
// rescale via shfl. Causal mask only on diagonal tile.
// DBUF: Ks/Vs[2] ping-pong; next tile's 4 stage16 issued at top of iter;
// ONE __syncthreads/tile. Balanced grid pairing: (qb+1)+(16-qb)=17.
// LDS: Qs 8K + Ks 16K + Vs 16K + Ps 8K = 48 KB.
// ---------------------------------------------------------------------------
__global__ __launch_bounds__(256) void attn_flash(
    const u16* __restrict__ Qb, const u16* __restrict__ Kb,
    const u16* __restrict__ Vt, u16* __restrict__ omat)
{
    const int f = blockIdx.x;
    const int u = f & 255, rr2 = f >> 8;
    const int z  = (rr2 == 0) ? (u >> 4) : 16 + (u >> 4);
    const int qb = (rr2 == 0) ? (u & 15) : 15 - (u & 15);

    const u16* Qz = Qb + (size_t)z * 65536;   // [1024 t][64 d]
    const u16* Kz = Kb + (size_t)z * 65536;   // [1024 t][64 d]
    const u16* Vz = Vt + (size_t)z * 65536;   // [64 d][1024 t]

    __shared__ alignas(16) u16 Qs[64 * 64];
    __shared__ alignas(16) u16 Ks[2][64 * 64];
    __shared__ alignas(16) u16 Vs[2][64 * 64];
    __shared__ alignas(16) u16 Ps[4][16 * 64];

    const int tid  = threadIdx.x;
    const int lane = tid & 63, w = tid >> 6;
    const int quad = lane >> 4, l16 = lane & 15;

    // staging geometry (32 rows per call): thread t -> row t>>3, phys slot t&7,
    // source slot = (t&7) ^ (row&7)  (involution, 0 conflicts R9-R17).
    const int srow   = tid >> 3;
    const int colOff = (((tid & 7) ^ (srow & 7)) * 8);
    const int wbase  = w * 512;               // wave-uniform LDS dest (u16)

    // prologue: stage Q tile + K/V tile 0, single drain
    #pragma unroll
    for (int c = 0; c < 2; ++c)
        stage16(Qz + (size_t)(qb * 64 + c * 32 + srow) * 64 + colOff,
                &Qs[c * 2048 + wbase]);
    #pragma unroll
    for (int c = 0; c < 2; ++c)
        stage16(Kz + (size_t)(c * 32 + srow) * 64 + colOff,
                &Ks[0][c * 2048 + wbase]);
    #pragma unroll
    for (int c = 0; c < 2; ++c)
        stage16(Vz + (size_t)(c * 32 + srow) * 1024 + colOff,
                &Vs[0][c * 2048 + wbase]);
    __syncthreads();

    // hoist Q B-frags: rows q = w*16 + l16, k-slot = ks*4+quad (swizzled)
    const int qrow = w * 16 + l16;
    bf16x8 qf[2];
    #pragma unroll
    for (int ks = 0; ks < 2; ++ks)
        qf[ks] = *(const bf16x8*)&Qs[qrow * 64 + (((ks * 4 + quad) ^ (l16 & 7)) * 8)];

    f32x4 acc_o[4] = {};                      // O[q 16][d 64]: nt frags, fp32
    float m_run = -1e30f, l_run = 0.f;        // per lane, q = l16

    const int sq0 = (quad ^ (l16 & 7)) * 8;   // swizzled k-slot bases (u16)
    const int sq1 = ((4 + quad) ^ (l16 & 7)) * 8;

    u16* Pw = &Ps[w][0];
    // P write addr: row q=l16; frag mt covers kv mt*16+quad*4+[0,4):
    //   8B granule g = mt*4+quad -> slot s8 = g>>1, half h = g&1
    //   addr_u16 = l16*64 + ((s8 ^ (l16&7))*8 + h*4)
    int pwa[4];
    #pragma unroll
    for (int mt = 0; mt < 4; ++mt) {
        int g = mt * 4 + quad;
        pwa[mt] = l16 * 64 + (((g >> 1) ^ (l16 & 7)) * 8) + (g & 1) * 4;
    }

    for (int kt = 0; kt <= qb; ++kt) {
        const int cur = kt & 1, nxt = cur ^ 1;
        // prefetch next tile's K/V early: covered by S^T + softmax + PV below.
        if (kt < qb) {
            #pragma unroll
            for (int c = 0; c < 2; ++c)
                stage16(Kz + (size_t)((kt + 1) * 64 + c * 32 + srow) * 64 + colOff,
                        &Ks[nxt][c * 2048 + wbase]);
            #pragma unroll
            for (int c = 0; c < 2; ++c)
                stage16(Vz + (size_t)(c * 32 + srow) * 1024 + (kt + 1) * 64 + colOff,
                        &Vs[nxt][c * 2048 + wbase]);
        }

        // ---- S^T = K @ Q^T (per wave: kv 64 x q 16) -------------------
        f32x4 accs[4] = {};
        #pragma unroll
        for (int ks = 0; ks < 2; ++ks) {
            const int so = ks ? sq1 : sq0;
            bf16x8 af[4];
            #pragma unroll
            for (int mt = 0; mt < 4; ++mt)
                af[mt] = *(const bf16x8*)&Ks[cur][(mt * 16 + l16) * 64 + so];
            #pragma unroll
            for (int mt = 0; mt < 4; ++mt)
                accs[mt] = __builtin_amdgcn_mfma_f32_16x16x32_bf16(
                    af[mt], qf[ks], accs[mt], 0, 0, 0);
        }

        // ---- scale + causal mask + row max (q = l16) ------------------
        float sv[4][4];
        float mx = -1e30f;
        const bool diag = (kt == qb);
        #pragma unroll
        for (int mt = 0; mt < 4; ++mt)
            #pragma unroll
            for (int r = 0; r < 4; ++r) {
                int kv = mt * 16 + quad * 4 + r;     // within tile
                float s = accs[mt][r] * 0.125f;
                if (diag && kv > qrow) s = -1e30f;
                sv[mt][r] = s;
                mx = fmaxf(mx, s);
            }
        mx = fmaxf(mx, __shfl_xor(mx, 16, 64));
        mx = fmaxf(mx, __shfl_xor(mx, 32, 64));

        const float m_new = fmaxf(m_run, mx);
        const float sc    = __expf(m_run - m_new);

        // ---- P = exp(S - m_new), tile sum -----------------------------
        float tsum = 0.f;
        u16 pb[4][4];
        #pragma unroll
        for (int mt = 0; mt < 4; ++mt)
            #pragma unroll
            for (int r = 0; r < 4; ++r) {
                float p = (sv[mt][r] > -1e29f) ? __expf(sv[mt][r] - m_new) : 0.f;
                tsum += p;
                pb[mt][r] = f2b(p);
            }
        tsum += __shfl_xor(tsum, 16, 64);
        tsum += __shfl_xor(tsum, 32, 64);
        l_run = l_run * sc + tsum;
        m_run = m_new;

        // ---- write P tile (per-wave, b64, swizzled) -------------------
        #pragma unroll
        for (int mt = 0; mt < 4; ++mt) {
            ushort4 pk = { pb[mt][0], pb[mt][1], pb[mt][2], pb[mt][3] };
            *(ushort4*)&Pw[pwa[mt]] = pk;
        }

        // ---- rescale O by sc (per O-row q' = quad*4+r) ----------------
        #pragma unroll
        for (int r = 0; r < 4; ++r) {
            float scr = __shfl(sc, quad * 4 + r, 64);
            #pragma unroll
            for (int nt = 0; nt < 4; ++nt) acc_o[nt][r] *= scr;
        }

        // ---- O += P @ V  (A = P rows q, B = Vt rows d) ----------------
        #pragma unroll
        for (int ks = 0; ks < 2; ++ks) {
            const int so = ks ? sq1 : sq0;
            bf16x8 pf = *(const bf16x8*)&Pw[l16 * 64 + so];
            bf16x8 vf[4];
            #pragma unroll
            for (int nt = 0; nt < 4; ++nt)
                vf[nt] = *(const bf16x8*)&Vs[cur][(nt * 16 + l16) * 64 + so];
            #pragma unroll
            for (int nt = 0; nt < 4; ++nt)
                acc_o[nt] = __builtin_amdgcn_mfma_f32_16x16x32_bf16(
                    pf, vf[nt], acc_o[nt], 0, 0, 0);
        }

        // one barrier per tile: drains the prefetch AND guarantees all waves
        // are done reading Ks/Vs[cur] before iteration kt+1 overwrites them.
        __syncthreads();
    }

    // epilogue: O /= l (l indexed by q=l16 -> shfl), write omat
    const float linv = 1.0f / l_run;
    const int qg0 = qb * 64 + w * 16;
    #pragma unroll
    for (int r = 0; r < 4; ++r) {
        float li = __shfl(linv, quad * 4 + r, 64);
        int row = qg0 + quad * 4 + r;
        size_t obase = ((size_t)(z >> 4) * T_ + row) * D_ + (z & 15) * HD_;
        #pragma unroll
        for (int nt = 0; nt < 4; ++nt)
            omat[obase + nt * 16 + l16] = f2b(acc_o[nt][r] * li);
    }
}

// ---------------------------------------------------------------------------
// gates+w_v GEMM: C[2048,18432] = h2[2048,1024] x waT[18432,1024]^T.
// m97-structure (stable anchor: 91.9-94.2 us, 0 conflicts): 128x192, BK=64,
// 256 threads (4 waves 2x2, wave tile 64x96), single-buffered 40 KB,
// 3 blocks/CU, grid 96x16 = 1536 blocks = 2 exact fill-waves.
// Swizzle: 16B slot phys = logical ^ (row&7).
// Epilogue: cg<1088 -> gates [chain][t][272] bf16; else vvT fp32.
// ---------------------------------------------------------------------------
__global__ __launch_bounds__(256, 3) void gemm_gates128(
    const u16* __restrict__ A, const u16* __restrict__ Bt,
    u16* __restrict__ gates, float* __restrict__ vvT)
{
    constexpr int K = 1024;
    constexpr int NTILE = 16;                    // K / 64

    // bijective XCD swizzle: 1536 blocks, 192/XCD = 12 bx x 16 by, by innermost
    const int f = blockIdx.y * gridDim.x + blockIdx.x;
    const int xcd = f & 7, k8 = f >> 3;          // k8 in [0,192)
    const int by = k8 & 15;
    const int bx = xcd * 12 + (k8 >> 4);
    const int m0 = by * 128;
    const int n0 = bx * 192;

    __shared__ alignas(16) u16 As[128 * 64];     // 16 KB
    __shared__ alignas(16) u16 Bs[192 * 64];     // 24 KB

    const int tid  = threadIdx.x;                // 0..255
    const int lane = tid & 63, w = tid >> 6;     // 4 waves
    const int wr = w >> 1, wc = w & 1;           // 2 x 2 wave grid
    const int quad = lane >> 4, l16 = lane & 15;

    // staging: thread t -> row (t>>3) within each 32-row call group, physical
    // 16B slot (t&7); global source slot = (t&7) ^ (row&7)  (involution).
    const int colOff = (((tid & 7) ^ ((tid >> 3) & 7)) * 8);
    const u16* pA = A  + (size_t)(m0 + (tid >> 3)) * K + colOff;
    const u16* pB = Bt + (size_t)(n0 + (tid >> 3)) * K + colOff;
    const int wbase = w * 512;                   // wave-uniform LDS dest (u16)

    // ds-read bases (u16): row*64 + phys_slot*8; phys = (kstep*4+quad)^(l16&7)
    const int sq0 = quad ^ (l16 & 7);
    const int sq1 = sq0 ^ 4;
    const int aoff0 = (wr * 64 + l16) * 64 + sq0 * 8;
    const int aoff1 = (wr * 64 + l16) * 64 + sq1 * 8;
    const int boff0 = (wc * 96 + l16) * 64 + sq0 * 8;
    const int boff1 = (wc * 96 + l16) * 64 + sq1 * 8;

    f32x4 acc[4][6] = {};                        // [mt][nt] wave tile 64x96

    #pragma unroll 1
    for (int t = 0; t < NTILE; ++t) {
        const int kc = t * 64;
        // stage A (4 calls x 32 rows) + B (6 calls x 32 rows)
        #pragma unroll
        for (int c = 0; c < 4; ++c)
            stage16(pA + (size_t)(c * 32) * K + kc, &As[c * 2048 + wbase]);
        #pragma unroll
        for (int c = 0; c < 6; ++c)
            stage16(pB + (size_t)(c * 32) * K + kc, &Bs[c * 2048 + wbase]);
        __syncthreads();

        bf16x8 af[4], bfr[6];
        // kstep 0 (k 0..31)
        #pragma unroll
        for (int mt = 0; mt < 4; ++mt) af[mt]  = *(const bf16x8*)&As[aoff0 + mt * 1024];
        #pragma unroll
        for (int nt = 0; nt < 6; ++nt) bfr[nt] = *(const bf16x8*)&Bs[boff0 + nt * 1024];
        #pragma unroll
        for (int mt = 0; mt < 4; ++mt)
            #pragma unroll
            for (int nt = 0; nt < 6; ++nt)
                acc[mt][nt] = __builtin_amdgcn_mfma_f32_16x16x32_bf16(
                    af[mt], bfr[nt], acc[mt][nt], 0, 0, 0);
        // kstep 1 (k 32..63)
        #pragma unroll
        for (int mt = 0; mt < 4; ++mt) af[mt]  = *(const bf16x8*)&As[aoff1 + mt * 1024];
        #pragma unroll
        for (int nt = 0; nt < 6; ++nt) bfr[nt] = *(const bf16x8*)&Bs[boff1 + nt * 1024];
        #pragma unroll
        for (int mt = 0; mt < 4; ++mt)
            #pragma unroll
            for (int nt = 0; nt < 6; ++nt)
                acc[mt][nt] = __builtin_amdgcn_mfma_f32_16x16x32_bf16(
                    af[mt], bfr[nt], acc[mt][nt], 0, 0, 0);
        __syncthreads();
    }

    // Epilogue: row = m0 + wr*64 + mt*16 + quad*4 + r
    //           col-group cg = bx*12 + wc*6 + nt (lane-uniform), col = cg*16+l16
    const int cgbase = bx * 12 + wc * 6;
    #pragma unroll
    for (int mt = 0; mt < 4; ++mt) {
        #pragma unroll
        for (int r = 0; r < 4; ++r) {
            int row = m0 + wr * 64 + mt * 16 + quad * 4 + r;
            int tt = row & (T_ - 1), bb = row >> 10;
            #pragma unroll
            for (int nt = 0; nt < 6; ++nt) {
                int cg = cgbase + nt;
                float val = acc[mt][nt][r];
                if (cg >= 1088) {
                    vvT[(((size_t)(bb * 64 + (cg - 1088))) * T_ + tt) * 16 + l16] = val;
                } else {
                    int hh = cg / 17, rem = cg - hh * 17;
                    gates[(((size_t)(bb * 64 + hh)) * T_ + tt) * 272 + rem * 16 + l16] = f2b(val);
                }
            }
        }
    }
}

// ---------------------------------------------------------------------------
__global__ __launch_bounds__(256) void rmsnorm_k(
    const float* __restrict__ x, const float* __restrict__ w, u16* __restrict__ out)
{
    const int row = blockIdx.x, tid = threadIdx.x;
    float4 v = ((const float4*)(x + (size_t)row * D_))[tid];
    float ss = v.x * v.x + v.y * v.y + v.z * v.z + v.w * v.w;
    #pragma unroll
    for (int o = 32; o >= 1; o >>= 1) ss += __shfl_xor(ss, o, 64);
    __shared__ float red[4];
    if ((tid & 63) == 0) red[tid >> 6] = ss;
    __syncthreads();
    ss = red[0] + red[1] + red[2] + red[3];
    float scale = rsqrtf(ss * (1.0f / D_) + 1e-5f);
    float4 wv = ((const float4*)w)[tid];
    ushort4 o4;
    o4.x = f2b(v.x * scale * wv.x);
    o4.y = f2b(v.y * scale * wv.y);
    o4.z = f2b(v.z * scale * wv.z);
    o4.w = f2b(v.w * scale * wv.w);
    ((ushort4*)(out + (size_t)row * D_))[tid] = o4;
}

// ---------------------------------------------------------------------------
// All weight converts in one launch. Segments by blockIdx.x (all R=1024):
//   [0,96)   wqkv C=3072 -> wqkvT
//   [96,128) wao  C=1024 -> waoT
//   [128,160)wv   C=1024 -> waT + 17408*1024 (contiguous with waT)
//   [160,704)wa   C=17408-> waT
//   [704,736)wop  C=1024 -> wopT
// ---------------------------------------------------------------------------
__global__ void convT_all(
    const float* __restrict__ wqkv, const float* __restrict__ wao,
    const float* __restrict__ wv,   const float* __restrict__ wa,
    const float* __restrict__ wop,
    u16* __restrict__ wqkvT, u16* __restrict__ waoT,
    u16* __restrict__ waT,   u16* __restrict__ wopT)
{
    const int x = blockIdx.x;
    const float* in; u16* out; int C, xb;
    if (x < 96)       { in = wqkv; out = wqkvT; C = 3072;  xb = x; }
    else if (x < 128) { in = wao;  out = waoT;  C = 1024;  xb = x - 96; }
    else if (x < 160) { in = wv;   out = waT + (size_t)17408 * 1024; C = 1024; xb = x - 128; }
    else if (x < 704) { in = wa;   out = waT;   C = 17408; xb = x - 160; }
    else              { in = wop;  out = wopT;  C = 1024;  xb = x - 704; }
    constexpr int R = 1024;
    __shared__ float tile[32][33];
    const int c0 = xb * 32, r0 = blockIdx.y * 32;
    const int tx = threadIdx.x, ty = threadIdx.y;
    #pragma unroll
    for (int k = 0; k < 4; ++k)
        tile[ty + 8 * k][tx] = in[(size_t)(r0 + ty + 8 * k) * C + c0 + tx];
    __syncthreads();
    #pragma unroll
    for (int k = 0; k < 4; ++k)
        out[(size_t)(c0 + ty + 8 * k) * R + r0 + tx] = f2b(tile[tx][ty + 8 * k]);
}

__global__ void transpose_bf16_k(const u16* __restrict__ in_, u16* __restrict__ out_, int R, int C)
{
    __shared__ u16 tile[32][33];
    const u16* in = in_ + (size_t)blockIdx.z * R * C;
    u16* out      = out_ + (size_t)blockIdx.z * R * C;
    const int c0 = blockIdx.x * 32, r0 = blockIdx.y * 32;
    const int tx = threadIdx.x, ty = threadIdx.y;
    #pragma unroll
    for (int k = 0; k < 4; ++k)
        tile[ty + 8 * k][tx] = in[(size_t)(r0 + ty + 8 * k) * C + c0 + tx];
    __syncthreads();
    #pragma unroll
    for (int k = 0; k < 4; ++k)
        out[(size_t)(c0 + ty + 8 * k) * R + r0 + tx] = tile[tx][ty + 8 * k];
}

// ---------------------------------------------------------------------------
// Scan-chunk prep (shared by p1/p2): raw gate logits for a 32-step chunk in
// glds (32 x 16 rows x 17 bf16 @ 34 B). Softmax each row, repack the 16
// A-entries in place to (st*16+i)*32 B (bf16), scale vlds (v -> a0*v).
// ---------------------------------------------------------------------------
__device__ __forceinline__ void scan_prep(u16* glds, float* vlds, int lane)
{
    #pragma unroll
    for (int rnd = 0; rnd < 2; ++rnd) {
        float p[4][17];
        #pragma unroll
        for (int j = 0; j < 4; ++j) {
            int r = rnd * 256 + j * 64 + lane;
            const u16* g = &glds[r * 17];
            float vv[17];
            float mx = -1e30f;
            #pragma unroll
            for (int tt = 0; tt < 17; ++tt) { vv[tt] = b2f(g[tt]); mx = fmaxf(mx, vv[tt]); }
            float s = 0.f;
            #pragma unroll
            for (int tt = 0; tt < 17; ++tt) { vv[tt] = __expf(vv[tt] - mx); s += vv[tt]; }
            float inv = 1.0f / s;
            #pragma unroll
            for (int tt = 0; tt < 17; ++tt) p[j][tt] = vv[tt] * inv;
        }
        __syncthreads();
        #pragma unroll
        for (int j = 0; j < 4; ++j) {
            int r = rnd * 256 + j * 64 + lane;
            uint4 w0, w1;
            w0.x = (u32)f2b(p[j][1])  | ((u32)f2b(p[j][2])  << 16);
            w0.y = (u32)f2b(p[j][3])  | ((u32)f2b(p[j][4])  << 16);
            w0.z = (u32)f2b(p[j][5])  | ((u32)f2b(p[j][6])  << 16);
            w0.w = (u32)f2b(p[j][7])  | ((u32)f2b(p[j][8])  << 16);
            w1.x = (u32)f2b(p[j][9])  | ((u32)f2b(p[j][10]) << 16);
            w1.y = (u32)f2b(p[j][11]) | ((u32)f2b(p[j][12]) << 16);
            w1.z = (u32)f2b(p[j][13]) | ((u32)f2b(p[j][14]) << 16);
            w1.w = (u32)f2b(p[j][15]) | ((u32)f2b(p[j][16]) << 16);
            ((uint4*)glds)[r * 2]     = w0;
            ((uint4*)glds)[r * 2 + 1] = w1;
            vlds[r] *= p[j][0];
        }
        __syncthreads();
    }
}

// ---------------------------------------------------------------------------
// scan pass 1: per chunk of 32 steps compute P_c = A_31..A_0, e_c.
// ---------------------------------------------------------------------------
__global__ __launch_bounds__(64) void scan_p1(
    const u16* __restrict__ gates, const float* __restrict__ vvT,
    float* __restrict__ Pmat, float* __restrict__ evec)
{
    const int c = blockIdx.x, chain = blockIdx.y;
    const int lane = threadIdx.x;
    const int i = lane >> 2, q = lane & 3;
    __shared__ alignas(16) u16   glds[32 * 272];
    __shared__ alignas(16) float vlds[32 * 16];
    __shared__ alignas(16) float Pb[2][256];
    __shared__ float slds[16];

    const char* gbase = (const char*)(gates + ((size_t)chain * T_ + c * 32) * 272);
    #pragma unroll
    for (int it = 0; it < 17; ++it)
        stage16(gbase + it * 1024 + lane * 16, (char*)glds + it * 1024);
    const char* vbase = (const char*)(vvT + ((size_t)chain * T_ + c * 32) * 16);
    #pragma unroll
    for (int it = 0; it < 2; ++it)
        stage16(vbase + it * 1024 + lane * 16, (char*)vlds + it * 1024);
    __syncthreads();

    scan_prep(glds, vlds, lane);

    {
        f32x4 idq;
        #pragma unroll
        for (int m = 0; m < 4; ++m) idq[m] = (i == q * 4 + m) ? 1.f : 0.f;
        *(f32x4*)&Pb[0][i * 16 + q * 4] = idq;
    }
    f32x4 e4[4] = {};
    f32x4 np = {};
    float neLast = 0.f;
    int cur = 0;

    for (int st = 0; st < 32; ++st) {
        const uint4* rp = (const uint4*)((const char*)glds + (st * 16 + i) * 32);
        uint4 d0 = rp[0], d1 = rp[1];
        float ar[16];
        ar[0]  = blo(d0.x); ar[1]  = bhi(d0.x);
        ar[2]  = blo(d0.y); ar[3]  = bhi(d0.y);
        ar[4]  = blo(d0.z); ar[5]  = bhi(d0.z);
        ar[6]  = blo(d0.w); ar[7]  = bhi(d0.w);
        ar[8]  = blo(d1.x); ar[9]  = bhi(d1.x);
        ar[10] = blo(d1.y); ar[11] = bhi(d1.y);
        ar[12] = blo(d1.z); ar[13] = bhi(d1.z);
        ar[14] = blo(d1.w); ar[15] = bhi(d1.w);

        f32x4 pk[16];
        #pragma unroll
        for (int k = 0; k < 16; ++k)
            pk[k] = *(const f32x4*)&Pb[cur][k * 16 + q * 4];

        f32x4 a = pk[0] * ar[0];
        #pragma unroll
        for (int k = 1; k < 16; ++k) a += pk[k] * ar[k];
        np = a;

        float ne0 = ar[0] * e4[0][0] + ar[1] * e4[0][1] + ar[2] * e4[0][2] + ar[3] * e4[0][3];
        float ne1 = ar[4] * e4[1][0] + ar[5] * e4[1][1] + ar[6] * e4[1][2] + ar[7] * e4[1][3];
        float ne2 = ar[8] * e4[2][0] + ar[9] * e4[2][1] + ar[10] * e4[2][2] + ar[11] * e4[2][3];
        float ne3 = ar[12] * e4[3][0] + ar[13] * e4[3][1] + ar[14] * e4[3][2] + ar[15] * e4[3][3];
        float ne = (ne0 + ne1) + (ne2 + ne3) + vlds[st * 16 + i];

        *(f32x4*)&Pb[cur ^ 1][i * 16 + q * 4] = np;
        if (q == 0) slds[i] = ne;
        #pragma unroll
        for (int m = 0; m < 4; ++m) e4[m] = *(const f32x4*)&slds[m * 4];
        neLast = ne;
        cur ^= 1;
    }

    float* Pd = Pmat + ((size_t)chain * 32 + c) * 256;
    *(f32x4*)&Pd[i * 16 + q * 4] = np;
    if (q == 0) evec[((size_t)chain * 32 + c) * 16 + i] = neLast;
}

// ---------------------------------------------------------------------------
// scan pass 2: per chain, sequentially combine 32 chunks; sIn[c] = entry state.
// ---------------------------------------------------------------------------
__global__ __launch_bounds__(64) void scan_comb(
    const float* __restrict__ Pmat, const float* __restrict__ evec, float* __restrict__ sIn)
{
    const int chain = blockIdx.x;
    const int lane = threadIdx.x;
    const int i = lane >> 2, q = lane & 3;
    __shared__ alignas(16) float Pl[32 * 256];
    __shared__ alignas(16) float El[32 * 16];
    __shared__ float slds[16];

    const char* Pg = (const char*)(Pmat + (size_t)chain * 32 * 256);
    #pragma unroll
    for (int it = 0; it < 32; ++it)
        stage16(Pg + it * 1024 + lane * 16, (char*)Pl + it * 1024);
    const char* Eg = (const char*)(evec + (size_t)chain * 32 * 16);
    #pragma unroll
    for (int it = 0; it < 2; ++it)
        stage16(Eg + it * 1024 + lane * 16, (char*)El + it * 1024);
    __syncthreads();

    f32x4 s4[4] = {};
    if (q == 0) sIn[((size_t)chain * 32 + 0) * 16 + i] = 0.f;
    for (int cc = 0; cc < 32; ++cc) {
        f32x4 pr[4];
        #pragma unroll
        for (int m = 0; m < 4; ++m)
            pr[m] = *(const f32x4*)&Pl[cc * 256 + i * 16 + m * 4];
        float ne = 0.f;
        #pragma unroll
        for (int k = 0; k < 16; ++k) ne += pr[k >> 2][k & 3] * s4[k >> 2][k & 3];
        ne += El[cc * 16 + i];
        if (q == 0) {
            slds[i] = ne;
            if (cc < 31) sIn[((size_t)chain * 32 + cc + 1) * 16 + i] = ne;
        }
        #pragma unroll
        for (int m = 0; m < 4; ++m) s4[m] = *(const f32x4*)&slds[m * 4];
    }
}

// ---------------------------------------------------------------------------
// scan pass 3: replay each chunk from its entry state, write h_out.
// ---------------------------------------------------------------------------
__global__ __launch_bounds__(64) void scan_p2(
    const u16* __restrict__ gates, const float* __restrict__ vvT,
    const float* __restrict__ sIn, u16* __restrict__ hout)
{
    const int c = blockIdx.x, chain = blockIdx.y;
    const int b = chain >> 6, hh = chain & 63;
    const int lane = threadIdx.x;
    const int i = lane >> 2, q = lane & 3;
    __shared__ alignas(16) u16   glds[32 * 272];
    __shared__ alignas(16) float vlds[32 * 16];
    __shared__ float slds[16];

    const char* gbase = (const char*)(gates + ((size_t)chain * T_ + c * 32) * 272);
    #pragma unroll
    for (int it = 0; it < 17; ++it)
        stage16(gbase + it * 1024 + lane * 16, (char*)glds + it * 1024);
    const char* vbase = (const char*)(vvT + ((size_t)chain * T_ + c * 32) * 16);
    #pragma unroll
    for (int it = 0; it < 2; ++it)
        stage16(vbase + it * 1024 + lane * 16, (char*)vlds + it * 1024);
    __syncthreads();

    scan_prep(glds, vlds, lane);

    const float* sp = sIn + ((size_t)chain * 32 + c) * 16;
    f32x4 s4[4];
    #pragma unroll
    for (int m = 0; m < 4; ++m) s4[m] = *(const f32x4*)(sp + m * 4);

    u16* hbase = hout + ((size_t)(b * T_ + c * 32)) * D_ + hh * 16;
    for (int st = 0; st < 32; ++st) {
        const uint4* rp = (const uint4*)((const char*)glds + (st * 16 + i) * 32);
        uint4 d0 = rp[0], d1 = rp[1];
        float ne0 = blo(d0.x) * s4[0][0] + bhi(d0.x) * s4[0][1]
                  + blo(d0.y) * s4[0][2] + bhi(d0.y) * s4[0][3];
        float ne1 = blo(d0.z) * s4[1][0] + bhi(d0.z) * s4[1][1]
                  + blo(d0.w) * s4[1][2] + bhi(d0.w) * s4[1][3];
        float ne2 = blo(d1.x) * s4[2][0] + bhi(d1.x) * s4[2][1]
                  + blo(d1.y) * s4[2][2] + bhi(d1.y) * s4[2][3];
        float ne3 = blo(d1.z) * s4[3][0] + bhi(d1.z) * s4[3][1]
                  + blo(d1.w) * s4[3][2] + bhi(d1.w) * s4[3][3];
        float ne = (ne0 + ne1) + (ne2 + ne3) + vlds[st * 16 + i];
        if (q == 0) {
            slds[i] = ne;
            hbase[(size_t)st * D_ + i] = f2b(ne);
        }
        #pragma unroll
        for (int m = 0; m < 4; ++m) s4[m] = *(const f32x4*)&slds[m * 4];
    }
}

// ---------------------------------------------------------------------------
extern "C" void kernel_launch(void* const* d_in, const int* in_sizes, int n_in,
                              void* d_out, int out_size, void* d_ws, size_t ws_size,
                              hipStream_t stream)
{
    const float* x    = (const float*)d_in[0];
    const float* anw  = (const float*)d_in[1];
    const float* wqkv = (const float*)d_in[2];
    const float* wao  = (const float*)d_in[3];
    const float* lnw  = (const float*)d_in[4];
    const float* wv   = (const float*)d_in[5];
    const float* wa   = (const float*)d_in[6];
    const float* wop  = (const float*)d_in[7];

    char* ws = (char*)d_ws;
    const size_t MB = 1u << 20;
    u16*   h     = (u16*)  (ws +   0 * MB);   //  4 MB
    u16*   h2    = (u16*)  (ws +   4 * MB);   //  4 MB
    u16*   wqkvT = (u16*)  (ws +   8 * MB);   //  6 MB
    u16*   waoT  = (u16*)  (ws +  14 * MB);   //  2 MB
    u16*   wopT  = (u16*)  (ws +  16 * MB);   //  2 MB
    u16*   waT   = (u16*)  (ws +  18 * MB);   // 36 MB (wa 17408 rows + wv 1024 rows)
    float* x2    = (float*)(ws +  54 * MB);   //  8 MB
    float* vvT   = (float*)(ws +  62 * MB);   //  8 MB scan layout [chain][t][16]
    u16*   Qb    = (u16*)  (ws +  78 * MB);   //  4 MB (dead after attn)
    float* Pmat  = (float*)(ws +  78 * MB);   //  4 MB aliases Qb
    u16*   Kb    = (u16*)  (ws +  82 * MB);   //  4 MB (dead after attn)
    float* evec  = (float*)(ws +  82 * MB);   // 256 KB aliases Kb
    float* sIn   = (float*)(ws +  82 * MB + 256 * 1024); // 256 KB
    u16*   Vb    = (u16*)  (ws +  86 * MB);   //  4 MB (dead after transpose)
    u16*   Vt    = (u16*)  (ws +  90 * MB);   //  4 MB (dead after attn)
    u16*   omat  = (u16*)  (ws + 158 * MB);   //  4 MB (dead after attn_out)
    u16*   gates = (u16*)  (ws +  94 * MB);   // 68 MB aliases old S region
    float* ropeT = (float*)(ws +  94 * MB);   // 256 KB RoPE table (dead before gates)
    u16*   hout  = (u16*)  (ws + 162 * MB);   //  4 MB (end: 166 MB)
    (void)in_sizes; (void)n_in; (void)out_size; (void)ws_size;

    // RoPE cos/sin table [1024][32] float2 (region is free until gemm_gates128)
    rope_tab_k<<<128, 256, 0, stream>>>((float2*)ropeT);

    dim3 tb(32, 8);
    convT_all<<<dim3(736, 32), tb, 0, stream>>>(
        wqkv, wao, wv, wa, wop, wqkvT, waoT, waT, wopT);

    rmsnorm_k<<<2048, 256, 0, stream>>>(x, anw, h);
    // qkv GEMM with fused RoPE epilogue -> Qb, Kb, Vb directly (128x128 tile)
    gemm_bt<128, 128, 64, 6, false, false, 0><<<dim3(24, 16, 1), 256, 0, stream>>>(
        h, wqkvT, (void*)Qb, (void*)Kb, (void*)Vb, ropeT, 2048, 3072, 1024, 0, 0, 0);
    transpose_bf16_k<<<dim3(2, 32, 32), tb, 0, stream>>>(Vb, Vt, 1024, 64);

    // fused flash attention (double-buffered): QK^T + softmax + PV, 1 launch
    attn_flash<<<512, 256, 0, stream>>>(Qb, Kb, Vt, omat);

    gemm_bt<64, 128, 64, 0, false, false, 0><<<dim3(8, 32, 1), 256, 0, stream>>>(
        omat, waoT, (void*)x2, nullptr, nullptr, x, 2048, 1024, 1024, 0, 0, 0);
    rmsnorm_k<<<2048, 256, 0, stream>>>(x2, lnw, h2);

    // fused gates + w_v GEMM: m97-structure 128x192, 1536 blocks, 3 blocks/CU
    gemm_gates128<<<dim3(96, 16), 256, 0, stream>>>(h2, waT, gates, vvT);

    scan_p1<<<dim3(32, 128), 64, 0, stream>>>(gates, vvT, Pmat, evec);
    scan_comb<<<128, 64, 0, stream>>>(Pmat, evec, sIn);
    scan_p2<<<dim3(32, 128), 64, 0, stream>>>(gates, vvT, sIn, hout);

    gemm_bt<64, 128, 64, 0, false, false, 0><<<dim3(8, 32, 1), 256, 0, stream>>>(
        hout, wopT, d_out, nullptr, nullptr, x2, 2048, 1024, 1024, 0, 0, 0);
}